// Round 5
// baseline (359.778 us; speedup 1.0000x reference)
//
#include <hip/hip_runtime.h>

// ---------------------------------------------------------------------------
// TransformerBlockQuantum: B=2,S=2048,E=1024,H=32,DK=32,FFN=4096
// GEMMs: bf16 MFMA 16x16x32 (m97 structure), fused QKV projection.
// Attention: swapped 32x32 QK^T, UNSHIFTED exp2 softmax (scores bounded:
// std~5.7, overflow needs 15-sigma), in-register P pack via permlane32_swap,
// split-K 2-way with LDS merge of {l, acc} only.
// ws layout (MB):
//  [0,2)WqT [2,4)WkT [4,6)WvT  (contiguous => fused QKV BT[3072][1024])
//  [6,8)WoT [8,16)W1T [16,24)W2T
//  [24,40) r1 (fp32 residual1 / post-LN1 fp32)
//  [40,48) xb  | [48,56) qh | [56,64) kh | [64,72) vT   <- hf aliases [40,72)
//  [72,80) ao  | [80,88) x1b                             <- r2 aliases [72,88)
// ---------------------------------------------------------------------------

typedef unsigned short u16;
typedef unsigned int u32;
typedef __bf16 bf16x8 __attribute__((ext_vector_type(8)));
typedef float f32x4 __attribute__((ext_vector_type(4)));
typedef float f32x16 __attribute__((ext_vector_type(16)));

__device__ __forceinline__ u16 f2b(float f) {
  union { float f; unsigned u; } x; x.f = f;
  unsigned r = x.u + 0x7FFFu + ((x.u >> 16) & 1u);
  return (u16)(r >> 16);
}

__device__ __forceinline__ unsigned pkbf(float lo, float hi) {
  unsigned r;
  asm("v_cvt_pk_bf16_f32 %0, %1, %2" : "=v"(r) : "v"(lo), "v"(hi));
  return r;
}

__device__ __forceinline__ float expo2(float x) {
#if __has_builtin(__builtin_amdgcn_exp2f)
  return __builtin_amdgcn_exp2f(x);
#else
  return exp2f(x);
#endif
}

#define GLDS16(gp, lp)                                                         \
  __builtin_amdgcn_global_load_lds(                                            \
      (const __attribute__((address_space(1))) void*)(gp),                     \
      (__attribute__((address_space(3))) void*)(lp), 16, 0, 0)

// ---------------- transpose + cast: W[K][N] f32 -> WT[N][K] bf16 ------------
__global__ __launch_bounds__(256) void transpose_cast(
    const float* __restrict__ W, u16* __restrict__ WT, int K, int N) {
  __shared__ float tile[32][33];
  const int tx = threadIdx.x & 31, ty = threadIdx.x >> 5;
  const int n0 = blockIdx.x * 32, k0 = blockIdx.y * 32;
#pragma unroll
  for (int i = 0; i < 4; ++i)
    tile[ty + 8 * i][tx] = W[(size_t)(k0 + ty + 8 * i) * N + n0 + tx];
  __syncthreads();
#pragma unroll
  for (int i = 0; i < 4; ++i)
    WT[(size_t)(n0 + ty + 8 * i) * K + k0 + tx] = f2b(tile[tx][ty + 8 * i]);
}

// ---------------- cast f32 -> bf16 (4 elems/thread) -------------------------
__global__ __launch_bounds__(256) void cast_b(const float* __restrict__ x,
                                              u16* __restrict__ y) {
  int i = blockIdx.x * 256 + threadIdx.x;
  float4 v = ((const float4*)x)[i];
  ushort4 o;
  o.x = f2b(v.x); o.y = f2b(v.y); o.z = f2b(v.z); o.w = f2b(v.w);
  ((ushort4*)y)[i] = o;
}

// ---------------- GEMM: C = A[M,K] @ BT[N,K]^T, bf16 in, fused epilogues ----
// MODE 2: fp32 out = acc + bias + res   (Wo and W2 paths)
// MODE 3: bf16 out = relu(acc + bias)   (W1 path)
// MODE 5: fused QKV: col<1024 -> q-scaled head store; <2048 -> k head store;
//         else -> v transposed store. bias/bias2/bias3 = bq/bk/bv.
template <int MODE>
__global__ __launch_bounds__(256) void gemm128(
    const u16* __restrict__ A, const u16* __restrict__ BT,
    const float* __restrict__ bias, const float* __restrict__ bias2,
    const float* __restrict__ bias3, const float* __restrict__ res,
    void* __restrict__ outp, const float* __restrict__ kW, int N_, int K_) {
  __shared__ __align__(16) u16 As[128 * 32];
  __shared__ __align__(16) u16 Bs[128 * 32];
  const int t = threadIdx.x;
  const int lane = t & 63, wid = t >> 6;
  const int m0 = blockIdx.y * 128, n0 = blockIdx.x * 128;
  const int wr = (wid >> 1) * 64, wc = (wid & 1) * 64;
  const int lr = lane & 15, lg = lane >> 4;
  const int K = K_;

  f32x4 acc[4][4] = {};

  const u16* ga0 = A + (size_t)(m0 + (t >> 2)) * K + (t & 3) * 8;
  const u16* ga1 = ga0 + (size_t)64 * K;
  const u16* gb0 = BT + (size_t)(n0 + (t >> 2)) * K + (t & 3) * 8;
  const u16* gb1 = gb0 + (size_t)64 * K;
  char* lA = (char*)As + wid * 1024;
  char* lB = (char*)Bs + wid * 1024;

  const int nk = K >> 5;
  for (int kt = 0; kt < nk; ++kt) {
    __syncthreads();
    GLDS16(ga0, lA); GLDS16(ga1, lA + 4096);
    GLDS16(gb0, lB); GLDS16(gb1, lB + 4096);
    ga0 += 32; ga1 += 32; gb0 += 32; gb1 += 32;
    __syncthreads();
    bf16x8 af[4], bf[4];
#pragma unroll
    for (int i = 0; i < 4; ++i) {
      af[i] = *(const bf16x8*)((const char*)As + (wr + i * 16 + lr) * 64 + lg * 16);
      bf[i] = *(const bf16x8*)((const char*)Bs + (wc + i * 16 + lr) * 64 + lg * 16);
    }
#pragma unroll
    for (int mi = 0; mi < 4; ++mi)
#pragma unroll
      for (int ni = 0; ni < 4; ++ni)
        acc[mi][ni] = __builtin_amdgcn_mfma_f32_16x16x32_bf16(
            af[mi], bf[ni], acc[mi][ni], 0, 0, 0);
  }

#pragma unroll
  for (int mi = 0; mi < 4; ++mi) {
#pragma unroll
    for (int ni = 0; ni < 4; ++ni) {
      const int row = m0 + wr + mi * 16 + lg * 4;
      const int col = n0 + wc + ni * 16 + lr;
      f32x4 v = acc[mi][ni];
      if constexpr (MODE == 2) {
        const float bv = bias[col];
        float* o = (float*)outp;
#pragma unroll
        for (int r = 0; r < 4; ++r) {
          const int rr = row + r;
          o[(size_t)rr * N_ + col] = v[r] + bv + res[(size_t)rr * N_ + col];
        }
      } else if constexpr (MODE == 3) {
        const float bv = bias[col];
        u16* o = (u16*)outp;
#pragma unroll
        for (int r = 0; r < 4; ++r) {
          const int rr = row + r;
          float y = v[r] + bv;
          o[(size_t)rr * N_ + col] = f2b(y > 0.f ? y : 0.f);
        }
      } else {  // MODE 5
        const int proj = col >> 10, c = col & 1023;
        const int h = c >> 5, d = c & 31;
        u16* qout = (u16*)outp;
        if (proj == 0) {
          const float bv = bias[c];
          const float sc = kW[d * 32 + h] * 1.44269504089f;
#pragma unroll
          for (int r = 0; r < 4; ++r) {
            const int rr = row + r;
            const int bb = rr >> 11, s = rr & 2047;
            qout[(size_t)(((bb * 32 + h) * 2048) + s) * 32 + d] =
                f2b((v[r] + bv) * sc);
          }
        } else if (proj == 1) {
          const float bv = bias2[c];
          u16* kout = qout + 4194304;
#pragma unroll
          for (int r = 0; r < 4; ++r) {
            const int rr = row + r;
            const int bb = rr >> 11, s = rr & 2047;
            kout[(size_t)(((bb * 32 + h) * 2048) + s) * 32 + d] =
                f2b(v[r] + bv);
          }
        } else {
          const float bv = bias3[c];
          u16* vout = qout + 8388608;
          const int bb = row >> 11, s0 = row & 2047;
          ushort4 st;
          st.x = f2b(v[0] + bv); st.y = f2b(v[1] + bv);
          st.z = f2b(v[2] + bv); st.w = f2b(v[3] + bv);
          *(ushort4*)(vout + ((size_t)((bb * 32 + h) * 32 + d)) * 2048 + s0) = st;
        }
      }
    }
  }
}

// ---------------- swapped 32x32 flash attention, split-K 2-way --------------
// Block = 4 waves: qg = wid&1 (32 queries each), kh = wid>>1 (1024 keys each).
// Scores pre-scaled by log2e (folded into q-proj). C[key][q]: lane holds 32
// scores of query lane&31 per 64-key batch. UNSHIFTED softmax: p = exp2(s)
// directly (safe: needs 15-sigma score to overflow f32). No max chain, no
// rescale -> all 32 exp2 per tile independent.
__global__ __launch_bounds__(256) void attn_kernel(
    const u16* __restrict__ Q, const u16* __restrict__ K,
    const u16* __restrict__ VT, u16* __restrict__ O) {
  __shared__ float sm_l[2][32];
  __shared__ float sm_acc[2][64][16];
  const int t = threadIdx.x, wid = t >> 6, lane = t & 63;
  const int qg = wid & 1, kh = wid >> 1;
  const int bid = blockIdx.x;
  const int swz = (bid & 7) * 256 + (bid >> 3);  // 2048 blocks, 8 XCDs
  const int bh = swz >> 5;                       // 0..63
  const int qt = swz & 31;                       // q-tile of 64
  const int q0 = qt * 64 + qg * 32;
  const int lq = lane & 31, hi = lane >> 5;
  const u16* Qh = Q + (size_t)bh * 2048 * 32;
  const u16* Kh = K + (size_t)bh * 2048 * 32;
  const u16* Vh = VT + (size_t)bh * 32 * 2048;

  bf16x8 qb[2];
  qb[0] = *(const bf16x8*)(Qh + (size_t)(q0 + lq) * 32 + hi * 8);
  qb[1] = *(const bf16x8*)(Qh + (size_t)(q0 + lq) * 32 + 16 + hi * 8);

  f32x16 acc = {};
  float la = 0.f, lb = 0.f, lc = 0.f, ld = 0.f;  // independent partial sums
  const f32x16 zero16 = {};

  const int jb = kh * 1024, je = jb + 1024;
  for (int j0 = jb; j0 < je; j0 += 64) {
    // QK^T: K as A-operand (row=key lane&31), Q as B
    f32x16 s[2];
    __builtin_amdgcn_s_setprio(1);
#pragma unroll
    for (int sub = 0; sub < 2; ++sub) {
      const u16* kr = Kh + (size_t)(j0 + sub * 32 + lq) * 32 + hi * 8;
      const bf16x8 ka0 = *(const bf16x8*)(kr);
      const bf16x8 ka1 = *(const bf16x8*)(kr + 16);
      f32x16 c = __builtin_amdgcn_mfma_f32_32x32x16_bf16(ka0, qb[0], zero16, 0, 0, 0);
      s[sub] = __builtin_amdgcn_mfma_f32_32x32x16_bf16(ka1, qb[1], c, 0, 0, 0);
    }
    __builtin_amdgcn_s_setprio(0);
    // unshifted exp2 + partial sums + pack to PV B-fragments
    bf16x8 pb[2][2];
#pragma unroll
    for (int sub = 0; sub < 2; ++sub) {
      float p[16];
#pragma unroll
      for (int r = 0; r < 16; ++r) p[r] = expo2(s[sub][r]);
#pragma unroll
      for (int r = 0; r < 4; ++r) {
        la += p[r]; lb += p[4 + r]; lc += p[8 + r]; ld += p[12 + r];
      }
#pragma unroll
      for (int c = 0; c < 2; ++c) {
        // x* = low-key words (keys 2i,2i+1), y* = high-key words (8+2i,..):
        // permlane32_swap vdst_HI <-> vsrc_LO with vdst = x.
        u32 x0 = pkbf(p[c * 8 + 0], p[c * 8 + 1]);
        u32 x1 = pkbf(p[c * 8 + 2], p[c * 8 + 3]);
        u32 y0 = pkbf(p[c * 8 + 4], p[c * 8 + 5]);
        u32 y1 = pkbf(p[c * 8 + 6], p[c * 8 + 7]);
        asm volatile("v_permlane32_swap_b32 %0, %1" : "+v"(x0), "+v"(y0));
        asm volatile("v_permlane32_swap_b32 %0, %1" : "+v"(x1), "+v"(y1));
        union { u32 d[4]; bf16x8 v; } u;
        u.d[0] = x0; u.d[1] = x1; u.d[2] = y0; u.d[3] = y1;
        pb[sub][c] = u.v;
      }
    }
    // PV: V^T as A-operand (row=d, k=key)
    __builtin_amdgcn_s_setprio(1);
#pragma unroll
    for (int sub = 0; sub < 2; ++sub)
#pragma unroll
      for (int c = 0; c < 2; ++c) {
        const bf16x8 va = *(const bf16x8*)(Vh + (size_t)lq * 2048 + j0 +
                                           sub * 32 + c * 16 + hi * 8);
        acc = __builtin_amdgcn_mfma_f32_32x32x16_bf16(va, pb[sub][c], acc, 0, 0, 0);
      }
    __builtin_amdgcn_s_setprio(0);
  }

  float lrun = (la + lb) + (lc + ld);
  lrun += __shfl_xor(lrun, 32);

  // merge the two key-halves via LDS
  if (kh == 1) {
    sm_l[qg][lq] = lrun;
#pragma unroll
    for (int r = 0; r < 16; ++r) sm_acc[qg][lane][r] = acc[r];
  }
  __syncthreads();
  if (kh == 0) {
    const float inv = 1.f / (lrun + sm_l[qg][lq]);
    const int bb = bh >> 5, h = bh & 31;
    u16* o = O + (size_t)(bb * 2048 + q0 + lq) * 1024 + h * 32;
#pragma unroll
    for (int g = 0; g < 4; ++g) {
      ushort4 st;
      st.x = f2b((acc[g * 4 + 0] + sm_acc[qg][lane][g * 4 + 0]) * inv);
      st.y = f2b((acc[g * 4 + 1] + sm_acc[qg][lane][g * 4 + 1]) * inv);
      st.z = f2b((acc[g * 4 + 2] + sm_acc[qg][lane][g * 4 + 2]) * inv);
      st.w = f2b((acc[g * 4 + 3] + sm_acc[qg][lane][g * 4 + 3]) * inv);
      *(ushort4*)(o + g * 8 + hi * 4) = st;
    }
  }
}

// ---------------- LayerNorm (1 wave per row of 1024) ------------------------
template <int WB>
__global__ __launch_bounds__(256) void ln_kernel(
    const float* X, const float* __restrict__ g, const float* __restrict__ b,
    float* outf, u16* __restrict__ outb) {
  const int wid = threadIdx.x >> 6, lane = threadIdx.x & 63;
  const int row = blockIdx.x * 4 + wid;
  const float4* X4 = (const float4*)(X + (size_t)row * 1024);
  float4 xs[4];
  float s = 0.f, sq = 0.f;
#pragma unroll
  for (int i = 0; i < 4; ++i) {
    xs[i] = X4[lane + i * 64];
    s += xs[i].x + xs[i].y + xs[i].z + xs[i].w;
    sq += xs[i].x * xs[i].x + xs[i].y * xs[i].y + xs[i].z * xs[i].z + xs[i].w * xs[i].w;
  }
#pragma unroll
  for (int m = 1; m < 64; m <<= 1) { s += __shfl_xor(s, m); sq += __shfl_xor(sq, m); }
  const float mean = s * (1.f / 1024.f);
  float var = sq * (1.f / 1024.f) - mean * mean;
  var = var > 0.f ? var : 0.f;
  const float rstd = rsqrtf(var + 1e-5f);
  const float4* g4 = (const float4*)g;
  const float4* b4 = (const float4*)b;
  float4* of = (float4*)(outf + (size_t)row * 1024);
#pragma unroll
  for (int i = 0; i < 4; ++i) {
    const int c = lane + i * 64;
    const float4 gv = g4[c], bv = b4[c], x = xs[i];
    float4 y;
    y.x = (x.x - mean) * rstd * gv.x + bv.x;
    y.y = (x.y - mean) * rstd * gv.y + bv.y;
    y.z = (x.z - mean) * rstd * gv.z + bv.z;
    y.w = (x.w - mean) * rstd * gv.w + bv.w;
    of[c] = y;
    if constexpr (WB) {
      ushort4 yb;
      yb.x = f2b(y.x); yb.y = f2b(y.y); yb.z = f2b(y.z); yb.w = f2b(y.w);
      ((ushort4*)(outb + (size_t)row * 1024))[c] = yb;
    }
  }
}

// ---------------------------------------------------------------------------
extern "C" void kernel_launch(void* const* d_in, const int* in_sizes, int n_in,
                              void* d_out, int out_size, void* d_ws,
                              size_t ws_size, hipStream_t stream) {
  const float* x   = (const float*)d_in[0];
  const float* Wq  = (const float*)d_in[1];
  const float* bq  = (const float*)d_in[2];
  const float* Wk  = (const float*)d_in[3];
  const float* bk  = (const float*)d_in[4];
  const float* Wv  = (const float*)d_in[5];
  const float* bv  = (const float*)d_in[6];
  const float* kW  = (const float*)d_in[7];
  const float* Wo  = (const float*)d_in[8];
  const float* bo  = (const float*)d_in[9];
  const float* W1  = (const float*)d_in[10];
  const float* b1  = (const float*)d_in[11];
  const float* W2  = (const float*)d_in[12];
  const float* b2  = (const float*)d_in[13];
  const float* g1  = (const float*)d_in[14];
  const float* be1 = (const float*)d_in[15];
  const float* g2  = (const float*)d_in[16];
  const float* be2 = (const float*)d_in[17];

  char* ws = (char*)d_ws;
  const size_t MB = 1024 * 1024;
  u16*   WqT = (u16*)(ws + 0 * MB);   // [0,6) = fused QKV BT[3072][1024]
  u16*   WkT = (u16*)(ws + 2 * MB);
  u16*   WvT = (u16*)(ws + 4 * MB);
  u16*   WoT = (u16*)(ws + 6 * MB);
  u16*   W1T = (u16*)(ws + 8 * MB);
  u16*   W2T = (u16*)(ws + 16 * MB);
  float* r1  = (float*)(ws + 24 * MB);
  u16*   xb  = (u16*)(ws + 40 * MB);
  u16*   qhB = (u16*)(ws + 48 * MB);
  u16*   khB = (u16*)(ws + 56 * MB);
  u16*   vTB = (u16*)(ws + 64 * MB);
  u16*   hf  = (u16*)(ws + 40 * MB);  // aliases xb..vT, free by then
  u16*   ao  = (u16*)(ws + 72 * MB);
  u16*   x1b = (u16*)(ws + 80 * MB);
  float* r2  = (float*)(ws + 72 * MB);  // aliases ao+x1b, free by then

  const dim3 blk(256);

  transpose_cast<<<dim3(32, 32), blk, 0, stream>>>(Wq, WqT, 1024, 1024);
  transpose_cast<<<dim3(32, 32), blk, 0, stream>>>(Wk, WkT, 1024, 1024);
  transpose_cast<<<dim3(32, 32), blk, 0, stream>>>(Wv, WvT, 1024, 1024);
  transpose_cast<<<dim3(32, 32), blk, 0, stream>>>(Wo, WoT, 1024, 1024);
  transpose_cast<<<dim3(128, 32), blk, 0, stream>>>(W1, W1T, 1024, 4096);
  transpose_cast<<<dim3(32, 128), blk, 0, stream>>>(W2, W2T, 4096, 1024);
  cast_b<<<4096, blk, 0, stream>>>(x, xb);

  // fused QKV projection (q scaled by kernelW*log2e, v stored transposed)
  gemm128<5><<<dim3(24, 32), blk, 0, stream>>>(xb, WqT, bq, bk, bv, nullptr,
                                               qhB, kW, 3072, 1024);

  // flash attention: 2048 blocks x 4 waves (2 qg x 2 key-halves)
  attn_kernel<<<2048, blk, 0, stream>>>(qhB, khB, vTB, ao);

  // out-proj + residual -> r1 (fp32)
  gemm128<2><<<dim3(8, 32), blk, 0, stream>>>(ao, WoT, bo, nullptr, nullptr, x,
                                              r1, nullptr, 1024, 1024);
  ln_kernel<1><<<1024, blk, 0, stream>>>(r1, g1, be1, r1, x1b);
  // FFN
  gemm128<3><<<dim3(32, 32), blk, 0, stream>>>(x1b, W1T, b1, nullptr, nullptr,
                                               nullptr, hf, nullptr, 4096, 1024);
  gemm128<2><<<dim3(8, 32), blk, 0, stream>>>(hf, W2T, b2, nullptr, nullptr, r1,
                                              r2, nullptr, 1024, 4096);
  ln_kernel<0><<<1024, blk, 0, stream>>>(r2, g2, be2, (float*)d_out, nullptr);

  (void)in_sizes; (void)n_in; (void)out_size; (void)ws_size;
}

// Round 6
// 350.868 us; speedup vs baseline: 1.0254x; 1.0254x over previous
//
#include <hip/hip_runtime.h>

// ---------------------------------------------------------------------------
// TransformerBlockQuantum: B=2,S=2048,E=1024,H=32,DK=32,FFN=4096
// GEMMs: bf16 MFMA 16x16x32 (m97 structure), fused QKV projection.
// Attention: swapped 32x32 QK^T, UNSHIFTED exp2 softmax, in-register P pack
// via permlane32_swap, split-K 2-way, explicit 2-stage register double-buffer
// (K/V loads for tile t+1 issued before compute of tile t).
// ws layout (MB):
//  [0,2)WqT [2,4)WkT [4,6)WvT  (contiguous => fused QKV BT[3072][1024])
//  [6,8)WoT [8,16)W1T [16,24)W2T
//  [24,40) r1 (fp32 residual1 / post-LN1 fp32)
//  [40,48) xb  | [48,56) qh | [56,64) kh | [64,72) vT   <- hf aliases [40,72)
//  [72,80) ao  | [80,88) x1b                             <- r2 aliases [72,88)
// ---------------------------------------------------------------------------

typedef unsigned short u16;
typedef unsigned int u32;
typedef __bf16 bf16x8 __attribute__((ext_vector_type(8)));
typedef float f32x4 __attribute__((ext_vector_type(4)));
typedef float f32x16 __attribute__((ext_vector_type(16)));

__device__ __forceinline__ u16 f2b(float f) {
  union { float f; unsigned u; } x; x.f = f;
  unsigned r = x.u + 0x7FFFu + ((x.u >> 16) & 1u);
  return (u16)(r >> 16);
}

__device__ __forceinline__ unsigned pkbf(float lo, float hi) {
  unsigned r;
  asm("v_cvt_pk_bf16_f32 %0, %1, %2" : "=v"(r) : "v"(lo), "v"(hi));
  return r;
}

__device__ __forceinline__ float expo2(float x) {
#if __has_builtin(__builtin_amdgcn_exp2f)
  return __builtin_amdgcn_exp2f(x);
#else
  return exp2f(x);
#endif
}

#define GLDS16(gp, lp)                                                         \
  __builtin_amdgcn_global_load_lds(                                            \
      (const __attribute__((address_space(1))) void*)(gp),                     \
      (__attribute__((address_space(3))) void*)(lp), 16, 0, 0)

// ---------------- transpose + cast: W[K][N] f32 -> WT[N][K] bf16 ------------
__global__ __launch_bounds__(256) void transpose_cast(
    const float* __restrict__ W, u16* __restrict__ WT, int K, int N) {
  __shared__ float tile[32][33];
  const int tx = threadIdx.x & 31, ty = threadIdx.x >> 5;
  const int n0 = blockIdx.x * 32, k0 = blockIdx.y * 32;
#pragma unroll
  for (int i = 0; i < 4; ++i)
    tile[ty + 8 * i][tx] = W[(size_t)(k0 + ty + 8 * i) * N + n0 + tx];
  __syncthreads();
#pragma unroll
  for (int i = 0; i < 4; ++i)
    WT[(size_t)(n0 + ty + 8 * i) * K + k0 + tx] = f2b(tile[tx][ty + 8 * i]);
}

// ---------------- cast f32 -> bf16 (4 elems/thread) -------------------------
__global__ __launch_bounds__(256) void cast_b(const float* __restrict__ x,
                                              u16* __restrict__ y) {
  int i = blockIdx.x * 256 + threadIdx.x;
  float4 v = ((const float4*)x)[i];
  ushort4 o;
  o.x = f2b(v.x); o.y = f2b(v.y); o.z = f2b(v.z); o.w = f2b(v.w);
  ((ushort4*)y)[i] = o;
}

// ---------------- GEMM: C = A[M,K] @ BT[N,K]^T, bf16 in, fused epilogues ----
// MODE 2: fp32 out = acc + bias + res   (Wo and W2 paths)
// MODE 3: bf16 out = relu(acc + bias)   (W1 path)
// MODE 5: fused QKV: col<1024 -> q-scaled head store; <2048 -> k head store;
//         else -> v transposed store. bias/bias2/bias3 = bq/bk/bv.
template <int MODE>
__global__ __launch_bounds__(256) void gemm128(
    const u16* __restrict__ A, const u16* __restrict__ BT,
    const float* __restrict__ bias, const float* __restrict__ bias2,
    const float* __restrict__ bias3, const float* __restrict__ res,
    void* __restrict__ outp, const float* __restrict__ kW, int N_, int K_) {
  __shared__ __align__(16) u16 As[128 * 32];
  __shared__ __align__(16) u16 Bs[128 * 32];
  const int t = threadIdx.x;
  const int lane = t & 63, wid = t >> 6;
  const int m0 = blockIdx.y * 128, n0 = blockIdx.x * 128;
  const int wr = (wid >> 1) * 64, wc = (wid & 1) * 64;
  const int lr = lane & 15, lg = lane >> 4;
  const int K = K_;

  f32x4 acc[4][4] = {};

  const u16* ga0 = A + (size_t)(m0 + (t >> 2)) * K + (t & 3) * 8;
  const u16* ga1 = ga0 + (size_t)64 * K;
  const u16* gb0 = BT + (size_t)(n0 + (t >> 2)) * K + (t & 3) * 8;
  const u16* gb1 = gb0 + (size_t)64 * K;
  char* lA = (char*)As + wid * 1024;
  char* lB = (char*)Bs + wid * 1024;

  const int nk = K >> 5;
  for (int kt = 0; kt < nk; ++kt) {
    __syncthreads();
    GLDS16(ga0, lA); GLDS16(ga1, lA + 4096);
    GLDS16(gb0, lB); GLDS16(gb1, lB + 4096);
    ga0 += 32; ga1 += 32; gb0 += 32; gb1 += 32;
    __syncthreads();
    bf16x8 af[4], bf[4];
#pragma unroll
    for (int i = 0; i < 4; ++i) {
      af[i] = *(const bf16x8*)((const char*)As + (wr + i * 16 + lr) * 64 + lg * 16);
      bf[i] = *(const bf16x8*)((const char*)Bs + (wc + i * 16 + lr) * 64 + lg * 16);
    }
#pragma unroll
    for (int mi = 0; mi < 4; ++mi)
#pragma unroll
      for (int ni = 0; ni < 4; ++ni)
        acc[mi][ni] = __builtin_amdgcn_mfma_f32_16x16x32_bf16(
            af[mi], bf[ni], acc[mi][ni], 0, 0, 0);
  }

#pragma unroll
  for (int mi = 0; mi < 4; ++mi) {
#pragma unroll
    for (int ni = 0; ni < 4; ++ni) {
      const int row = m0 + wr + mi * 16 + lg * 4;
      const int col = n0 + wc + ni * 16 + lr;
      f32x4 v = acc[mi][ni];
      if constexpr (MODE == 2) {
        const float bv = bias[col];
        float* o = (float*)outp;
#pragma unroll
        for (int r = 0; r < 4; ++r) {
          const int rr = row + r;
          o[(size_t)rr * N_ + col] = v[r] + bv + res[(size_t)rr * N_ + col];
        }
      } else if constexpr (MODE == 3) {
        const float bv = bias[col];
        u16* o = (u16*)outp;
#pragma unroll
        for (int r = 0; r < 4; ++r) {
          const int rr = row + r;
          float y = v[r] + bv;
          o[(size_t)rr * N_ + col] = f2b(y > 0.f ? y : 0.f);
        }
      } else {  // MODE 5
        const int proj = col >> 10, c = col & 1023;
        const int h = c >> 5, d = c & 31;
        u16* qout = (u16*)outp;
        if (proj == 0) {
          const float bv = bias[c];
          const float sc = kW[d * 32 + h] * 1.44269504089f;
#pragma unroll
          for (int r = 0; r < 4; ++r) {
            const int rr = row + r;
            const int bb = rr >> 11, s = rr & 2047;
            qout[(size_t)(((bb * 32 + h) * 2048) + s) * 32 + d] =
                f2b((v[r] + bv) * sc);
          }
        } else if (proj == 1) {
          const float bv = bias2[c];
          u16* kout = qout + 4194304;
#pragma unroll
          for (int r = 0; r < 4; ++r) {
            const int rr = row + r;
            const int bb = rr >> 11, s = rr & 2047;
            kout[(size_t)(((bb * 32 + h) * 2048) + s) * 32 + d] =
                f2b(v[r] + bv);
          }
        } else {
          const float bv = bias3[c];
          u16* vout = qout + 8388608;
          const int bb = row >> 11, s0 = row & 2047;
          ushort4 st;
          st.x = f2b(v[0] + bv); st.y = f2b(v[1] + bv);
          st.z = f2b(v[2] + bv); st.w = f2b(v[3] + bv);
          *(ushort4*)(vout + ((size_t)((bb * 32 + h) * 32 + d)) * 2048 + s0) = st;
        }
      }
    }
  }
}

// ---------------- attention tile compute (64 keys) --------------------------
__device__ __forceinline__ void attn_tile(
    const bf16x8& k0, const bf16x8& k1, const bf16x8& k2, const bf16x8& k3,
    const bf16x8& v0, const bf16x8& v1, const bf16x8& v2, const bf16x8& v3,
    const bf16x8& qb0, const bf16x8& qb1,
    f32x16& acc, float& la, float& lb, float& lc, float& ld) {
  const f32x16 z16 = {};
  f32x16 s0 = __builtin_amdgcn_mfma_f32_32x32x16_bf16(k0, qb0, z16, 0, 0, 0);
  s0 = __builtin_amdgcn_mfma_f32_32x32x16_bf16(k1, qb1, s0, 0, 0, 0);
  f32x16 s1 = __builtin_amdgcn_mfma_f32_32x32x16_bf16(k2, qb0, z16, 0, 0, 0);
  s1 = __builtin_amdgcn_mfma_f32_32x32x16_bf16(k3, qb1, s1, 0, 0, 0);
  float p0[16], p1[16];
#pragma unroll
  for (int r = 0; r < 16; ++r) p0[r] = expo2(s0[r]);
#pragma unroll
  for (int r = 0; r < 16; ++r) p1[r] = expo2(s1[r]);
#pragma unroll
  for (int r = 0; r < 4; ++r) {
    la += p0[r] + p1[r];
    lb += p0[4 + r] + p1[4 + r];
    lc += p0[8 + r] + p1[8 + r];
    ld += p0[12 + r] + p1[12 + r];
  }
  // pack + PV, interleaved per 16-key group. permlane32_swap: vdst_HI <->
  // vsrc_LO with vdst = low-key word.
  {
    u32 x0 = pkbf(p0[0], p0[1]), x1 = pkbf(p0[2], p0[3]);
    u32 y0 = pkbf(p0[4], p0[5]), y1 = pkbf(p0[6], p0[7]);
    asm("v_permlane32_swap_b32 %0, %1" : "+v"(x0), "+v"(y0));
    asm("v_permlane32_swap_b32 %0, %1" : "+v"(x1), "+v"(y1));
    union { u32 d[4]; bf16x8 v; } u;
    u.d[0] = x0; u.d[1] = x1; u.d[2] = y0; u.d[3] = y1;
    acc = __builtin_amdgcn_mfma_f32_32x32x16_bf16(v0, u.v, acc, 0, 0, 0);
  }
  {
    u32 x0 = pkbf(p0[8], p0[9]), x1 = pkbf(p0[10], p0[11]);
    u32 y0 = pkbf(p0[12], p0[13]), y1 = pkbf(p0[14], p0[15]);
    asm("v_permlane32_swap_b32 %0, %1" : "+v"(x0), "+v"(y0));
    asm("v_permlane32_swap_b32 %0, %1" : "+v"(x1), "+v"(y1));
    union { u32 d[4]; bf16x8 v; } u;
    u.d[0] = x0; u.d[1] = x1; u.d[2] = y0; u.d[3] = y1;
    acc = __builtin_amdgcn_mfma_f32_32x32x16_bf16(v1, u.v, acc, 0, 0, 0);
  }
  {
    u32 x0 = pkbf(p1[0], p1[1]), x1 = pkbf(p1[2], p1[3]);
    u32 y0 = pkbf(p1[4], p1[5]), y1 = pkbf(p1[6], p1[7]);
    asm("v_permlane32_swap_b32 %0, %1" : "+v"(x0), "+v"(y0));
    asm("v_permlane32_swap_b32 %0, %1" : "+v"(x1), "+v"(y1));
    union { u32 d[4]; bf16x8 v; } u;
    u.d[0] = x0; u.d[1] = x1; u.d[2] = y0; u.d[3] = y1;
    acc = __builtin_amdgcn_mfma_f32_32x32x16_bf16(v2, u.v, acc, 0, 0, 0);
  }
  {
    u32 x0 = pkbf(p1[8], p1[9]), x1 = pkbf(p1[10], p1[11]);
    u32 y0 = pkbf(p1[12], p1[13]), y1 = pkbf(p1[14], p1[15]);
    asm("v_permlane32_swap_b32 %0, %1" : "+v"(x0), "+v"(y0));
    asm("v_permlane32_swap_b32 %0, %1" : "+v"(x1), "+v"(y1));
    union { u32 d[4]; bf16x8 v; } u;
    u.d[0] = x0; u.d[1] = x1; u.d[2] = y0; u.d[3] = y1;
    acc = __builtin_amdgcn_mfma_f32_32x32x16_bf16(v3, u.v, acc, 0, 0, 0);
  }
}

#define LOADK(d0, d1, d2, d3, J)                                               \
  {                                                                            \
    const u16* kp_ = kbase + (size_t)(J) * 32;                                 \
    d0 = *(const bf16x8*)(kp_);                                                \
    d1 = *(const bf16x8*)(kp_ + 16);                                           \
    d2 = *(const bf16x8*)(kp_ + 1024);                                         \
    d3 = *(const bf16x8*)(kp_ + 1024 + 16);                                    \
  }
#define LOADV(d0, d1, d2, d3, J)                                               \
  {                                                                            \
    const u16* vp_ = vbase + (J);                                              \
    d0 = *(const bf16x8*)(vp_);                                                \
    d1 = *(const bf16x8*)(vp_ + 16);                                           \
    d2 = *(const bf16x8*)(vp_ + 32);                                           \
    d3 = *(const bf16x8*)(vp_ + 48);                                           \
  }

// ---------------- swapped 32x32 flash attention, split-K 2-way --------------
// Block = 4 waves: qg = wid&1 (32 queries each), kh = wid>>1 (1024 keys each).
// Scores pre-scaled by log2e (folded into q-proj). Unshifted exp2 softmax.
// Explicit 2-stage register double-buffer: loads for tile t+1 issued before
// compute of tile t (8x16B in flight under each tile's MFMA+exp2 work).
__global__ __launch_bounds__(256) void attn_kernel(
    const u16* __restrict__ Q, const u16* __restrict__ K,
    const u16* __restrict__ VT, u16* __restrict__ O) {
  __shared__ float sm_l[2][32];
  __shared__ float sm_acc[2][64][16];
  const int t = threadIdx.x, wid = t >> 6, lane = t & 63;
  const int qg = wid & 1, kh = wid >> 1;
  const int bid = blockIdx.x;
  const int swz = (bid & 7) * 256 + (bid >> 3);  // 2048 blocks, 8 XCDs
  const int bh = swz >> 5;                       // 0..63
  const int qt = swz & 31;                       // q-tile of 64
  const int q0 = qt * 64 + qg * 32;
  const int lq = lane & 31, hi = lane >> 5;
  const u16* Qh = Q + (size_t)bh * 2048 * 32;
  const u16* Kh = K + (size_t)bh * 2048 * 32;
  const u16* Vh = VT + (size_t)bh * 32 * 2048;

  const bf16x8 qb0 = *(const bf16x8*)(Qh + (size_t)(q0 + lq) * 32 + hi * 8);
  const bf16x8 qb1 = *(const bf16x8*)(Qh + (size_t)(q0 + lq) * 32 + 16 + hi * 8);

  const u16* kbase = Kh + (size_t)lq * 32 + hi * 8;
  const u16* vbase = Vh + (size_t)lq * 2048 + hi * 8;

  f32x16 acc = {};
  float la = 0.f, lb = 0.f, lc = 0.f, ld = 0.f;

  const int jb = kh * 1024;

  bf16x8 ka0, ka1, ka2, ka3, va0, va1, va2, va3;
  bf16x8 kb0, kb1, kb2, kb3, vb0, vb1, vb2, vb3;
  LOADK(ka0, ka1, ka2, ka3, jb);
  LOADV(va0, va1, va2, va3, jb);

  int j0 = jb;
#pragma unroll 1
  for (int pr = 0; pr < 8; ++pr) {
    LOADK(kb0, kb1, kb2, kb3, j0 + 64);
    LOADV(vb0, vb1, vb2, vb3, j0 + 64);
    attn_tile(ka0, ka1, ka2, ka3, va0, va1, va2, va3, qb0, qb1,
              acc, la, lb, lc, ld);
    LOADK(ka0, ka1, ka2, ka3, j0 + 128);  // last iter reads 4KB past je: safe
    LOADV(va0, va1, va2, va3, j0 + 128);  // (lands in adjacent ws region)
    attn_tile(kb0, kb1, kb2, kb3, vb0, vb1, vb2, vb3, qb0, qb1,
              acc, la, lb, lc, ld);
    j0 += 128;
  }

  float lrun = (la + lb) + (lc + ld);
  lrun += __shfl_xor(lrun, 32);

  // merge the two key-halves via LDS
  if (kh == 1) {
    sm_l[qg][lq] = lrun;
#pragma unroll
    for (int r = 0; r < 16; ++r) sm_acc[qg][lane][r] = acc[r];
  }
  __syncthreads();
  if (kh == 0) {
    const float inv = 1.f / (lrun + sm_l[qg][lq]);
    const int bb = bh >> 5, h = bh & 31;
    u16* o = O + (size_t)(bb * 2048 + q0 + lq) * 1024 + h * 32;
#pragma unroll
    for (int g = 0; g < 4; ++g) {
      ushort4 st;
      st.x = f2b((acc[g * 4 + 0] + sm_acc[qg][lane][g * 4 + 0]) * inv);
      st.y = f2b((acc[g * 4 + 1] + sm_acc[qg][lane][g * 4 + 1]) * inv);
      st.z = f2b((acc[g * 4 + 2] + sm_acc[qg][lane][g * 4 + 2]) * inv);
      st.w = f2b((acc[g * 4 + 3] + sm_acc[qg][lane][g * 4 + 3]) * inv);
      *(ushort4*)(o + g * 8 + hi * 4) = st;
    }
  }
}

// ---------------- LayerNorm (1 wave per row of 1024) ------------------------
template <int WB>
__global__ __launch_bounds__(256) void ln_kernel(
    const float* X, const float* __restrict__ g, const float* __restrict__ b,
    float* outf, u16* __restrict__ outb) {
  const int wid = threadIdx.x >> 6, lane = threadIdx.x & 63;
  const int row = blockIdx.x * 4 + wid;
  const float4* X4 = (const float4*)(X + (size_t)row * 1024);
  float4 xs[4];
  float s = 0.f, sq = 0.f;
#pragma unroll
  for (int i = 0; i < 4; ++i) {
    xs[i] = X4[lane + i * 64];
    s += xs[i].x + xs[i].y + xs[i].z + xs[i].w;
    sq += xs[i].x * xs[i].x + xs[i].y * xs[i].y + xs[i].z * xs[i].z + xs[i].w * xs[i].w;
  }
#pragma unroll
  for (int m = 1; m < 64; m <<= 1) { s += __shfl_xor(s, m); sq += __shfl_xor(sq, m); }
  const float mean = s * (1.f / 1024.f);
  float var = sq * (1.f / 1024.f) - mean * mean;
  var = var > 0.f ? var : 0.f;
  const float rstd = rsqrtf(var + 1e-5f);
  const float4* g4 = (const float4*)g;
  const float4* b4 = (const float4*)b;
  float4* of = (float4*)(outf + (size_t)row * 1024);
#pragma unroll
  for (int i = 0; i < 4; ++i) {
    const int c = lane + i * 64;
    const float4 gv = g4[c], bv = b4[c], x = xs[i];
    float4 y;
    y.x = (x.x - mean) * rstd * gv.x + bv.x;
    y.y = (x.y - mean) * rstd * gv.y + bv.y;
    y.z = (x.z - mean) * rstd * gv.z + bv.z;
    y.w = (x.w - mean) * rstd * gv.w + bv.w;
    of[c] = y;
    if constexpr (WB) {
      ushort4 yb;
      yb.x = f2b(y.x); yb.y = f2b(y.y); yb.z = f2b(y.z); yb.w = f2b(y.w);
      ((ushort4*)(outb + (size_t)row * 1024))[c] = yb;
    }
  }
}

// ---------------------------------------------------------------------------
extern "C" void kernel_launch(void* const* d_in, const int* in_sizes, int n_in,
                              void* d_out, int out_size, void* d_ws,
                              size_t ws_size, hipStream_t stream) {
  const float* x   = (const float*)d_in[0];
  const float* Wq  = (const float*)d_in[1];
  const float* bq  = (const float*)d_in[2];
  const float* Wk  = (const float*)d_in[3];
  const float* bk  = (const float*)d_in[4];
  const float* Wv  = (const float*)d_in[5];
  const float* bv  = (const float*)d_in[6];
  const float* kW  = (const float*)d_in[7];
  const float* Wo  = (const float*)d_in[8];
  const float* bo  = (const float*)d_in[9];
  const float* W1  = (const float*)d_in[10];
  const float* b1  = (const float*)d_in[11];
  const float* W2  = (const float*)d_in[12];
  const float* b2  = (const float*)d_in[13];
  const float* g1  = (const float*)d_in[14];
  const float* be1 = (const float*)d_in[15];
  const float* g2  = (const float*)d_in[16];
  const float* be2 = (const float*)d_in[17];

  char* ws = (char*)d_ws;
  const size_t MB = 1024 * 1024;
  u16*   WqT = (u16*)(ws + 0 * MB);   // [0,6) = fused QKV BT[3072][1024]
  u16*   WkT = (u16*)(ws + 2 * MB);
  u16*   WvT = (u16*)(ws + 4 * MB);
  u16*   WoT = (u16*)(ws + 6 * MB);
  u16*   W1T = (u16*)(ws + 8 * MB);
  u16*   W2T = (u16*)(ws + 16 * MB);
  float* r1  = (float*)(ws + 24 * MB);
  u16*   xb  = (u16*)(ws + 40 * MB);
  u16*   qhB = (u16*)(ws + 48 * MB);
  u16*   khB = (u16*)(ws + 56 * MB);
  u16*   vTB = (u16*)(ws + 64 * MB);
  u16*   hf  = (u16*)(ws + 40 * MB);  // aliases xb..vT, free by then
  u16*   ao  = (u16*)(ws + 72 * MB);
  u16*   x1b = (u16*)(ws + 80 * MB);
  float* r2  = (float*)(ws + 72 * MB);  // aliases ao+x1b, free by then

  const dim3 blk(256);

  transpose_cast<<<dim3(32, 32), blk, 0, stream>>>(Wq, WqT, 1024, 1024);
  transpose_cast<<<dim3(32, 32), blk, 0, stream>>>(Wk, WkT, 1024, 1024);
  transpose_cast<<<dim3(32, 32), blk, 0, stream>>>(Wv, WvT, 1024, 1024);
  transpose_cast<<<dim3(32, 32), blk, 0, stream>>>(Wo, WoT, 1024, 1024);
  transpose_cast<<<dim3(128, 32), blk, 0, stream>>>(W1, W1T, 1024, 4096);
  transpose_cast<<<dim3(32, 128), blk, 0, stream>>>(W2, W2T, 4096, 1024);
  cast_b<<<4096, blk, 0, stream>>>(x, xb);

  // fused QKV projection (q scaled by kernelW*log2e, v stored transposed)
  gemm128<5><<<dim3(24, 32), blk, 0, stream>>>(xb, WqT, bq, bk, bv, nullptr,
                                               qhB, kW, 3072, 1024);

  // flash attention: 2048 blocks x 4 waves (2 qg x 2 key-halves)
  attn_kernel<<<2048, blk, 0, stream>>>(qhB, khB, vTB, ao);

  // out-proj + residual -> r1 (fp32)
  gemm128<2><<<dim3(8, 32), blk, 0, stream>>>(ao, WoT, bo, nullptr, nullptr, x,
                                              r1, nullptr, 1024, 1024);
  ln_kernel<1><<<1024, blk, 0, stream>>>(r1, g1, be1, r1, x1b);
  // FFN
  gemm128<3><<<dim3(32, 32), blk, 0, stream>>>(x1b, W1T, b1, nullptr, nullptr,
                                               nullptr, hf, nullptr, 4096, 1024);
  gemm128<2><<<dim3(8, 32), blk, 0, stream>>>(hf, W2T, b2, nullptr, nullptr, r1,
                                              r2, nullptr, 1024, 4096);
  ln_kernel<0><<<1024, blk, 0, stream>>>(r2, g2, be2, (float*)d_out, nullptr);

  (void)in_sizes; (void)n_in; (void)out_size; (void)ws_size;
}

// Round 8
// 309.436 us; speedup vs baseline: 1.1627x; 1.1339x over previous
//
#include <hip/hip_runtime.h>

// ---------------------------------------------------------------------------
// TransformerBlockQuantum: B=2,S=2048,E=1024,H=32,DK=32,FFN=4096
// GEMMs: bf16 MFMA 16x16x32, LDS double-buffer, single-barrier K-loop
// (stage t+1 issued before compute of t). BN=64 variant for N=1024 GEMMs.
// Attention: round-6 exact (swapped 32x32 QK^T, unshifted exp2 softmax,
// permlane32_swap P-pack, split-K 2-way, LINEAR V^T layout).
// ws layout (MB):
//  [0,2)WqT [2,4)WkT [4,6)WvT  (contiguous => fused QKV BT[3072][1024])
//  [6,8)WoT [8,16)W1T [16,24)W2T
//  [24,40) r1 (fp32 residual1 / post-LN1 fp32)
//  [40,48) xb  | [48,56) qh | [56,64) kh | [64,72) vT   <- hf aliases [40,72)
//  [72,80) ao  | [80,88) x1b                             <- r2 aliases [72,88)
// ---------------------------------------------------------------------------

typedef unsigned short u16;
typedef unsigned int u32;
typedef __bf16 bf16x8 __attribute__((ext_vector_type(8)));
typedef float f32x4 __attribute__((ext_vector_type(4)));
typedef float f32x16 __attribute__((ext_vector_type(16)));

__device__ __forceinline__ u16 f2b(float f) {
  union { float f; unsigned u; } x; x.f = f;
  unsigned r = x.u + 0x7FFFu + ((x.u >> 16) & 1u);
  return (u16)(r >> 16);
}

__device__ __forceinline__ unsigned pkbf(float lo, float hi) {
  unsigned r;
  asm("v_cvt_pk_bf16_f32 %0, %1, %2" : "=v"(r) : "v"(lo), "v"(hi));
  return r;
}

__device__ __forceinline__ float expo2(float x) {
#if __has_builtin(__builtin_amdgcn_exp2f)
  return __builtin_amdgcn_exp2f(x);
#else
  return exp2f(x);
#endif
}

#define GLDS16(gp, lp)                                                         \
  __builtin_amdgcn_global_load_lds(                                            \
      (const __attribute__((address_space(1))) void*)(gp),                     \
      (__attribute__((address_space(3))) void*)(lp), 16, 0, 0)

// ---------------- transpose + cast: W[K][N] f32 -> WT[N][K] bf16 ------------
__global__ __launch_bounds__(256) void transpose_cast(
    const float* __restrict__ W, u16* __restrict__ WT, int K, int N) {
  __shared__ float tile[32][33];
  const int tx = threadIdx.x & 31, ty = threadIdx.x >> 5;
  const int n0 = blockIdx.x * 32, k0 = blockIdx.y * 32;
#pragma unroll
  for (int i = 0; i < 4; ++i)
    tile[ty + 8 * i][tx] = W[(size_t)(k0 + ty + 8 * i) * N + n0 + tx];
  __syncthreads();
#pragma unroll
  for (int i = 0; i < 4; ++i)
    WT[(size_t)(n0 + ty + 8 * i) * K + k0 + tx] = f2b(tile[tx][ty + 8 * i]);
}

// ---------------- cast f32 -> bf16 (4 elems/thread) -------------------------
__global__ __launch_bounds__(256) void cast_b(const float* __restrict__ x,
                                              u16* __restrict__ y) {
  int i = blockIdx.x * 256 + threadIdx.x;
  float4 v = ((const float4*)x)[i];
  ushort4 o;
  o.x = f2b(v.x); o.y = f2b(v.y); o.z = f2b(v.z); o.w = f2b(v.w);
  ((ushort4*)y)[i] = o;
}

// ---------------- GEMM: C = A[M,K] @ BT[N,K]^T, bf16, dbuf 1-barrier loop ---
// MODE 2: fp32 out = acc + bias + res   (Wo and W2 paths)
// MODE 3: bf16 out = relu(acc + bias)   (W1 path)
// MODE 5: fused QKV: col<1024 -> q-scaled head store; <2048 -> k head store;
//         else -> v transposed store (LINEAR layout).
template <int MODE, int BN>
__global__ __launch_bounds__(256) void gemmT(
    const u16* __restrict__ A, const u16* __restrict__ BT,
    const float* __restrict__ bias, const float* __restrict__ bias2,
    const float* __restrict__ bias3, const float* __restrict__ res,
    void* __restrict__ outp, const float* __restrict__ kW, int N_, int K_) {
  constexpr int ABYT = 128 * 32 * 2;        // 8 KB A tile
  constexpr int BBYT = BN * 32 * 2;         // 8/4 KB B tile
  constexpr int STRIDE = ABYT + BBYT;
  constexpr int MI = (BN == 128) ? 4 : 2;
  __shared__ __align__(16) char SH[2 * STRIDE];
  const int t = threadIdx.x, lane = t & 63, wid = t >> 6;
  const int m0 = blockIdx.y * 128, n0 = blockIdx.x * BN;
  const int wr = (BN == 128) ? (wid >> 1) * 64 : wid * 32;
  const int wc = (BN == 128) ? (wid & 1) * 64 : 0;
  const int lr = lane & 15, lg = lane >> 4;
  const int K = K_;

  f32x4 acc[MI][4] = {};

  const u16* ga0 = A + (size_t)(m0 + (t >> 2)) * K + (t & 3) * 8;
  const u16* ga1 = ga0 + (size_t)64 * K;
  const u16* gb0 = BT + (size_t)(n0 + (t >> 2)) * K + (t & 3) * 8;
  const u16* gb1 = gb0 + (size_t)64 * K;  // only used when BN==128
  const int stA = wid * 1024;

#define STAGE(CUR, KT)                                                         \
  {                                                                            \
    char* l_ = (char*)SH + (CUR) * STRIDE + stA;                               \
    const size_t o_ = (size_t)(KT) * 32;                                       \
    GLDS16(ga0 + o_, l_);                                                      \
    GLDS16(ga1 + o_, l_ + 4096);                                               \
    GLDS16(gb0 + o_, l_ + ABYT);                                               \
    if constexpr (BN == 128) GLDS16(gb1 + o_, l_ + ABYT + 4096);               \
  }

  const int nk = K >> 5;
  STAGE(0, 0);
  __syncthreads();
  int cur = 0;
  for (int kt = 0; kt < nk; ++kt) {
    if (kt + 1 < nk) STAGE(cur ^ 1, kt + 1);
    const char* l = (const char*)SH + cur * STRIDE;
    bf16x8 af[MI], bf[4];
#pragma unroll
    for (int i = 0; i < MI; ++i)
      af[i] = *(const bf16x8*)(l + (wr + i * 16 + lr) * 64 + lg * 16);
#pragma unroll
    for (int i = 0; i < 4; ++i)
      bf[i] = *(const bf16x8*)(l + ABYT + (wc + i * 16 + lr) * 64 + lg * 16);
#pragma unroll
    for (int mi = 0; mi < MI; ++mi)
#pragma unroll
      for (int ni = 0; ni < 4; ++ni)
        acc[mi][ni] = __builtin_amdgcn_mfma_f32_16x16x32_bf16(
            af[mi], bf[ni], acc[mi][ni], 0, 0, 0);
    __syncthreads();
    cur ^= 1;
  }
#undef STAGE

#pragma unroll
  for (int mi = 0; mi < MI; ++mi) {
#pragma unroll
    for (int ni = 0; ni < 4; ++ni) {
      const int row = m0 + wr + mi * 16 + lg * 4;
      const int col = n0 + wc + ni * 16 + lr;
      f32x4 v = acc[mi][ni];
      if constexpr (MODE == 2) {
        const float bv = bias[col];
        float* o = (float*)outp;
#pragma unroll
        for (int r = 0; r < 4; ++r) {
          const int rr = row + r;
          o[(size_t)rr * N_ + col] = v[r] + bv + res[(size_t)rr * N_ + col];
        }
      } else if constexpr (MODE == 3) {
        const float bv = bias[col];
        u16* o = (u16*)outp;
#pragma unroll
        for (int r = 0; r < 4; ++r) {
          const int rr = row + r;
          float y = v[r] + bv;
          o[(size_t)rr * N_ + col] = f2b(y > 0.f ? y : 0.f);
        }
      } else {  // MODE 5
        const int proj = col >> 10, c = col & 1023;
        const int h = c >> 5, d = c & 31;
        u16* qout = (u16*)outp;
        if (proj == 0) {
          const float bv = bias[c];
          const float sc = kW[d * 32 + h] * 1.44269504089f;
#pragma unroll
          for (int r = 0; r < 4; ++r) {
            const int rr = row + r;
            const int bb = rr >> 11, s = rr & 2047;
            qout[(size_t)(((bb * 32 + h) * 2048) + s) * 32 + d] =
                f2b((v[r] + bv) * sc);
          }
        } else if (proj == 1) {
          const float bv = bias2[c];
          u16* kout = qout + 4194304;
#pragma unroll
          for (int r = 0; r < 4; ++r) {
            const int rr = row + r;
            const int bb = rr >> 11, s = rr & 2047;
            kout[(size_t)(((bb * 32 + h) * 2048) + s) * 32 + d] =
                f2b(v[r] + bv);
          }
        } else {
          const float bv = bias3[c];
          u16* vout = qout + 8388608;
          const int bb = row >> 11, s0 = row & 2047;
          ushort4 st;
          st.x = f2b(v[0] + bv); st.y = f2b(v[1] + bv);
          st.z = f2b(v[2] + bv); st.w = f2b(v[3] + bv);
          *(ushort4*)(vout + ((size_t)((bb * 32 + h) * 32 + d)) * 2048 + s0) = st;
        }
      }
    }
  }
}

// ---------------- attention tile compute (64 keys) --------------------------
__device__ __forceinline__ void attn_tile(
    const bf16x8& k0, const bf16x8& k1, const bf16x8& k2, const bf16x8& k3,
    const bf16x8& v0, const bf16x8& v1, const bf16x8& v2, const bf16x8& v3,
    const bf16x8& qb0, const bf16x8& qb1,
    f32x16& acc, float& la, float& lb, float& lc, float& ld) {
  const f32x16 z16 = {};
  f32x16 s0 = __builtin_amdgcn_mfma_f32_32x32x16_bf16(k0, qb0, z16, 0, 0, 0);
  s0 = __builtin_amdgcn_mfma_f32_32x32x16_bf16(k1, qb1, s0, 0, 0, 0);
  f32x16 s1 = __builtin_amdgcn_mfma_f32_32x32x16_bf16(k2, qb0, z16, 0, 0, 0);
  s1 = __builtin_amdgcn_mfma_f32_32x32x16_bf16(k3, qb1, s1, 0, 0, 0);
  float p0[16], p1[16];
#pragma unroll
  for (int r = 0; r < 16; ++r) p0[r] = expo2(s0[r]);
#pragma unroll
  for (int r = 0; r < 16; ++r) p1[r] = expo2(s1[r]);
#pragma unroll
  for (int r = 0; r < 4; ++r) {
    la += p0[r] + p1[r];
    lb += p0[4 + r] + p1[4 + r];
    lc += p0[8 + r] + p1[8 + r];
    ld += p0[12 + r] + p1[12 + r];
  }
  {
    u32 x0 = pkbf(p0[0], p0[1]), x1 = pkbf(p0[2], p0[3]);
    u32 y0 = pkbf(p0[4], p0[5]), y1 = pkbf(p0[6], p0[7]);
    asm("v_permlane32_swap_b32 %0, %1" : "+v"(x0), "+v"(y0));
    asm("v_permlane32_swap_b32 %0, %1" : "+v"(x1), "+v"(y1));
    union { u32 d[4]; bf16x8 v; } u;
    u.d[0] = x0; u.d[1] = x1; u.d[2] = y0; u.d[3] = y1;
    acc = __builtin_amdgcn_mfma_f32_32x32x16_bf16(v0, u.v, acc, 0, 0, 0);
  }
  {
    u32 x0 = pkbf(p0[8], p0[9]), x1 = pkbf(p0[10], p0[11]);
    u32 y0 = pkbf(p0[12], p0[13]), y1 = pkbf(p0[14], p0[15]);
    asm("v_permlane32_swap_b32 %0, %1" : "+v"(x0), "+v"(y0));
    asm("v_permlane32_swap_b32 %0, %1" : "+v"(x1), "+v"(y1));
    union { u32 d[4]; bf16x8 v; } u;
    u.d[0] = x0; u.d[1] = x1; u.d[2] = y0; u.d[3] = y1;
    acc = __builtin_amdgcn_mfma_f32_32x32x16_bf16(v1, u.v, acc, 0, 0, 0);
  }
  {
    u32 x0 = pkbf(p1[0], p1[1]), x1 = pkbf(p1[2], p1[3]);
    u32 y0 = pkbf(p1[4], p1[5]), y1 = pkbf(p1[6], p1[7]);
    asm("v_permlane32_swap_b32 %0, %1" : "+v"(x0), "+v"(y0));
    asm("v_permlane32_swap_b32 %0, %1" : "+v"(x1), "+v"(y1));
    union { u32 d[4]; bf16x8 v; } u;
    u.d[0] = x0; u.d[1] = x1; u.d[2] = y0; u.d[3] = y1;
    acc = __builtin_amdgcn_mfma_f32_32x32x16_bf16(v2, u.v, acc, 0, 0, 0);
  }
  {
    u32 x0 = pkbf(p1[8], p1[9]), x1 = pkbf(p1[10], p1[11]);
    u32 y0 = pkbf(p1[12], p1[13]), y1 = pkbf(p1[14], p1[15]);
    asm("v_permlane32_swap_b32 %0, %1" : "+v"(x0), "+v"(y0));
    asm("v_permlane32_swap_b32 %0, %1" : "+v"(x1), "+v"(y1));
    union { u32 d[4]; bf16x8 v; } u;
    u.d[0] = x0; u.d[1] = x1; u.d[2] = y0; u.d[3] = y1;
    acc = __builtin_amdgcn_mfma_f32_32x32x16_bf16(v3, u.v, acc, 0, 0, 0);
  }
}

#define LOADK(d0, d1, d2, d3, J)                                               \
  {                                                                            \
    const u16* kp_ = kbase + (size_t)(J) * 32;                                 \
    d0 = *(const bf16x8*)(kp_);                                                \
    d1 = *(const bf16x8*)(kp_ + 16);                                           \
    d2 = *(const bf16x8*)(kp_ + 1024);                                         \
    d3 = *(const bf16x8*)(kp_ + 1024 + 16);                                    \
  }
#define LOADV(d0, d1, d2, d3, J)                                               \
  {                                                                            \
    const u16* vp_ = vbase + (J);                                              \
    d0 = *(const bf16x8*)(vp_);                                                \
    d1 = *(const bf16x8*)(vp_ + 16);                                           \
    d2 = *(const bf16x8*)(vp_ + 32);                                           \
    d3 = *(const bf16x8*)(vp_ + 48);                                           \
  }

// ---------------- swapped 32x32 flash attention, split-K 2-way --------------
__global__ __launch_bounds__(256) void attn_kernel(
    const u16* __restrict__ Q, const u16* __restrict__ K,
    const u16* __restrict__ VT, u16* __restrict__ O) {
  __shared__ float sm_l[2][32];
  __shared__ float sm_acc[2][64][16];
  const int t = threadIdx.x, wid = t >> 6, lane = t & 63;
  const int qg = wid & 1, kh = wid >> 1;
  const int bid = blockIdx.x;
  const int swz = (bid & 7) * 256 + (bid >> 3);  // 2048 blocks, 8 XCDs
  const int bh = swz >> 5;                       // 0..63
  const int qt = swz & 31;                       // q-tile of 64
  const int q0 = qt * 64 + qg * 32;
  const int lq = lane & 31, hi = lane >> 5;
  const u16* Qh = Q + (size_t)bh * 2048 * 32;
  const u16* Kh = K + (size_t)bh * 2048 * 32;
  const u16* Vh = VT + (size_t)bh * 32 * 2048;

  const bf16x8 qb0 = *(const bf16x8*)(Qh + (size_t)(q0 + lq) * 32 + hi * 8);
  const bf16x8 qb1 = *(const bf16x8*)(Qh + (size_t)(q0 + lq) * 32 + 16 + hi * 8);

  const u16* kbase = Kh + (size_t)lq * 32 + hi * 8;
  const u16* vbase = Vh + (size_t)lq * 2048 + hi * 8;

  f32x16 acc = {};
  float la = 0.f, lb = 0.f, lc = 0.f, ld = 0.f;

  const int jb = kh * 1024;

  bf16x8 ka0, ka1, ka2, ka3, va0, va1, va2, va3;
  bf16x8 kb0, kb1, kb2, kb3, vb0, vb1, vb2, vb3;
  LOADK(ka0, ka1, ka2, ka3, jb);
  LOADV(va0, va1, va2, va3, jb);

  int j0 = jb;
#pragma unroll 1
  for (int pr = 0; pr < 8; ++pr) {
    LOADK(kb0, kb1, kb2, kb3, j0 + 64);
    LOADV(vb0, vb1, vb2, vb3, j0 + 64);
    attn_tile(ka0, ka1, ka2, ka3, va0, va1, va2, va3, qb0, qb1,
              acc, la, lb, lc, ld);
    LOADK(ka0, ka1, ka2, ka3, j0 + 128);  // last iter overreads 4KB: lands in
    LOADV(va0, va1, va2, va3, j0 + 128);  // adjacent ws regions, discarded
    attn_tile(kb0, kb1, kb2, kb3, vb0, vb1, vb2, vb3, qb0, qb1,
              acc, la, lb, lc, ld);
    j0 += 128;
  }

  float lrun = (la + lb) + (lc + ld);
  lrun += __shfl_xor(lrun, 32);

  if (kh == 1) {
    sm_l[qg][lq] = lrun;
#pragma unroll
    for (int r = 0; r < 16; ++r) sm_acc[qg][lane][r] = acc[r];
  }
  __syncthreads();
  if (kh == 0) {
    const float inv = 1.f / (lrun + sm_l[qg][lq]);
    const int bb = bh >> 5, h = bh & 31;
    u16* o = O + (size_t)(bb * 2048 + q0 + lq) * 1024 + h * 32;
#pragma unroll
    for (int g = 0; g < 4; ++g) {
      ushort4 st;
      st.x = f2b((acc[g * 4 + 0] + sm_acc[qg][lane][g * 4 + 0]) * inv);
      st.y = f2b((acc[g * 4 + 1] + sm_acc[qg][lane][g * 4 + 1]) * inv);
      st.z = f2b((acc[g * 4 + 2] + sm_acc[qg][lane][g * 4 + 2]) * inv);
      st.w = f2b((acc[g * 4 + 3] + sm_acc[qg][lane][g * 4 + 3]) * inv);
      *(ushort4*)(o + g * 8 + hi * 4) = st;
    }
  }
}

// ---------------- LayerNorm (1 wave per row of 1024) ------------------------
template <int WB>
__global__ __launch_bounds__(256) void ln_kernel(
    const float* X, const float* __restrict__ g, const float* __restrict__ b,
    float* outf, u16* __restrict__ outb) {
  const int wid = threadIdx.x >> 6, lane = threadIdx.x & 63;
  const int row = blockIdx.x * 4 + wid;
  const float4* X4 = (const float4*)(X + (size_t)row * 1024);
  float4 xs[4];
  float s = 0.f, sq = 0.f;
#pragma unroll
  for (int i = 0; i < 4; ++i) {
    xs[i] = X4[lane + i * 64];
    s += xs[i].x + xs[i].y + xs[i].z + xs[i].w;
    sq += xs[i].x * xs[i].x + xs[i].y * xs[i].y + xs[i].z * xs[i].z + xs[i].w * xs[i].w;
  }
#pragma unroll
  for (int m = 1; m < 64; m <<= 1) { s += __shfl_xor(s, m); sq += __shfl_xor(sq, m); }
  const float mean = s * (1.f / 1024.f);
  float var = sq * (1.f / 1024.f) - mean * mean;
  var = var > 0.f ? var : 0.f;
  const float rstd = rsqrtf(var + 1e-5f);
  const float4* g4 = (const float4*)g;
  const float4* b4 = (const float4*)b;
  float4* of = (float4*)(outf + (size_t)row * 1024);
#pragma unroll
  for (int i = 0; i < 4; ++i) {
    const int c = lane + i * 64;
    const float4 gv = g4[c], bv = b4[c], x = xs[i];
    float4 y;
    y.x = (x.x - mean) * rstd * gv.x + bv.x;
    y.y = (x.y - mean) * rstd * gv.y + bv.y;
    y.z = (x.z - mean) * rstd * gv.z + bv.z;
    y.w = (x.w - mean) * rstd * gv.w + bv.w;
    of[c] = y;
    if constexpr (WB) {
      ushort4 yb;
      yb.x = f2b(y.x); yb.y = f2b(y.y); yb.z = f2b(y.z); yb.w = f2b(y.w);
      ((ushort4*)(outb + (size_t)row * 1024))[c] = yb;
    }
  }
}

// ---------------------------------------------------------------------------
extern "C" void kernel_launch(void* const* d_in, const int* in_sizes, int n_in,
                              void* d_out, int out_size, void* d_ws,
                              size_t ws_size, hipStream_t stream) {
  const float* x   = (const float*)d_in[0];
  const float* Wq  = (const float*)d_in[1];
  const float* bq  = (const float*)d_in[2];
  const float* Wk  = (const float*)d_in[3];
  const float* bk  = (const float*)d_in[4];
  const float* Wv  = (const float*)d_in[5];
  const float* bv  = (const float*)d_in[6];
  const float* kW  = (const float*)d_in[7];
  const float* Wo  = (const float*)d_in[8];
  const float* bo  = (const float*)d_in[9];
  const float* W1  = (const float*)d_in[10];
  const float* b1  = (const float*)d_in[11];
  const float* W2  = (const float*)d_in[12];
  const float* b2  = (const float*)d_in[13];
  const float* g1  = (const float*)d_in[14];
  const float* be1 = (const float*)d_in[15];
  const float* g2  = (const float*)d_in[16];
  const float* be2 = (const float*)d_in[17];

  char* ws = (char*)d_ws;
  const size_t MB = 1024 * 1024;
  u16*   WqT = (u16*)(ws + 0 * MB);   // [0,6) = fused QKV BT[3072][1024]
  u16*   WkT = (u16*)(ws + 2 * MB);
  u16*   WvT = (u16*)(ws + 4 * MB);
  u16*   WoT = (u16*)(ws + 6 * MB);
  u16*   W1T = (u16*)(ws + 8 * MB);
  u16*   W2T = (u16*)(ws + 16 * MB);
  float* r1  = (float*)(ws + 24 * MB);
  u16*   xb  = (u16*)(ws + 40 * MB);
  u16*   qhB = (u16*)(ws + 48 * MB);
  u16*   khB = (u16*)(ws + 56 * MB);
  u16*   vTB = (u16*)(ws + 64 * MB);
  u16*   hf  = (u16*)(ws + 40 * MB);  // aliases xb..vT, free by then
  u16*   ao  = (u16*)(ws + 72 * MB);
  u16*   x1b = (u16*)(ws + 80 * MB);
  float* r2  = (float*)(ws + 72 * MB);  // aliases ao+x1b, free by then

  const dim3 blk(256);

  transpose_cast<<<dim3(32, 32), blk, 0, stream>>>(Wq, WqT, 1024, 1024);
  transpose_cast<<<dim3(32, 32), blk, 0, stream>>>(Wk, WkT, 1024, 1024);
  transpose_cast<<<dim3(32, 32), blk, 0, stream>>>(Wv, WvT, 1024, 1024);
  transpose_cast<<<dim3(32, 32), blk, 0, stream>>>(Wo, WoT, 1024, 1024);
  transpose_cast<<<dim3(128, 32), blk, 0, stream>>>(W1, W1T, 1024, 4096);
  transpose_cast<<<dim3(32, 128), blk, 0, stream>>>(W2, W2T, 4096, 1024);
  cast_b<<<4096, blk, 0, stream>>>(x, xb);

  // fused QKV projection (q scaled by kernelW*log2e, v stored transposed)
  gemmT<5, 128><<<dim3(24, 32), blk, 0, stream>>>(
      xb, WqT, bq, bk, bv, nullptr, qhB, kW, 3072, 1024);

  // flash attention: 2048 blocks x 4 waves (2 qg x 2 key-halves)
  attn_kernel<<<2048, blk, 0, stream>>>(qhB, khB, vTB, ao);

  // out-proj + residual -> r1 (fp32); BN=64 -> 512 blocks
  gemmT<2, 64><<<dim3(16, 32), blk, 0, stream>>>(
      ao, WoT, bo, nullptr, nullptr, x, r1, nullptr, 1024, 1024);
  ln_kernel<1><<<1024, blk, 0, stream>>>(r1, g1, be1, r1, x1b);
  // FFN
  gemmT<3, 128><<<dim3(32, 32), blk, 0, stream>>>(
      x1b, W1T, b1, nullptr, nullptr, nullptr, hf, nullptr, 4096, 1024);
  gemmT<2, 64><<<dim3(16, 32), blk, 0, stream>>>(
      hf, W2T, b2, nullptr, nullptr, r1, r2, nullptr, 1024, 4096);
  ln_kernel<0><<<1024, blk, 0, stream>>>(r2, g2, be2, (float*)d_out, nullptr);

  (void)in_sizes; (void)n_in; (void)out_size; (void)ws_size;
}

// Round 9
// 304.631 us; speedup vs baseline: 1.1810x; 1.0158x over previous
//
#include <hip/hip_runtime.h>

// ---------------------------------------------------------------------------
// TransformerBlockQuantum: B=2,S=2048,E=1024,H=32,DK=32,FFN=4096
// GEMMs: bf16 MFMA 16x16x32, LDS double-buffer, single-barrier K-loop.
// BN=64 variant for N=1024 GEMMs.
// Attention: swapped 32x32 QK^T, unshifted exp2 softmax, permlane32_swap
// P-pack, split-K 2-way. V^T stored CHANNEL-TILED: elem (d,s) at
// (s>>6)*2048 + d*64 + (s&63)  [per head]. Lane d reads at 128B stride ->
// 16 L2 channels (was 4096B stride -> 1 channel, 32-way serialized).
// ws layout (MB):
//  [0,2)WqT [2,4)WkT [4,6)WvT  (contiguous => fused QKV BT[3072][1024])
//  [6,8)WoT [8,16)W1T [16,24)W2T
//  [24,40) r1 (fp32 residual1 / post-LN1 fp32)
//  [40,48) xb  | [48,56) qh | [56,64) kh | [64,72) vT   <- hf aliases [40,72)
//  [72,80) ao  | [80,88) x1b                             <- r2 aliases [72,88)
// ---------------------------------------------------------------------------

typedef unsigned short u16;
typedef unsigned int u32;
typedef __bf16 bf16x8 __attribute__((ext_vector_type(8)));
typedef float f32x4 __attribute__((ext_vector_type(4)));
typedef float f32x16 __attribute__((ext_vector_type(16)));

__device__ __forceinline__ u16 f2b(float f) {
  union { float f; unsigned u; } x; x.f = f;
  unsigned r = x.u + 0x7FFFu + ((x.u >> 16) & 1u);
  return (u16)(r >> 16);
}

__device__ __forceinline__ unsigned pkbf(float lo, float hi) {
  unsigned r;
  asm("v_cvt_pk_bf16_f32 %0, %1, %2" : "=v"(r) : "v"(lo), "v"(hi));
  return r;
}

__device__ __forceinline__ float expo2(float x) {
#if __has_builtin(__builtin_amdgcn_exp2f)
  return __builtin_amdgcn_exp2f(x);
#else
  return exp2f(x);
#endif
}

#define GLDS16(gp, lp)                                                         \
  __builtin_amdgcn_global_load_lds(                                            \
      (const __attribute__((address_space(1))) void*)(gp),                     \
      (__attribute__((address_space(3))) void*)(lp), 16, 0, 0)

// ---------------- transpose + cast: W[K][N] f32 -> WT[N][K] bf16 ------------
__global__ __launch_bounds__(256) void transpose_cast(
    const float* __restrict__ W, u16* __restrict__ WT, int K, int N) {
  __shared__ float tile[32][33];
  const int tx = threadIdx.x & 31, ty = threadIdx.x >> 5;
  const int n0 = blockIdx.x * 32, k0 = blockIdx.y * 32;
#pragma unroll
  for (int i = 0; i < 4; ++i)
    tile[ty + 8 * i][tx] = W[(size_t)(k0 + ty + 8 * i) * N + n0 + tx];
  __syncthreads();
#pragma unroll
  for (int i = 0; i < 4; ++i)
    WT[(size_t)(n0 + ty + 8 * i) * K + k0 + tx] = f2b(tile[tx][ty + 8 * i]);
}

// ---------------- cast f32 -> bf16 (4 elems/thread) -------------------------
__global__ __launch_bounds__(256) void cast_b(const float* __restrict__ x,
                                              u16* __restrict__ y) {
  int i = blockIdx.x * 256 + threadIdx.x;
  float4 v = ((const float4*)x)[i];
  ushort4 o;
  o.x = f2b(v.x); o.y = f2b(v.y); o.z = f2b(v.z); o.w = f2b(v.w);
  ((ushort4*)y)[i] = o;
}

// ---------------- GEMM: C = A[M,K] @ BT[N,K]^T, bf16, dbuf 1-barrier loop ---
// MODE 2: fp32 out = acc + bias + res   (Wo and W2 paths)
// MODE 3: bf16 out = relu(acc + bias)   (W1 path)
// MODE 5: fused QKV: col<1024 -> q-scaled head store; <2048 -> k head store;
//         else -> v channel-tiled transposed store.
template <int MODE, int BN>
__global__ __launch_bounds__(256) void gemmT(
    const u16* __restrict__ A, const u16* __restrict__ BT,
    const float* __restrict__ bias, const float* __restrict__ bias2,
    const float* __restrict__ bias3, const float* __restrict__ res,
    void* __restrict__ outp, const float* __restrict__ kW, int N_, int K_) {
  constexpr int ABYT = 128 * 32 * 2;        // 8 KB A tile
  constexpr int BBYT = BN * 32 * 2;         // 8/4 KB B tile
  constexpr int STRIDE = ABYT + BBYT;
  constexpr int MI = (BN == 128) ? 4 : 2;
  __shared__ __align__(16) char SH[2 * STRIDE];
  const int t = threadIdx.x, lane = t & 63, wid = t >> 6;
  const int m0 = blockIdx.y * 128, n0 = blockIdx.x * BN;
  const int wr = (BN == 128) ? (wid >> 1) * 64 : wid * 32;
  const int wc = (BN == 128) ? (wid & 1) * 64 : 0;
  const int lr = lane & 15, lg = lane >> 4;
  const int K = K_;

  f32x4 acc[MI][4] = {};

  const u16* ga0 = A + (size_t)(m0 + (t >> 2)) * K + (t & 3) * 8;
  const u16* ga1 = ga0 + (size_t)64 * K;
  const u16* gb0 = BT + (size_t)(n0 + (t >> 2)) * K + (t & 3) * 8;
  const u16* gb1 = gb0 + (size_t)64 * K;  // only used when BN==128
  const int stA = wid * 1024;

#define STAGE(CUR, KT)                                                         \
  {                                                                            \
    char* l_ = (char*)SH + (CUR) * STRIDE + stA;                               \
    const size_t o_ = (size_t)(KT) * 32;                                       \
    GLDS16(ga0 + o_, l_);                                                      \
    GLDS16(ga1 + o_, l_ + 4096);                                               \
    GLDS16(gb0 + o_, l_ + ABYT);                                               \
    if constexpr (BN == 128) GLDS16(gb1 + o_, l_ + ABYT + 4096);               \
  }

  const int nk = K >> 5;
  STAGE(0, 0);
  __syncthreads();
  int cur = 0;
  for (int kt = 0; kt < nk; ++kt) {
    if (kt + 1 < nk) STAGE(cur ^ 1, kt + 1);
    const char* l = (const char*)SH + cur * STRIDE;
    bf16x8 af[MI], bf[4];
#pragma unroll
    for (int i = 0; i < MI; ++i)
      af[i] = *(const bf16x8*)(l + (wr + i * 16 + lr) * 64 + lg * 16);
#pragma unroll
    for (int i = 0; i < 4; ++i)
      bf[i] = *(const bf16x8*)(l + ABYT + (wc + i * 16 + lr) * 64 + lg * 16);
#pragma unroll
    for (int mi = 0; mi < MI; ++mi)
#pragma unroll
      for (int ni = 0; ni < 4; ++ni)
        acc[mi][ni] = __builtin_amdgcn_mfma_f32_16x16x32_bf16(
            af[mi], bf[ni], acc[mi][ni], 0, 0, 0);
    __syncthreads();
    cur ^= 1;
  }
#undef STAGE

#pragma unroll
  for (int mi = 0; mi < MI; ++mi) {
#pragma unroll
    for (int ni = 0; ni < 4; ++ni) {
      const int row = m0 + wr + mi * 16 + lg * 4;
      const int col = n0 + wc + ni * 16 + lr;
      f32x4 v = acc[mi][ni];
      if constexpr (MODE == 2) {
        const float bv = bias[col];
        float* o = (float*)outp;
#pragma unroll
        for (int r = 0; r < 4; ++r) {
          const int rr = row + r;
          o[(size_t)rr * N_ + col] = v[r] + bv + res[(size_t)rr * N_ + col];
        }
      } else if constexpr (MODE == 3) {
        const float bv = bias[col];
        u16* o = (u16*)outp;
#pragma unroll
        for (int r = 0; r < 4; ++r) {
          const int rr = row + r;
          float y = v[r] + bv;
          o[(size_t)rr * N_ + col] = f2b(y > 0.f ? y : 0.f);
        }
      } else {  // MODE 5
        const int proj = col >> 10, c = col & 1023;
        const int h = c >> 5, d = c & 31;
        u16* qout = (u16*)outp;
        if (proj == 0) {
          const float bv = bias[c];
          const float sc = kW[d * 32 + h] * 1.44269504089f;
#pragma unroll
          for (int r = 0; r < 4; ++r) {
            const int rr = row + r;
            const int bb = rr >> 11, s = rr & 2047;
            qout[(size_t)(((bb * 32 + h) * 2048) + s) * 32 + d] =
                f2b((v[r] + bv) * sc);
          }
        } else if (proj == 1) {
          const float bv = bias2[c];
          u16* kout = qout + 4194304;
#pragma unroll
          for (int r = 0; r < 4; ++r) {
            const int rr = row + r;
            const int bb = rr >> 11, s = rr & 2047;
            kout[(size_t)(((bb * 32 + h) * 2048) + s) * 32 + d] =
                f2b(v[r] + bv);
          }
        } else {
          const float bv = bias3[c];
          u16* vout = qout + 8388608;
          const int bb = row >> 11, s0 = row & 2047;
          ushort4 st;
          st.x = f2b(v[0] + bv); st.y = f2b(v[1] + bv);
          st.z = f2b(v[2] + bv); st.w = f2b(v[3] + bv);
          // channel-tiled: elem (d,s) -> (s>>6)*2048 + d*64 + (s&63)
          const int kb = s0 >> 6, ko = s0 & 63;
          *(ushort4*)(vout + (size_t)(bb * 32 + h) * 65536 + kb * 2048 +
                      d * 64 + ko) = st;
        }
      }
    }
  }
}

// ---------------- attention tile compute (64 keys) --------------------------
__device__ __forceinline__ void attn_tile(
    const bf16x8& k0, const bf16x8& k1, const bf16x8& k2, const bf16x8& k3,
    const bf16x8& v0, const bf16x8& v1, const bf16x8& v2, const bf16x8& v3,
    const bf16x8& qb0, const bf16x8& qb1,
    f32x16& acc, float& la, float& lb, float& lc, float& ld) {
  const f32x16 z16 = {};
  f32x16 s0 = __builtin_amdgcn_mfma_f32_32x32x16_bf16(k0, qb0, z16, 0, 0, 0);
  s0 = __builtin_amdgcn_mfma_f32_32x32x16_bf16(k1, qb1, s0, 0, 0, 0);
  f32x16 s1 = __builtin_amdgcn_mfma_f32_32x32x16_bf16(k2, qb0, z16, 0, 0, 0);
  s1 = __builtin_amdgcn_mfma_f32_32x32x16_bf16(k3, qb1, s1, 0, 0, 0);
  float p0[16], p1[16];
#pragma unroll
  for (int r = 0; r < 16; ++r) p0[r] = expo2(s0[r]);
#pragma unroll
  for (int r = 0; r < 16; ++r) p1[r] = expo2(s1[r]);
#pragma unroll
  for (int r = 0; r < 4; ++r) {
    la += p0[r] + p1[r];
    lb += p0[4 + r] + p1[4 + r];
    lc += p0[8 + r] + p1[8 + r];
    ld += p0[12 + r] + p1[12 + r];
  }
  {
    u32 x0 = pkbf(p0[0], p0[1]), x1 = pkbf(p0[2], p0[3]);
    u32 y0 = pkbf(p0[4], p0[5]), y1 = pkbf(p0[6], p0[7]);
    asm("v_permlane32_swap_b32 %0, %1" : "+v"(x0), "+v"(y0));
    asm("v_permlane32_swap_b32 %0, %1" : "+v"(x1), "+v"(y1));
    union { u32 d[4]; bf16x8 v; } u;
    u.d[0] = x0; u.d[1] = x1; u.d[2] = y0; u.d[3] = y1;
    acc = __builtin_amdgcn_mfma_f32_32x32x16_bf16(v0, u.v, acc, 0, 0, 0);
  }
  {
    u32 x0 = pkbf(p0[8], p0[9]), x1 = pkbf(p0[10], p0[11]);
    u32 y0 = pkbf(p0[12], p0[13]), y1 = pkbf(p0[14], p0[15]);
    asm("v_permlane32_swap_b32 %0, %1" : "+v"(x0), "+v"(y0));
    asm("v_permlane32_swap_b32 %0, %1" : "+v"(x1), "+v"(y1));
    union { u32 d[4]; bf16x8 v; } u;
    u.d[0] = x0; u.d[1] = x1; u.d[2] = y0; u.d[3] = y1;
    acc = __builtin_amdgcn_mfma_f32_32x32x16_bf16(v1, u.v, acc, 0, 0, 0);
  }
  {
    u32 x0 = pkbf(p1[0], p1[1]), x1 = pkbf(p1[2], p1[3]);
    u32 y0 = pkbf(p1[4], p1[5]), y1 = pkbf(p1[6], p1[7]);
    asm("v_permlane32_swap_b32 %0, %1" : "+v"(x0), "+v"(y0));
    asm("v_permlane32_swap_b32 %0, %1" : "+v"(x1), "+v"(y1));
    union { u32 d[4]; bf16x8 v; } u;
    u.d[0] = x0; u.d[1] = x1; u.d[2] = y0; u.d[3] = y1;
    acc = __builtin_amdgcn_mfma_f32_32x32x16_bf16(v2, u.v, acc, 0, 0, 0);
  }
  {
    u32 x0 = pkbf(p1[8], p1[9]), x1 = pkbf(p1[10], p1[11]);
    u32 y0 = pkbf(p1[12], p1[13]), y1 = pkbf(p1[14], p1[15]);
    asm("v_permlane32_swap_b32 %0, %1" : "+v"(x0), "+v"(y0));
    asm("v_permlane32_swap_b32 %0, %1" : "+v"(x1), "+v"(y1));
    union { u32 d[4]; bf16x8 v; } u;
    u.d[0] = x0; u.d[1] = x1; u.d[2] = y0; u.d[3] = y1;
    acc = __builtin_amdgcn_mfma_f32_32x32x16_bf16(v3, u.v, acc, 0, 0, 0);
  }
}

#define LOADK(d0, d1, d2, d3, J)                                               \
  {                                                                            \
    const u16* kp_ = kbase + (size_t)(J) * 32;                                 \
    d0 = *(const bf16x8*)(kp_);                                                \
    d1 = *(const bf16x8*)(kp_ + 16);                                           \
    d2 = *(const bf16x8*)(kp_ + 1024);                                         \
    d3 = *(const bf16x8*)(kp_ + 1024 + 16);                                    \
  }
// channel-tiled V: block (J>>6) base = J*32; lane d=lq at d*64; keys
// sub*32+c*16+hi*8 -> offsets +0,+16,+32,+48 from vp_ (same as before).
#define LOADV(d0, d1, d2, d3, J)                                               \
  {                                                                            \
    const u16* vp_ = vbase + (size_t)(J) * 32;                                 \
    d0 = *(const bf16x8*)(vp_);                                                \
    d1 = *(const bf16x8*)(vp_ + 16);                                           \
    d2 = *(const bf16x8*)(vp_ + 32);                                           \
    d3 = *(const bf16x8*)(vp_ + 48);                                           \
  }

// ---------------- swapped 32x32 flash attention, split-K 2-way --------------
__global__ __launch_bounds__(256) void attn_kernel(
    const u16* __restrict__ Q, const u16* __restrict__ K,
    const u16* __restrict__ VT, u16* __restrict__ O) {
  __shared__ float sm_l[2][32];
  __shared__ float sm_acc[2][64][16];
  const int t = threadIdx.x, wid = t >> 6, lane = t & 63;
  const int qg = wid & 1, kh = wid >> 1;
  const int bid = blockIdx.x;
  const int swz = (bid & 7) * 256 + (bid >> 3);  // 2048 blocks, 8 XCDs
  const int bh = swz >> 5;                       // 0..63
  const int qt = swz & 31;                       // q-tile of 64
  const int q0 = qt * 64 + qg * 32;
  const int lq = lane & 31, hi = lane >> 5;
  const u16* Qh = Q + (size_t)bh * 2048 * 32;
  const u16* Kh = K + (size_t)bh * 2048 * 32;
  const u16* Vh = VT + (size_t)bh * 32 * 2048;

  const bf16x8 qb0 = *(const bf16x8*)(Qh + (size_t)(q0 + lq) * 32 + hi * 8);
  const bf16x8 qb1 = *(const bf16x8*)(Qh + (size_t)(q0 + lq) * 32 + 16 + hi * 8);

  const u16* kbase = Kh + (size_t)lq * 32 + hi * 8;
  const u16* vbase = Vh + lq * 64 + hi * 8;

  f32x16 acc = {};
  float la = 0.f, lb = 0.f, lc = 0.f, ld = 0.f;

  const int jb = kh * 1024;

  bf16x8 ka0, ka1, ka2, ka3, va0, va1, va2, va3;
  bf16x8 kb0, kb1, kb2, kb3, vb0, vb1, vb2, vb3;
  LOADK(ka0, ka1, ka2, ka3, jb);
  LOADV(va0, va1, va2, va3, jb);

  int j0 = jb;
#pragma unroll 1
  for (int pr = 0; pr < 8; ++pr) {
    LOADK(kb0, kb1, kb2, kb3, j0 + 64);
    LOADV(vb0, vb1, vb2, vb3, j0 + 64);
    attn_tile(ka0, ka1, ka2, ka3, va0, va1, va2, va3, qb0, qb1,
              acc, la, lb, lc, ld);
    LOADK(ka0, ka1, ka2, ka3, j0 + 128);  // last iter overreads 4KB: lands in
    LOADV(va0, va1, va2, va3, j0 + 128);  // adjacent ws regions, discarded
    attn_tile(kb0, kb1, kb2, kb3, vb0, vb1, vb2, vb3, qb0, qb1,
              acc, la, lb, lc, ld);
    j0 += 128;
  }

  float lrun = (la + lb) + (lc + ld);
  lrun += __shfl_xor(lrun, 32);

  if (kh == 1) {
    sm_l[qg][lq] = lrun;
#pragma unroll
    for (int r = 0; r < 16; ++r) sm_acc[qg][lane][r] = acc[r];
  }
  __syncthreads();
  if (kh == 0) {
    const float inv = 1.f / (lrun + sm_l[qg][lq]);
    const int bb = bh >> 5, h = bh & 31;
    u16* o = O + (size_t)(bb * 2048 + q0 + lq) * 1024 + h * 32;
#pragma unroll
    for (int g = 0; g < 4; ++g) {
      ushort4 st;
      st.x = f2b((acc[g * 4 + 0] + sm_acc[qg][lane][g * 4 + 0]) * inv);
      st.y = f2b((acc[g * 4 + 1] + sm_acc[qg][lane][g * 4 + 1]) * inv);
      st.z = f2b((acc[g * 4 + 2] + sm_acc[qg][lane][g * 4 + 2]) * inv);
      st.w = f2b((acc[g * 4 + 3] + sm_acc[qg][lane][g * 4 + 3]) * inv);
      *(ushort4*)(o + g * 8 + hi * 4) = st;
    }
  }
}

// ---------------- LayerNorm (1 wave per row of 1024) ------------------------
template <int WB>
__global__ __launch_bounds__(256) void ln_kernel(
    const float* X, const float* __restrict__ g, const float* __restrict__ b,
    float* outf, u16* __restrict__ outb) {
  const int wid = threadIdx.x >> 6, lane = threadIdx.x & 63;
  const int row = blockIdx.x * 4 + wid;
  const float4* X4 = (const float4*)(X + (size_t)row * 1024);
  float4 xs[4];
  float s = 0.f, sq = 0.f;
#pragma unroll
  for (int i = 0; i < 4; ++i) {
    xs[i] = X4[lane + i * 64];
    s += xs[i].x + xs[i].y + xs[i].z + xs[i].w;
    sq += xs[i].x * xs[i].x + xs[i].y * xs[i].y + xs[i].z * xs[i].z + xs[i].w * xs[i].w;
  }
#pragma unroll
  for (int m = 1; m < 64; m <<= 1) { s += __shfl_xor(s, m); sq += __shfl_xor(sq, m); }
  const float mean = s * (1.f / 1024.f);
  float var = sq * (1.f / 1024.f) - mean * mean;
  var = var > 0.f ? var : 0.f;
  const float rstd = rsqrtf(var + 1e-5f);
  const float4* g4 = (const float4*)g;
  const float4* b4 = (const float4*)b;
  float4* of = (float4*)(outf + (size_t)row * 1024);
#pragma unroll
  for (int i = 0; i < 4; ++i) {
    const int c = lane + i * 64;
    const float4 gv = g4[c], bv = b4[c], x = xs[i];
    float4 y;
    y.x = (x.x - mean) * rstd * gv.x + bv.x;
    y.y = (x.y - mean) * rstd * gv.y + bv.y;
    y.z = (x.z - mean) * rstd * gv.z + bv.z;
    y.w = (x.w - mean) * rstd * gv.w + bv.w;
    of[c] = y;
    if constexpr (WB) {
      ushort4 yb;
      yb.x = f2b(y.x); yb.y = f2b(y.y); yb.z = f2b(y.z); yb.w = f2b(y.w);
      ((ushort4*)(outb + (size_t)row * 1024))[c] = yb;
    }
  }
}

// ---------------------------------------------------------------------------
extern "C" void kernel_launch(void* const* d_in, const int* in_sizes, int n_in,
                              void* d_out, int out_size, void* d_ws,
                              size_t ws_size, hipStream_t stream) {
  const float* x   = (const float*)d_in[0];
  const float* Wq  = (const float*)d_in[1];
  const float* bq  = (const float*)d_in[2];
  const float* Wk  = (const float*)d_in[3];
  const float* bk  = (const float*)d_in[4];
  const float* Wv  = (const float*)d_in[5];
  const float* bv  = (const float*)d_in[6];
  const float* kW  = (const float*)d_in[7];
  const float* Wo  = (const float*)d_in[8];
  const float* bo  = (const float*)d_in[9];
  const float* W1  = (const float*)d_in[10];
  const float* b1  = (const float*)d_in[11];
  const float* W2  = (const float*)d_in[12];
  const float* b2  = (const float*)d_in[13];
  const float* g1  = (const float*)d_in[14];
  const float* be1 = (const float*)d_in[15];
  const float* g2  = (const float*)d_in[16];
  const float* be2 = (const float*)d_in[17];

  char* ws = (char*)d_ws;
  const size_t MB = 1024 * 1024;
  u16*   WqT = (u16*)(ws + 0 * MB);   // [0,6) = fused QKV BT[3072][1024]
  u16*   WkT = (u16*)(ws + 2 * MB);
  u16*   WvT = (u16*)(ws + 4 * MB);
  u16*   WoT = (u16*)(ws + 6 * MB);
  u16*   W1T = (u16*)(ws + 8 * MB);
  u16*   W2T = (u16*)(ws + 16 * MB);
  float* r1  = (float*)(ws + 24 * MB);
  u16*   xb  = (u16*)(ws + 40 * MB);
  u16*   qhB = (u16*)(ws + 48 * MB);
  u16*   khB = (u16*)(ws + 56 * MB);
  u16*   vTB = (u16*)(ws + 64 * MB);
  u16*   hf  = (u16*)(ws + 40 * MB);  // aliases xb..vT, free by then
  u16*   ao  = (u16*)(ws + 72 * MB);
  u16*   x1b = (u16*)(ws + 80 * MB);
  float* r2  = (float*)(ws + 72 * MB);  // aliases ao+x1b, free by then

  const dim3 blk(256);

  transpose_cast<<<dim3(32, 32), blk, 0, stream>>>(Wq, WqT, 1024, 1024);
  transpose_cast<<<dim3(32, 32), blk, 0, stream>>>(Wk, WkT, 1024, 1024);
  transpose_cast<<<dim3(32, 32), blk, 0, stream>>>(Wv, WvT, 1024, 1024);
  transpose_cast<<<dim3(32, 32), blk, 0, stream>>>(Wo, WoT, 1024, 1024);
  transpose_cast<<<dim3(128, 32), blk, 0, stream>>>(W1, W1T, 1024, 4096);
  transpose_cast<<<dim3(32, 128), blk, 0, stream>>>(W2, W2T, 4096, 1024);
  cast_b<<<4096, blk, 0, stream>>>(x, xb);

  // fused QKV projection (q scaled by kernelW*log2e, v channel-tiled)
  gemmT<5, 128><<<dim3(24, 32), blk, 0, stream>>>(
      xb, WqT, bq, bk, bv, nullptr, qhB, kW, 3072, 1024);

  // flash attention: 2048 blocks x 4 waves (2 qg x 2 key-halves)
  attn_kernel<<<2048, blk, 0, stream>>>(qhB, khB, vTB, ao);

  // out-proj + residual -> r1 (fp32); BN=64 -> 512 blocks
  gemmT<2, 64><<<dim3(16, 32), blk, 0, stream>>>(
      ao, WoT, bo, nullptr, nullptr, x, r1, nullptr, 1024, 1024);
  ln_kernel<1><<<1024, blk, 0, stream>>>(r1, g1, be1, r1, x1b);
  // FFN
  gemmT<3, 128><<<dim3(32, 32), blk, 0, stream>>>(
      x1b, W1T, b1, nullptr, nullptr, nullptr, hf, nullptr, 4096, 1024);
  gemmT<2, 64><<<dim3(16, 32), blk, 0, stream>>>(
      hf, W2T, b2, nullptr, nullptr, r1, r2, nullptr, 1024, 4096);
  ln_kernel<0><<<1024, blk, 0, stream>>>(r2, g2, be2, (float*)d_out, nullptr);

  (void)in_sizes; (void)n_in; (void)out_size; (void)ws_size;
}

// Round 10
// 272.928 us; speedup vs baseline: 1.3182x; 1.1162x over previous
//
#include <hip/hip_runtime.h>

// ---------------------------------------------------------------------------
// TransformerBlockQuantum: B=2,S=2048,E=1024,H=32,DK=32,FFN=4096
// GEMMs: bf16 MFMA 16x16x32, LDS double-buffer, single-barrier K-loop.
// Attention: swapped 32x32 QK^T, unshifted exp2 softmax, permlane32_swap
// P-pack, split-K 2-way. K/V stored in FRAGMENT-ORDER 4KB tiles so a linear
// global_load_lds fill + (base + r*1024 + lane*16) reads give exact MFMA
// fragments, conflict-free. LDS double-buffered staging (prefetch lives in
// LDS, not VGPRs -- r6/r9 showed compiler drops VGPR prefetch at 76 regs).
// K tile (64 keys x 32 d): elem(k,d): c=d>>3; g=((k>>5)<<1)|(c>>1);
//   off = g*512 + (c&1)*256 + (k&31)*8 + (d&7)
// V tile: elem(k,d): c=k>>3; off = (c>>1)*512 + (c&1)*256 + d*8 + (k&7)
// ws layout (MB): unchanged from round 8/9.
// ---------------------------------------------------------------------------

typedef unsigned short u16;
typedef unsigned int u32;
typedef __bf16 bf16x8 __attribute__((ext_vector_type(8)));
typedef float f32x4 __attribute__((ext_vector_type(4)));
typedef float f32x16 __attribute__((ext_vector_type(16)));

__device__ __forceinline__ u16 f2b(float f) {
  union { float f; unsigned u; } x; x.f = f;
  unsigned r = x.u + 0x7FFFu + ((x.u >> 16) & 1u);
  return (u16)(r >> 16);
}

__device__ __forceinline__ unsigned pkbf(float lo, float hi) {
  unsigned r;
  asm("v_cvt_pk_bf16_f32 %0, %1, %2" : "=v"(r) : "v"(lo), "v"(hi));
  return r;
}

__device__ __forceinline__ float expo2(float x) {
#if __has_builtin(__builtin_amdgcn_exp2f)
  return __builtin_amdgcn_exp2f(x);
#else
  return exp2f(x);
#endif
}

#define GLDS16(gp, lp)                                                         \
  __builtin_amdgcn_global_load_lds(                                            \
      (const __attribute__((address_space(1))) void*)(gp),                     \
      (__attribute__((address_space(3))) void*)(lp), 16, 0, 0)

// ---------------- transpose + cast: W[K][N] f32 -> WT[N][K] bf16 ------------
__global__ __launch_bounds__(256) void transpose_cast(
    const float* __restrict__ W, u16* __restrict__ WT, int K, int N) {
  __shared__ float tile[32][33];
  const int tx = threadIdx.x & 31, ty = threadIdx.x >> 5;
  const int n0 = blockIdx.x * 32, k0 = blockIdx.y * 32;
#pragma unroll
  for (int i = 0; i < 4; ++i)
    tile[ty + 8 * i][tx] = W[(size_t)(k0 + ty + 8 * i) * N + n0 + tx];
  __syncthreads();
#pragma unroll
  for (int i = 0; i < 4; ++i)
    WT[(size_t)(n0 + ty + 8 * i) * K + k0 + tx] = f2b(tile[tx][ty + 8 * i]);
}

// ---------------- cast f32 -> bf16 (4 elems/thread) -------------------------
__global__ __launch_bounds__(256) void cast_b(const float* __restrict__ x,
                                              u16* __restrict__ y) {
  int i = blockIdx.x * 256 + threadIdx.x;
  float4 v = ((const float4*)x)[i];
  ushort4 o;
  o.x = f2b(v.x); o.y = f2b(v.y); o.z = f2b(v.z); o.w = f2b(v.w);
  ((ushort4*)y)[i] = o;
}

// ---------------- GEMM: C = A[M,K] @ BT[N,K]^T, bf16, dbuf 1-barrier loop ---
// MODE 2: fp32 out = acc + bias + res   (Wo and W2 paths)
// MODE 3: bf16 out = relu(acc + bias)   (W1 path)
// MODE 5: fused QKV: q-scaled head store / k,v fragment-order tile stores.
template <int MODE, int BN>
__global__ __launch_bounds__(256) void gemmT(
    const u16* __restrict__ A, const u16* __restrict__ BT,
    const float* __restrict__ bias, const float* __restrict__ bias2,
    const float* __restrict__ bias3, const float* __restrict__ res,
    void* __restrict__ outp, const float* __restrict__ kW, int N_, int K_) {
  constexpr int ABYT = 128 * 32 * 2;        // 8 KB A tile
  constexpr int BBYT = BN * 32 * 2;         // 8/4 KB B tile
  constexpr int STRIDE = ABYT + BBYT;
  constexpr int MI = (BN == 128) ? 4 : 2;
  __shared__ __align__(16) char SH[2 * STRIDE];
  const int t = threadIdx.x, lane = t & 63, wid = t >> 6;
  const int m0 = blockIdx.y * 128, n0 = blockIdx.x * BN;
  const int wr = (BN == 128) ? (wid >> 1) * 64 : wid * 32;
  const int wc = (BN == 128) ? (wid & 1) * 64 : 0;
  const int lr = lane & 15, lg = lane >> 4;
  const int K = K_;

  f32x4 acc[MI][4] = {};

  const u16* ga0 = A + (size_t)(m0 + (t >> 2)) * K + (t & 3) * 8;
  const u16* ga1 = ga0 + (size_t)64 * K;
  const u16* gb0 = BT + (size_t)(n0 + (t >> 2)) * K + (t & 3) * 8;
  const u16* gb1 = gb0 + (size_t)64 * K;  // only used when BN==128
  const int stA = wid * 1024;

#define STAGE(CUR, KT)                                                         \
  {                                                                            \
    char* l_ = (char*)SH + (CUR) * STRIDE + stA;                               \
    const size_t o_ = (size_t)(KT) * 32;                                       \
    GLDS16(ga0 + o_, l_);                                                      \
    GLDS16(ga1 + o_, l_ + 4096);                                               \
    GLDS16(gb0 + o_, l_ + ABYT);                                               \
    if constexpr (BN == 128) GLDS16(gb1 + o_, l_ + ABYT + 4096);               \
  }

  const int nk = K >> 5;
  STAGE(0, 0);
  __syncthreads();
  int cur = 0;
  for (int kt = 0; kt < nk; ++kt) {
    if (kt + 1 < nk) STAGE(cur ^ 1, kt + 1);
    const char* l = (const char*)SH + cur * STRIDE;
    bf16x8 af[MI], bf[4];
#pragma unroll
    for (int i = 0; i < MI; ++i)
      af[i] = *(const bf16x8*)(l + (wr + i * 16 + lr) * 64 + lg * 16);
#pragma unroll
    for (int i = 0; i < 4; ++i)
      bf[i] = *(const bf16x8*)(l + ABYT + (wc + i * 16 + lr) * 64 + lg * 16);
#pragma unroll
    for (int mi = 0; mi < MI; ++mi)
#pragma unroll
      for (int ni = 0; ni < 4; ++ni)
        acc[mi][ni] = __builtin_amdgcn_mfma_f32_16x16x32_bf16(
            af[mi], bf[ni], acc[mi][ni], 0, 0, 0);
    __syncthreads();
    cur ^= 1;
  }
#undef STAGE

#pragma unroll
  for (int mi = 0; mi < MI; ++mi) {
#pragma unroll
    for (int ni = 0; ni < 4; ++ni) {
      const int row = m0 + wr + mi * 16 + lg * 4;
      const int col = n0 + wc + ni * 16 + lr;
      f32x4 v = acc[mi][ni];
      if constexpr (MODE == 2) {
        const float bv = bias[col];
        float* o = (float*)outp;
#pragma unroll
        for (int r = 0; r < 4; ++r) {
          const int rr = row + r;
          o[(size_t)rr * N_ + col] = v[r] + bv + res[(size_t)rr * N_ + col];
        }
      } else if constexpr (MODE == 3) {
        const float bv = bias[col];
        u16* o = (u16*)outp;
#pragma unroll
        for (int r = 0; r < 4; ++r) {
          const int rr = row + r;
          float y = v[r] + bv;
          o[(size_t)rr * N_ + col] = f2b(y > 0.f ? y : 0.f);
        }
      } else {  // MODE 5
        const int proj = col >> 10, c = col & 1023;
        const int h = c >> 5, d = c & 31;
        u16* qout = (u16*)outp;
        if (proj == 0) {
          const float bv = bias[c];
          const float sc = kW[d * 32 + h] * 1.44269504089f;
#pragma unroll
          for (int r = 0; r < 4; ++r) {
            const int rr = row + r;
            const int bb = rr >> 11, s = rr & 2047;
            qout[(size_t)(((bb * 32 + h) * 2048) + s) * 32 + d] =
                f2b((v[r] + bv) * sc);
          }
        } else if (proj == 1) {
          const float bv = bias2[c];
          u16* kout = qout + 4194304;
          const int c2 = d >> 3;  // 16B chunk within key row
#pragma unroll
          for (int r = 0; r < 4; ++r) {
            const int rr = row + r;
            const int bb = rr >> 11, s = rr & 2047;
            const int k = s & 63;
            const int g = ((k >> 5) << 1) | (c2 >> 1);
            kout[(size_t)(bb * 32 + h) * 65536 + (s >> 6) * 2048 + g * 512 +
                 (c2 & 1) * 256 + (k & 31) * 8 + (d & 7)] = f2b(v[r] + bv);
          }
        } else {
          const float bv = bias3[c];
          u16* vout = qout + 8388608;
          const int bb = row >> 11, s0 = row & 2047;
          const int k = s0 & 63;
          const int cc = k >> 3, rb = cc >> 1, hb = cc & 1, e = k & 7;
          ushort4 st;
          st.x = f2b(v[0] + bv); st.y = f2b(v[1] + bv);
          st.z = f2b(v[2] + bv); st.w = f2b(v[3] + bv);
          *(ushort4*)(vout + (size_t)(bb * 32 + h) * 65536 +
                      (s0 >> 6) * 2048 + rb * 512 + hb * 256 + d * 8 + e) = st;
        }
      }
    }
  }
}

// ---------------- attention tile compute (64 keys) --------------------------
__device__ __forceinline__ void attn_tile(
    const bf16x8& k0, const bf16x8& k1, const bf16x8& k2, const bf16x8& k3,
    const bf16x8& v0, const bf16x8& v1, const bf16x8& v2, const bf16x8& v3,
    const bf16x8& qb0, const bf16x8& qb1,
    f32x16& acc, float& la, float& lb, float& lc, float& ld) {
  const f32x16 z16 = {};
  f32x16 s0 = __builtin_amdgcn_mfma_f32_32x32x16_bf16(k0, qb0, z16, 0, 0, 0);
  s0 = __builtin_amdgcn_mfma_f32_32x32x16_bf16(k1, qb1, s0, 0, 0, 0);
  f32x16 s1 = __builtin_amdgcn_mfma_f32_32x32x16_bf16(k2, qb0, z16, 0, 0, 0);
  s1 = __builtin_amdgcn_mfma_f32_32x32x16_bf16(k3, qb1, s1, 0, 0, 0);
  float p0[16], p1[16];
#pragma unroll
  for (int r = 0; r < 16; ++r) p0[r] = expo2(s0[r]);
#pragma unroll
  for (int r = 0; r < 16; ++r) p1[r] = expo2(s1[r]);
#pragma unroll
  for (int r = 0; r < 4; ++r) {
    la += p0[r] + p1[r];
    lb += p0[4 + r] + p1[4 + r];
    lc += p0[8 + r] + p1[8 + r];
    ld += p0[12 + r] + p1[12 + r];
  }
  {
    u32 x0 = pkbf(p0[0], p0[1]), x1 = pkbf(p0[2], p0[3]);
    u32 y0 = pkbf(p0[4], p0[5]), y1 = pkbf(p0[6], p0[7]);
    asm("v_permlane32_swap_b32 %0, %1" : "+v"(x0), "+v"(y0));
    asm("v_permlane32_swap_b32 %0, %1" : "+v"(x1), "+v"(y1));
    union { u32 d[4]; bf16x8 v; } u;
    u.d[0] = x0; u.d[1] = x1; u.d[2] = y0; u.d[3] = y1;
    acc = __builtin_amdgcn_mfma_f32_32x32x16_bf16(v0, u.v, acc, 0, 0, 0);
  }
  {
    u32 x0 = pkbf(p0[8], p0[9]), x1 = pkbf(p0[10], p0[11]);
    u32 y0 = pkbf(p0[12], p0[13]), y1 = pkbf(p0[14], p0[15]);
    asm("v_permlane32_swap_b32 %0, %1" : "+v"(x0), "+v"(y0));
    asm("v_permlane32_swap_b32 %0, %1" : "+v"(x1), "+v"(y1));
    union { u32 d[4]; bf16x8 v; } u;
    u.d[0] = x0; u.d[1] = x1; u.d[2] = y0; u.d[3] = y1;
    acc = __builtin_amdgcn_mfma_f32_32x32x16_bf16(v1, u.v, acc, 0, 0, 0);
  }
  {
    u32 x0 = pkbf(p1[0], p1[1]), x1 = pkbf(p1[2], p1[3]);
    u32 y0 = pkbf(p1[4], p1[5]), y1 = pkbf(p1[6], p1[7]);
    asm("v_permlane32_swap_b32 %0, %1" : "+v"(x0), "+v"(y0));
    asm("v_permlane32_swap_b32 %0, %1" : "+v"(x1), "+v"(y1));
    union { u32 d[4]; bf16x8 v; } u;
    u.d[0] = x0; u.d[1] = x1; u.d[2] = y0; u.d[3] = y1;
    acc = __builtin_amdgcn_mfma_f32_32x32x16_bf16(v2, u.v, acc, 0, 0, 0);
  }
  {
    u32 x0 = pkbf(p1[8], p1[9]), x1 = pkbf(p1[10], p1[11]);
    u32 y0 = pkbf(p1[12], p1[13]), y1 = pkbf(p1[14], p1[15]);
    asm("v_permlane32_swap_b32 %0, %1" : "+v"(x0), "+v"(y0));
    asm("v_permlane32_swap_b32 %0, %1" : "+v"(x1), "+v"(y1));
    union { u32 d[4]; bf16x8 v; } u;
    u.d[0] = x0; u.d[1] = x1; u.d[2] = y0; u.d[3] = y1;
    acc = __builtin_amdgcn_mfma_f32_32x32x16_bf16(v3, u.v, acc, 0, 0, 0);
  }
}

// ---------------- swapped 32x32 flash attention, LDS-staged -----------------
// Block = 4 waves: qg = wid&1 (32 queries), kh = wid>>1 (1024 keys each).
// Per tile (64 keys per kh): cooperative GLDS16 staging of K0/V0/K1/V1
// fragment-order tiles (16KB), double-buffered; reads at base+r*1024+lane*16.
__global__ __launch_bounds__(256) void attn_kernel(
    const u16* __restrict__ Q, const u16* __restrict__ K,
    const u16* __restrict__ VT, u16* __restrict__ O) {
  __shared__ __align__(16) char LDSB[32768];
  const int t = threadIdx.x, wid = t >> 6, lane = t & 63;
  const int qg = wid & 1, kh = wid >> 1;
  const int bid = blockIdx.x;
  const int swz = (bid & 7) * 256 + (bid >> 3);  // 2048 blocks, 8 XCDs
  const int bh = swz >> 5;                       // 0..63
  const int qt = swz & 31;                       // q-tile of 64
  const int q0 = qt * 64 + qg * 32;
  const int lq = lane & 31, hi = lane >> 5;
  const u16* Qh = Q + (size_t)bh * 65536;
  const u16* Kh = K + (size_t)bh * 65536;
  const u16* Vh = VT + (size_t)bh * 65536;

  const bf16x8 qb0 = *(const bf16x8*)(Qh + (size_t)(q0 + lq) * 32 + hi * 8);
  const bf16x8 qb1 = *(const bf16x8*)(Qh + (size_t)(q0 + lq) * 32 + 16 + hi * 8);

  // per-lane staging srcs: this wave stages quarter `wid` of each region.
  // tile i of key-half hh lives at (hh*16 + i)*2048 u16.
  const u16* kg = Kh + wid * 512 + lane * 8;
  const u16* vg = Vh + wid * 512 + lane * 8;
  const int lds_w = wid * 1024;

#define STAGEA(CUR, I)                                                         \
  {                                                                            \
    char* b_ = LDSB + (CUR) * 16384 + lds_w;                                   \
    GLDS16(kg + (size_t)(I) * 2048, b_);                                       \
    GLDS16(vg + (size_t)(I) * 2048, b_ + 4096);                                \
    GLDS16(kg + (size_t)(16 + (I)) * 2048, b_ + 8192);                         \
    GLDS16(vg + (size_t)(16 + (I)) * 2048, b_ + 12288);                        \
  }

  f32x16 acc = {};
  float la = 0.f, lb = 0.f, lc = 0.f, ld = 0.f;

  STAGEA(0, 0);
  __syncthreads();
  int cur = 0;
#pragma unroll 1
  for (int i = 0; i < 16; ++i) {
    if (i < 15) STAGEA(cur ^ 1, i + 1);
    const char* kb = LDSB + cur * 16384 + kh * 8192 + lane * 16;
    const bf16x8 ka0 = *(const bf16x8*)(kb);
    const bf16x8 ka1 = *(const bf16x8*)(kb + 1024);
    const bf16x8 ka2 = *(const bf16x8*)(kb + 2048);
    const bf16x8 ka3 = *(const bf16x8*)(kb + 3072);
    const bf16x8 va0 = *(const bf16x8*)(kb + 4096);
    const bf16x8 va1 = *(const bf16x8*)(kb + 5120);
    const bf16x8 va2 = *(const bf16x8*)(kb + 6144);
    const bf16x8 va3 = *(const bf16x8*)(kb + 7168);
    attn_tile(ka0, ka1, ka2, ka3, va0, va1, va2, va3, qb0, qb1,
              acc, la, lb, lc, ld);
    __syncthreads();
    cur ^= 1;
  }
#undef STAGEA

  float lrun = (la + lb) + (lc + ld);
  lrun += __shfl_xor(lrun, 32);

  // merge scratch aliases buf0 (dead after final loop barrier)
  float* sm_acc = (float*)LDSB;            // [2][64][16]
  float* sm_l = (float*)(LDSB + 8192);     // [2][32]
  if (kh == 1) {
    sm_l[qg * 32 + lq] = lrun;
#pragma unroll
    for (int r = 0; r < 16; ++r) sm_acc[(qg * 64 + lane) * 16 + r] = acc[r];
  }
  __syncthreads();
  if (kh == 0) {
    const float inv = 1.f / (lrun + sm_l[qg * 32 + lq]);
    const int bb = bh >> 5, h = bh & 31;
    u16* o = O + (size_t)(bb * 2048 + q0 + lq) * 1024 + h * 32;
#pragma unroll
    for (int g = 0; g < 4; ++g) {
      ushort4 st;
      st.x = f2b((acc[g * 4 + 0] + sm_acc[(qg * 64 + lane) * 16 + g * 4 + 0]) * inv);
      st.y = f2b((acc[g * 4 + 1] + sm_acc[(qg * 64 + lane) * 16 + g * 4 + 1]) * inv);
      st.z = f2b((acc[g * 4 + 2] + sm_acc[(qg * 64 + lane) * 16 + g * 4 + 2]) * inv);
      st.w = f2b((acc[g * 4 + 3] + sm_acc[(qg * 64 + lane) * 16 + g * 4 + 3]) * inv);
      *(ushort4*)(o + g * 8 + hi * 4) = st;
    }
  }
}

// ---------------- LayerNorm (1 wave per row of 1024) ------------------------
template <int WB>
__global__ __launch_bounds__(256) void ln_kernel(
    const float* X, const float* __restrict__ g, const float* __restrict__ b,
    float* outf, u16* __restrict__ outb) {
  const int wid = threadIdx.x >> 6, lane = threadIdx.x & 63;
  const int row = blockIdx.x * 4 + wid;
  const float4* X4 = (const float4*)(X + (size_t)row * 1024);
  float4 xs[4];
  float s = 0.f, sq = 0.f;
#pragma unroll
  for (int i = 0; i < 4; ++i) {
    xs[i] = X4[lane + i * 64];
    s += xs[i].x + xs[i].y + xs[i].z + xs[i].w;
    sq += xs[i].x * xs[i].x + xs[i].y * xs[i].y + xs[i].z * xs[i].z + xs[i].w * xs[i].w;
  }
#pragma unroll
  for (int m = 1; m < 64; m <<= 1) { s += __shfl_xor(s, m); sq += __shfl_xor(sq, m); }
  const float mean = s * (1.f / 1024.f);
  float var = sq * (1.f / 1024.f) - mean * mean;
  var = var > 0.f ? var : 0.f;
  const float rstd = rsqrtf(var + 1e-5f);
  const float4* g4 = (const float4*)g;
  const float4* b4 = (const float4*)b;
  float4* of = (float4*)(outf + (size_t)row * 1024);
#pragma unroll
  for (int i = 0; i < 4; ++i) {
    const int c = lane + i * 64;
    const float4 gv = g4[c], bv = b4[c], x = xs[i];
    float4 y;
    y.x = (x.x - mean) * rstd * gv.x + bv.x;
    y.y = (x.y - mean) * rstd * gv.y + bv.y;
    y.z = (x.z - mean) * rstd * gv.z + bv.z;
    y.w = (x.w - mean) * rstd * gv.w + bv.w;
    of[c] = y;
    if constexpr (WB) {
      ushort4 yb;
      yb.x = f2b(y.x); yb.y = f2b(y.y); yb.z = f2b(y.z); yb.w = f2b(y.w);
      ((ushort4*)(outb + (size_t)row * 1024))[c] = yb;
    }
  }
}

// ---------------------------------------------------------------------------
extern "C" void kernel_launch(void* const* d_in, const int* in_sizes, int n_in,
                              void* d_out, int out_size, void* d_ws,
                              size_t ws_size, hipStream_t stream) {
  const float* x   = (const float*)d_in[0];
  const float* Wq  = (const float*)d_in[1];
  const float* bq  = (const float*)d_in[2];
  const float* Wk  = (const float*)d_in[3];
  const float* bk  = (const float*)d_in[4];
  const float* Wv  = (const float*)d_in[5];
  const float* bv  = (const float*)d_in[6];
  const float* kW  = (const float*)d_in[7];
  const float* Wo  = (const float*)d_in[8];
  const float* bo  = (const float*)d_in[9];
  const float* W1  = (const float*)d_in[10];
  const float* b1  = (const float*)d_in[11];
  const float* W2  = (const float*)d_in[12];
  const float* b2  = (const float*)d_in[13];
  const float* g1  = (const float*)d_in[14];
  const float* be1 = (const float*)d_in[15];
  const float* g2  = (const float*)d_in[16];
  const float* be2 = (const float*)d_in[17];

  char* ws = (char*)d_ws;
  const size_t MB = 1024 * 1024;
  u16*   WqT = (u16*)(ws + 0 * MB);   // [0,6) = fused QKV BT[3072][1024]
  u16*   WkT = (u16*)(ws + 2 * MB);
  u16*   WvT = (u16*)(ws + 4 * MB);
  u16*   WoT = (u16*)(ws + 6 * MB);
  u16*   W1T = (u16*)(ws + 8 * MB);
  u16*   W2T = (u16*)(ws + 16 * MB);
  float* r1  = (float*)(ws + 24 * MB);
  u16*   xb  = (u16*)(ws + 40 * MB);
  u16*   qhB = (u16*)(ws + 48 * MB);
  u16*   khB = (u16*)(ws + 56 * MB);
  u16*   vTB = (u16*)(ws + 64 * MB);
  u16*   hf  = (u16*)(ws + 40 * MB);  // aliases xb..vT, free by then
  u16*   ao  = (u16*)(ws + 72 * MB);
  u16*   x1b = (u16*)(ws + 80 * MB);
  float* r2  = (float*)(ws + 72 * MB);  // aliases ao+x1b, free by then

  const dim3 blk(256);

  transpose_cast<<<dim3(32, 32), blk, 0, stream>>>(Wq, WqT, 1024, 1024);
  transpose_cast<<<dim3(32, 32), blk, 0, stream>>>(Wk, WkT, 1024, 1024);
  transpose_cast<<<dim3(32, 32), blk, 0, stream>>>(Wv, WvT, 1024, 1024);
  transpose_cast<<<dim3(32, 32), blk, 0, stream>>>(Wo, WoT, 1024, 1024);
  transpose_cast<<<dim3(128, 32), blk, 0, stream>>>(W1, W1T, 1024, 4096);
  transpose_cast<<<dim3(32, 128), blk, 0, stream>>>(W2, W2T, 4096, 1024);
  cast_b<<<4096, blk, 0, stream>>>(x, xb);

  // fused QKV projection (q scaled by kernelW*log2e; k,v fragment-tiled)
  gemmT<5, 128><<<dim3(24, 32), blk, 0, stream>>>(
      xb, WqT, bq, bk, bv, nullptr, qhB, kW, 3072, 1024);

  // flash attention: 2048 blocks x 4 waves (2 qg x 2 key-halves), LDS-staged
  attn_kernel<<<2048, blk, 0, stream>>>(qhB, khB, vTB, ao);

  // out-proj + residual -> r1 (fp32); BN=64 -> 512 blocks
  gemmT<2, 64><<<dim3(16, 32), blk, 0, stream>>>(
      ao, WoT, bo, nullptr, nullptr, x, r1, nullptr, 1024, 1024);
  ln_kernel<1><<<1024, blk, 0, stream>>>(r1, g1, be1, r1, x1b);
  // FFN
  gemmT<3, 128><<<dim3(32, 32), blk, 0, stream>>>(
      x1b, W1T, b1, nullptr, nullptr, nullptr, hf, nullptr, 4096, 1024);
  gemmT<2, 64><<<dim3(16, 32), blk, 0, stream>>>(
      hf, W2T, b2, nullptr, nullptr, r1, r2, nullptr, 1024, 4096);
  ln_kernel<0><<<1024, blk, 0, stream>>>(r2, g2, be2, (float*)d_out, nullptr);

  (void)in_sizes; (void)n_in; (void)out_size; (void)ws_size;
}

// Round 11
// 270.472 us; speedup vs baseline: 1.3302x; 1.0091x over previous
//
#include <hip/hip_runtime.h>

// ---------------------------------------------------------------------------
// TransformerBlockQuantum: B=2,S=2048,E=1024,H=32,DK=32,FFN=4096
// GEMMs: bf16 MFMA 16x16x32, LDS double-buffer, single-barrier K-loop,
// XCD-chunked block swizzle. FFN2 = split-K 2-way (grid 16x64, f32 partials
// to r2a/r2b; ln2sum merges). Attention: round-10 exact (LDS-staged
// fragment-order K/V tiles, swapped 32x32 QK^T, unshifted exp2 softmax).
// ws layout (MB):
//  [0,6) QKV BT  [6,8)WoT [8,16)W1T [16,24)W2T
//  [24,40) r1    [40,72) xb/qh/kh/vT then hf   [72,88) ao/x1b then r2b
//  r2a aliases [0,16) (weights dead by FFN2 time; W2T at [16,24) stays live)
// ---------------------------------------------------------------------------

typedef unsigned short u16;
typedef unsigned int u32;
typedef __bf16 bf16x8 __attribute__((ext_vector_type(8)));
typedef float f32x4 __attribute__((ext_vector_type(4)));
typedef float f32x16 __attribute__((ext_vector_type(16)));

__device__ __forceinline__ u16 f2b(float f) {
  union { float f; unsigned u; } x; x.f = f;
  unsigned r = x.u + 0x7FFFu + ((x.u >> 16) & 1u);
  return (u16)(r >> 16);
}

__device__ __forceinline__ unsigned pkbf(float lo, float hi) {
  unsigned r;
  asm("v_cvt_pk_bf16_f32 %0, %1, %2" : "=v"(r) : "v"(lo), "v"(hi));
  return r;
}

__device__ __forceinline__ float expo2(float x) {
#if __has_builtin(__builtin_amdgcn_exp2f)
  return __builtin_amdgcn_exp2f(x);
#else
  return exp2f(x);
#endif
}

#define GLDS16(gp, lp)                                                         \
  __builtin_amdgcn_global_load_lds(                                            \
      (const __attribute__((address_space(1))) void*)(gp),                     \
      (__attribute__((address_space(3))) void*)(lp), 16, 0, 0)

// ---------------- transpose + cast: W[K][N] f32 -> WT[N][K] bf16 ------------
__global__ __launch_bounds__(256) void transpose_cast(
    const float* __restrict__ W, u16* __restrict__ WT, int K, int N) {
  __shared__ float tile[32][33];
  const int tx = threadIdx.x & 31, ty = threadIdx.x >> 5;
  const int n0 = blockIdx.x * 32, k0 = blockIdx.y * 32;
#pragma unroll
  for (int i = 0; i < 4; ++i)
    tile[ty + 8 * i][tx] = W[(size_t)(k0 + ty + 8 * i) * N + n0 + tx];
  __syncthreads();
#pragma unroll
  for (int i = 0; i < 4; ++i)
    WT[(size_t)(n0 + ty + 8 * i) * K + k0 + tx] = f2b(tile[tx][ty + 8 * i]);
}

// ---------------- cast f32 -> bf16 (4 elems/thread) -------------------------
__global__ __launch_bounds__(256) void cast_b(const float* __restrict__ x,
                                              u16* __restrict__ y) {
  int i = blockIdx.x * 256 + threadIdx.x;
  float4 v = ((const float4*)x)[i];
  ushort4 o;
  o.x = f2b(v.x); o.y = f2b(v.y); o.z = f2b(v.z); o.w = f2b(v.w);
  ((ushort4*)y)[i] = o;
}

// ---------------- GEMM: C = A[M,K] @ BT[N,K]^T, bf16, dbuf 1-barrier loop ---
// MODE 2: fp32 out = acc + bias + res
// MODE 3: bf16 out = relu(acc + bias)
// MODE 5: fused QKV epilogues (q-scaled head / k,v fragment-order tiles)
// MODE 6: split-K 2-way partial (grid y: by&31=m-row, by>>5=k-half);
//         f32 partial -> outp (kh=0) or res-cast (kh=1). No bias/res.
template <int MODE, int BN>
__global__ __launch_bounds__(256) void gemmT(
    const u16* __restrict__ A, const u16* __restrict__ BT,
    const float* __restrict__ bias, const float* __restrict__ bias2,
    const float* __restrict__ bias3, const float* __restrict__ res,
    void* __restrict__ outp, const float* __restrict__ kW, int N_, int K_) {
  constexpr int ABYT = 128 * 32 * 2;
  constexpr int BBYT = BN * 32 * 2;
  constexpr int STRIDE = ABYT + BBYT;
  constexpr int MI = (BN == 128) ? 4 : 2;
  __shared__ __align__(16) char SH[2 * STRIDE];
  const int t = threadIdx.x, lane = t & 63, wid = t >> 6;
  // XCD-chunked bijective swizzle (all grids are multiples of 8 blocks)
  const int gx = gridDim.x;
  const int id = blockIdx.y * gx + blockIdx.x;
  const int nb = gx * gridDim.y;
  const int sid = (id & 7) * (nb >> 3) + (id >> 3);
  const int bx = sid % gx;
  int by = sid / gx;
  int kh6 = 0;
  if constexpr (MODE == 6) { kh6 = by >> 5; by &= 31; }
  const int m0 = by * 128, n0 = bx * BN;
  const int wr = (BN == 128) ? (wid >> 1) * 64 : wid * 32;
  const int wc = (BN == 128) ? (wid & 1) * 64 : 0;
  const int lr = lane & 15, lg = lane >> 4;
  const int K = K_;
  const int koff = (MODE == 6) ? kh6 * 2048 : 0;

  f32x4 acc[MI][4] = {};

  const u16* ga0 = A + (size_t)(m0 + (t >> 2)) * K + koff + (t & 3) * 8;
  const u16* ga1 = ga0 + (size_t)64 * K;
  const u16* gb0 = BT + (size_t)(n0 + (t >> 2)) * K + koff + (t & 3) * 8;
  const u16* gb1 = gb0 + (size_t)64 * K;  // only used when BN==128
  const int stA = wid * 1024;

#define STAGE(CUR, KT)                                                         \
  {                                                                            \
    char* l_ = (char*)SH + (CUR) * STRIDE + stA;                               \
    const size_t o_ = (size_t)(KT) * 32;                                       \
    GLDS16(ga0 + o_, l_);                                                      \
    GLDS16(ga1 + o_, l_ + 4096);                                               \
    GLDS16(gb0 + o_, l_ + ABYT);                                               \
    if constexpr (BN == 128) GLDS16(gb1 + o_, l_ + ABYT + 4096);               \
  }

  const int nk = (MODE == 6) ? 64 : (K >> 5);
  STAGE(0, 0);
  __syncthreads();
  int cur = 0;
  for (int kt = 0; kt < nk; ++kt) {
    if (kt + 1 < nk) STAGE(cur ^ 1, kt + 1);
    const char* l = (const char*)SH + cur * STRIDE;
    bf16x8 af[MI], bf[4];
#pragma unroll
    for (int i = 0; i < MI; ++i)
      af[i] = *(const bf16x8*)(l + (wr + i * 16 + lr) * 64 + lg * 16);
#pragma unroll
    for (int i = 0; i < 4; ++i)
      bf[i] = *(const bf16x8*)(l + ABYT + (wc + i * 16 + lr) * 64 + lg * 16);
#pragma unroll
    for (int mi = 0; mi < MI; ++mi)
#pragma unroll
      for (int ni = 0; ni < 4; ++ni)
        acc[mi][ni] = __builtin_amdgcn_mfma_f32_16x16x32_bf16(
            af[mi], bf[ni], acc[mi][ni], 0, 0, 0);
    __syncthreads();
    cur ^= 1;
  }
#undef STAGE

#pragma unroll
  for (int mi = 0; mi < MI; ++mi) {
#pragma unroll
    for (int ni = 0; ni < 4; ++ni) {
      const int row = m0 + wr + mi * 16 + lg * 4;
      const int col = n0 + wc + ni * 16 + lr;
      f32x4 v = acc[mi][ni];
      if constexpr (MODE == 2) {
        const float bv = bias[col];
        float* o = (float*)outp;
#pragma unroll
        for (int r = 0; r < 4; ++r) {
          const int rr = row + r;
          o[(size_t)rr * N_ + col] = v[r] + bv + res[(size_t)rr * N_ + col];
        }
      } else if constexpr (MODE == 3) {
        const float bv = bias[col];
        u16* o = (u16*)outp;
#pragma unroll
        for (int r = 0; r < 4; ++r) {
          const int rr = row + r;
          float y = v[r] + bv;
          o[(size_t)rr * N_ + col] = f2b(y > 0.f ? y : 0.f);
        }
      } else if constexpr (MODE == 6) {
        float* o = (kh6 == 0) ? (float*)outp : (float*)res;
#pragma unroll
        for (int r = 0; r < 4; ++r) {
          const int rr = row + r;
          o[(size_t)rr * N_ + col] = v[r];
        }
      } else {  // MODE 5
        const int proj = col >> 10, c = col & 1023;
        const int h = c >> 5, d = c & 31;
        u16* qout = (u16*)outp;
        if (proj == 0) {
          const float bv = bias[c];
          const float sc = kW[d * 32 + h] * 1.44269504089f;
#pragma unroll
          for (int r = 0; r < 4; ++r) {
            const int rr = row + r;
            const int bb = rr >> 11, s = rr & 2047;
            qout[(size_t)(((bb * 32 + h) * 2048) + s) * 32 + d] =
                f2b((v[r] + bv) * sc);
          }
        } else if (proj == 1) {
          const float bv = bias2[c];
          u16* kout = qout + 4194304;
          const int c2 = d >> 3;
#pragma unroll
          for (int r = 0; r < 4; ++r) {
            const int rr = row + r;
            const int bb = rr >> 11, s = rr & 2047;
            const int k = s & 63;
            const int g = ((k >> 5) << 1) | (c2 >> 1);
            kout[(size_t)(bb * 32 + h) * 65536 + (s >> 6) * 2048 + g * 512 +
                 (c2 & 1) * 256 + (k & 31) * 8 + (d & 7)] = f2b(v[r] + bv);
          }
        } else {
          const float bv = bias3[c];
          u16* vout = qout + 8388608;
          const int bb = row >> 11, s0 = row & 2047;
          const int k = s0 & 63;
          const int cc = k >> 3, rb = cc >> 1, hb = cc & 1, e = k & 7;
          ushort4 st;
          st.x = f2b(v[0] + bv); st.y = f2b(v[1] + bv);
          st.z = f2b(v[2] + bv); st.w = f2b(v[3] + bv);
          *(ushort4*)(vout + (size_t)(bb * 32 + h) * 65536 +
                      (s0 >> 6) * 2048 + rb * 512 + hb * 256 + d * 8 + e) = st;
        }
      }
    }
  }
}

// ---------------- attention tile compute (64 keys) --------------------------
__device__ __forceinline__ void attn_tile(
    const bf16x8& k0, const bf16x8& k1, const bf16x8& k2, const bf16x8& k3,
    const bf16x8& v0, const bf16x8& v1, const bf16x8& v2, const bf16x8& v3,
    const bf16x8& qb0, const bf16x8& qb1,
    f32x16& acc, float& la, float& lb, float& lc, float& ld) {
  const f32x16 z16 = {};
  f32x16 s0 = __builtin_amdgcn_mfma_f32_32x32x16_bf16(k0, qb0, z16, 0, 0, 0);
  s0 = __builtin_amdgcn_mfma_f32_32x32x16_bf16(k1, qb1, s0, 0, 0, 0);
  f32x16 s1 = __builtin_amdgcn_mfma_f32_32x32x16_bf16(k2, qb0, z16, 0, 0, 0);
  s1 = __builtin_amdgcn_mfma_f32_32x32x16_bf16(k3, qb1, s1, 0, 0, 0);
  float p0[16], p1[16];
#pragma unroll
  for (int r = 0; r < 16; ++r) p0[r] = expo2(s0[r]);
#pragma unroll
  for (int r = 0; r < 16; ++r) p1[r] = expo2(s1[r]);
#pragma unroll
  for (int r = 0; r < 4; ++r) {
    la += p0[r] + p1[r];
    lb += p0[4 + r] + p1[4 + r];
    lc += p0[8 + r] + p1[8 + r];
    ld += p0[12 + r] + p1[12 + r];
  }
  {
    u32 x0 = pkbf(p0[0], p0[1]), x1 = pkbf(p0[2], p0[3]);
    u32 y0 = pkbf(p0[4], p0[5]), y1 = pkbf(p0[6], p0[7]);
    asm("v_permlane32_swap_b32 %0, %1" : "+v"(x0), "+v"(y0));
    asm("v_permlane32_swap_b32 %0, %1" : "+v"(x1), "+v"(y1));
    union { u32 d[4]; bf16x8 v; } u;
    u.d[0] = x0; u.d[1] = x1; u.d[2] = y0; u.d[3] = y1;
    acc = __builtin_amdgcn_mfma_f32_32x32x16_bf16(v0, u.v, acc, 0, 0, 0);
  }
  {
    u32 x0 = pkbf(p0[8], p0[9]), x1 = pkbf(p0[10], p0[11]);
    u32 y0 = pkbf(p0[12], p0[13]), y1 = pkbf(p0[14], p0[15]);
    asm("v_permlane32_swap_b32 %0, %1" : "+v"(x0), "+v"(y0));
    asm("v_permlane32_swap_b32 %0, %1" : "+v"(x1), "+v"(y1));
    union { u32 d[4]; bf16x8 v; } u;
    u.d[0] = x0; u.d[1] = x1; u.d[2] = y0; u.d[3] = y1;
    acc = __builtin_amdgcn_mfma_f32_32x32x16_bf16(v1, u.v, acc, 0, 0, 0);
  }
  {
    u32 x0 = pkbf(p1[0], p1[1]), x1 = pkbf(p1[2], p1[3]);
    u32 y0 = pkbf(p1[4], p1[5]), y1 = pkbf(p1[6], p1[7]);
    asm("v_permlane32_swap_b32 %0, %1" : "+v"(x0), "+v"(y0));
    asm("v_permlane32_swap_b32 %0, %1" : "+v"(x1), "+v"(y1));
    union { u32 d[4]; bf16x8 v; } u;
    u.d[0] = x0; u.d[1] = x1; u.d[2] = y0; u.d[3] = y1;
    acc = __builtin_amdgcn_mfma_f32_32x32x16_bf16(v2, u.v, acc, 0, 0, 0);
  }
  {
    u32 x0 = pkbf(p1[8], p1[9]), x1 = pkbf(p1[10], p1[11]);
    u32 y0 = pkbf(p1[12], p1[13]), y1 = pkbf(p1[14], p1[15]);
    asm("v_permlane32_swap_b32 %0, %1" : "+v"(x0), "+v"(y0));
    asm("v_permlane32_swap_b32 %0, %1" : "+v"(x1), "+v"(y1));
    union { u32 d[4]; bf16x8 v; } u;
    u.d[0] = x0; u.d[1] = x1; u.d[2] = y0; u.d[3] = y1;
    acc = __builtin_amdgcn_mfma_f32_32x32x16_bf16(v3, u.v, acc, 0, 0, 0);
  }
}

// ---------------- swapped 32x32 flash attention, LDS-staged -----------------
__global__ __launch_bounds__(256) void attn_kernel(
    const u16* __restrict__ Q, const u16* __restrict__ K,
    const u16* __restrict__ VT, u16* __restrict__ O) {
  __shared__ __align__(16) char LDSB[32768];
  const int t = threadIdx.x, wid = t >> 6, lane = t & 63;
  const int qg = wid & 1, kh = wid >> 1;
  const int bid = blockIdx.x;
  const int swz = (bid & 7) * 256 + (bid >> 3);  // 2048 blocks, 8 XCDs
  const int bh = swz >> 5;
  const int qt = swz & 31;
  const int q0 = qt * 64 + qg * 32;
  const int lq = lane & 31, hi = lane >> 5;
  const u16* Qh = Q + (size_t)bh * 65536;
  const u16* Kh = K + (size_t)bh * 65536;
  const u16* Vh = VT + (size_t)bh * 65536;

  const bf16x8 qb0 = *(const bf16x8*)(Qh + (size_t)(q0 + lq) * 32 + hi * 8);
  const bf16x8 qb1 = *(const bf16x8*)(Qh + (size_t)(q0 + lq) * 32 + 16 + hi * 8);

  const u16* kg = Kh + wid * 512 + lane * 8;
  const u16* vg = Vh + wid * 512 + lane * 8;
  const int lds_w = wid * 1024;

#define STAGEA(CUR, I)                                                         \
  {                                                                            \
    char* b_ = LDSB + (CUR) * 16384 + lds_w;                                   \
    GLDS16(kg + (size_t)(I) * 2048, b_);                                       \
    GLDS16(vg + (size_t)(I) * 2048, b_ + 4096);                                \
    GLDS16(kg + (size_t)(16 + (I)) * 2048, b_ + 8192);                         \
    GLDS16(vg + (size_t)(16 + (I)) * 2048, b_ + 12288);                        \
  }

  f32x16 acc = {};
  float la = 0.f, lb = 0.f, lc = 0.f, ld = 0.f;

  STAGEA(0, 0);
  __syncthreads();
  int cur = 0;
#pragma unroll 1
  for (int i = 0; i < 16; ++i) {
    if (i < 15) STAGEA(cur ^ 1, i + 1);
    const char* kb = LDSB + cur * 16384 + kh * 8192 + lane * 16;
    const bf16x8 ka0 = *(const bf16x8*)(kb);
    const bf16x8 ka1 = *(const bf16x8*)(kb + 1024);
    const bf16x8 ka2 = *(const bf16x8*)(kb + 2048);
    const bf16x8 ka3 = *(const bf16x8*)(kb + 3072);
    const bf16x8 va0 = *(const bf16x8*)(kb + 4096);
    const bf16x8 va1 = *(const bf16x8*)(kb + 5120);
    const bf16x8 va2 = *(const bf16x8*)(kb + 6144);
    const bf16x8 va3 = *(const bf16x8*)(kb + 7168);
    attn_tile(ka0, ka1, ka2, ka3, va0, va1, va2, va3, qb0, qb1,
              acc, la, lb, lc, ld);
    __syncthreads();
    cur ^= 1;
  }
#undef STAGEA

  float lrun = (la + lb) + (lc + ld);
  lrun += __shfl_xor(lrun, 32);

  float* sm_acc = (float*)LDSB;
  float* sm_l = (float*)(LDSB + 8192);
  if (kh == 1) {
    sm_l[qg * 32 + lq] = lrun;
#pragma unroll
    for (int r = 0; r < 16; ++r) sm_acc[(qg * 64 + lane) * 16 + r] = acc[r];
  }
  __syncthreads();
  if (kh == 0) {
    const float inv = 1.f / (lrun + sm_l[qg * 32 + lq]);
    const int bb = bh >> 5, h = bh & 31;
    u16* o = O + (size_t)(bb * 2048 + q0 + lq) * 1024 + h * 32;
#pragma unroll
    for (int g = 0; g < 4; ++g) {
      ushort4 st;
      st.x = f2b((acc[g * 4 + 0] + sm_acc[(qg * 64 + lane) * 16 + g * 4 + 0]) * inv);
      st.y = f2b((acc[g * 4 + 1] + sm_acc[(qg * 64 + lane) * 16 + g * 4 + 1]) * inv);
      st.z = f2b((acc[g * 4 + 2] + sm_acc[(qg * 64 + lane) * 16 + g * 4 + 2]) * inv);
      st.w = f2b((acc[g * 4 + 3] + sm_acc[(qg * 64 + lane) * 16 + g * 4 + 3]) * inv);
      *(ushort4*)(o + g * 8 + hi * 4) = st;
    }
  }
}

// ---------------- LayerNorm (1 wave per row of 1024) ------------------------
template <int WB>
__global__ __launch_bounds__(256) void ln_kernel(
    const float* X, const float* __restrict__ g, const float* __restrict__ b,
    float* outf, u16* __restrict__ outb) {
  const int wid = threadIdx.x >> 6, lane = threadIdx.x & 63;
  const int row = blockIdx.x * 4 + wid;
  const float4* X4 = (const float4*)(X + (size_t)row * 1024);
  float4 xs[4];
  float s = 0.f, sq = 0.f;
#pragma unroll
  for (int i = 0; i < 4; ++i) {
    xs[i] = X4[lane + i * 64];
    s += xs[i].x + xs[i].y + xs[i].z + xs[i].w;
    sq += xs[i].x * xs[i].x + xs[i].y * xs[i].y + xs[i].z * xs[i].z + xs[i].w * xs[i].w;
  }
#pragma unroll
  for (int m = 1; m < 64; m <<= 1) { s += __shfl_xor(s, m); sq += __shfl_xor(sq, m); }
  const float mean = s * (1.f / 1024.f);
  float var = sq * (1.f / 1024.f) - mean * mean;
  var = var > 0.f ? var : 0.f;
  const float rstd = rsqrtf(var + 1e-5f);
  const float4* g4 = (const float4*)g;
  const float4* b4 = (const float4*)b;
  float4* of = (float4*)(outf + (size_t)row * 1024);
#pragma unroll
  for (int i = 0; i < 4; ++i) {
    const int c = lane + i * 64;
    const float4 gv = g4[c], bv = b4[c], x = xs[i];
    float4 y;
    y.x = (x.x - mean) * rstd * gv.x + bv.x;
    y.y = (x.y - mean) * rstd * gv.y + bv.y;
    y.z = (x.z - mean) * rstd * gv.z + bv.z;
    y.w = (x.w - mean) * rstd * gv.w + bv.w;
    of[c] = y;
    if constexpr (WB) {
      ushort4 yb;
      yb.x = f2b(y.x); yb.y = f2b(y.y); yb.z = f2b(y.z); yb.w = f2b(y.w);
      ((ushort4*)(outb + (size_t)row * 1024))[c] = yb;
    }
  }
}

// ---------------- LN2 with 4-way sum: x = pa + pb + res + bias --------------
__global__ __launch_bounds__(256) void ln2sum_kernel(
    const float* __restrict__ PA, const float* __restrict__ PB,
    const float* __restrict__ R, const float* __restrict__ bias,
    const float* __restrict__ g, const float* __restrict__ b,
    float* __restrict__ out) {
  const int wid = threadIdx.x >> 6, lane = threadIdx.x & 63;
  const int row = blockIdx.x * 4 + wid;
  const float4* A4 = (const float4*)(PA + (size_t)row * 1024);
  const float4* B4 = (const float4*)(PB + (size_t)row * 1024);
  const float4* R4 = (const float4*)(R + (size_t)row * 1024);
  const float4* Bi4 = (const float4*)bias;
  float4 xs[4];
  float s = 0.f, sq = 0.f;
#pragma unroll
  for (int i = 0; i < 4; ++i) {
    const int c = lane + i * 64;
    const float4 a = A4[c], pb = B4[c], r = R4[c], bi = Bi4[c];
    float4 x;
    x.x = a.x + pb.x + r.x + bi.x;
    x.y = a.y + pb.y + r.y + bi.y;
    x.z = a.z + pb.z + r.z + bi.z;
    x.w = a.w + pb.w + r.w + bi.w;
    xs[i] = x;
    s += x.x + x.y + x.z + x.w;
    sq += x.x * x.x + x.y * x.y + x.z * x.z + x.w * x.w;
  }
#pragma unroll
  for (int m = 1; m < 64; m <<= 1) { s += __shfl_xor(s, m); sq += __shfl_xor(sq, m); }
  const float mean = s * (1.f / 1024.f);
  float var = sq * (1.f / 1024.f) - mean * mean;
  var = var > 0.f ? var : 0.f;
  const float rstd = rsqrtf(var + 1e-5f);
  const float4* g4 = (const float4*)g;
  const float4* b4 = (const float4*)b;
  float4* of = (float4*)(out + (size_t)row * 1024);
#pragma unroll
  for (int i = 0; i < 4; ++i) {
    const int c = lane + i * 64;
    const float4 gv = g4[c], bv = b4[c], x = xs[i];
    float4 y;
    y.x = (x.x - mean) * rstd * gv.x + bv.x;
    y.y = (x.y - mean) * rstd * gv.y + bv.y;
    y.z = (x.z - mean) * rstd * gv.z + bv.z;
    y.w = (x.w - mean) * rstd * gv.w + bv.w;
    of[c] = y;
  }
}

// ---------------------------------------------------------------------------
extern "C" void kernel_launch(void* const* d_in, const int* in_sizes, int n_in,
                              void* d_out, int out_size, void* d_ws,
                              size_t ws_size, hipStream_t stream) {
  const float* x   = (const float*)d_in[0];
  const float* Wq  = (const float*)d_in[1];
  const float* bq  = (const float*)d_in[2];
  const float* Wk  = (const float*)d_in[3];
  const float* bk  = (const float*)d_in[4];
  const float* Wv  = (const float*)d_in[5];
  const float* bv  = (const float*)d_in[6];
  const float* kW  = (const float*)d_in[7];
  const float* Wo  = (const float*)d_in[8];
  const float* bo  = (const float*)d_in[9];
  const float* W1  = (const float*)d_in[10];
  const float* b1  = (const float*)d_in[11];
  const float* W2  = (const float*)d_in[12];
  const float* b2  = (const float*)d_in[13];
  const float* g1  = (const float*)d_in[14];
  const float* be1 = (const float*)d_in[15];
  const float* g2  = (const float*)d_in[16];
  const float* be2 = (const float*)d_in[17];

  char* ws = (char*)d_ws;
  const size_t MB = 1024 * 1024;
  u16*   WqT = (u16*)(ws + 0 * MB);   // [0,6) = fused QKV BT[3072][1024]
  u16*   WoT = (u16*)(ws + 6 * MB);
  u16*   W1T = (u16*)(ws + 8 * MB);
  u16*   W2T = (u16*)(ws + 16 * MB);
  float* r1  = (float*)(ws + 24 * MB);
  u16*   xb  = (u16*)(ws + 40 * MB);
  u16*   qhB = (u16*)(ws + 48 * MB);
  u16*   khB = (u16*)(ws + 56 * MB);
  u16*   vTB = (u16*)(ws + 64 * MB);
  u16*   hf  = (u16*)(ws + 40 * MB);   // aliases xb..vT, free by then
  u16*   ao  = (u16*)(ws + 72 * MB);
  u16*   x1b = (u16*)(ws + 80 * MB);
  float* r2a = (float*)(ws + 0 * MB);  // aliases QKV-T/WoT/W1T (dead by FFN2)
  float* r2b = (float*)(ws + 72 * MB); // aliases ao+x1b (dead by FFN2)

  const dim3 blk(256);

  transpose_cast<<<dim3(32, 32), blk, 0, stream>>>(Wq, WqT, 1024, 1024);
  transpose_cast<<<dim3(32, 32), blk, 0, stream>>>(Wk, WqT + 1048576, 1024, 1024);
  transpose_cast<<<dim3(32, 32), blk, 0, stream>>>(Wv, WqT + 2097152, 1024, 1024);
  transpose_cast<<<dim3(32, 32), blk, 0, stream>>>(Wo, WoT, 1024, 1024);
  transpose_cast<<<dim3(128, 32), blk, 0, stream>>>(W1, W1T, 1024, 4096);
  transpose_cast<<<dim3(32, 128), blk, 0, stream>>>(W2, W2T, 4096, 1024);
  cast_b<<<4096, blk, 0, stream>>>(x, xb);

  // fused QKV projection (q scaled by kernelW*log2e; k,v fragment-tiled)
  gemmT<5, 128><<<dim3(24, 32), blk, 0, stream>>>(
      xb, WqT, bq, bk, bv, nullptr, qhB, kW, 3072, 1024);

  // flash attention: 2048 blocks x 4 waves (2 qg x 2 key-halves), LDS-staged
  attn_kernel<<<2048, blk, 0, stream>>>(qhB, khB, vTB, ao);

  // out-proj + residual -> r1 (fp32)
  gemmT<2, 64><<<dim3(16, 32), blk, 0, stream>>>(
      ao, WoT, bo, nullptr, nullptr, x, r1, nullptr, 1024, 1024);
  ln_kernel<1><<<1024, blk, 0, stream>>>(r1, g1, be1, r1, x1b);
  // FFN1
  gemmT<3, 128><<<dim3(32, 32), blk, 0, stream>>>(
      x1b, W1T, b1, nullptr, nullptr, nullptr, hf, nullptr, 4096, 1024);
  // FFN2: split-K 2-way, f32 partials to r2a/r2b (1024 blocks)
  gemmT<6, 64><<<dim3(16, 64), blk, 0, stream>>>(
      hf, W2T, nullptr, nullptr, nullptr, r2b, r2a, nullptr, 1024, 4096);
  // LN2 merges partials + residual + bias
  ln2sum_kernel<<<1024, blk, 0, stream>>>(r2a, r2b, r1, b2, g2, be2,
                                          (float*)d_out);

  (void)in_sizes; (void)n_in; (void)out_size; (void)ws_size;
}

// Round 12
// 258.589 us; speedup vs baseline: 1.3913x; 1.0460x over previous
//
#include <hip/hip_runtime.h>

// ---------------------------------------------------------------------------
// TransformerBlockQuantum: B=2,S=2048,E=1024,H=32,DK=32,FFN=4096
// GEMMs: bf16 MFMA 16x16x32, LDS double-buffer, single-barrier K-loop,
// XCD-chunked block swizzle. FFN2 = split-K 2-way (f32 partials, ln2sum).
// Attention: 8-wave blocks (4 qg x 2 kh), LDS-staged fragment-order K/V
// tiles (32KB dbuf serves 128 queries), swapped 32x32 QK^T, unshifted exp2.
// ws layout (MB):
//  [0,6) QKV BT  [6,8)WoT [8,16)W1T [16,24)W2T
//  [24,40) r1    [40,72) xb/qh/kh/vT then hf   [72,88) ao/x1b then r2b
//  r2a aliases [0,16)
// ---------------------------------------------------------------------------

typedef unsigned short u16;
typedef unsigned int u32;
typedef __bf16 bf16x8 __attribute__((ext_vector_type(8)));
typedef float f32x4 __attribute__((ext_vector_type(4)));
typedef float f32x16 __attribute__((ext_vector_type(16)));

__device__ __forceinline__ u16 f2b(float f) {
  union { float f; unsigned u; } x; x.f = f;
  unsigned r = x.u + 0x7FFFu + ((x.u >> 16) & 1u);
  return (u16)(r >> 16);
}

__device__ __forceinline__ unsigned pkbf(float lo, float hi) {
  unsigned r;
  asm("v_cvt_pk_bf16_f32 %0, %1, %2" : "=v"(r) : "v"(lo), "v"(hi));
  return r;
}

__device__ __forceinline__ float expo2(float x) {
#if __has_builtin(__builtin_amdgcn_exp2f)
  return __builtin_amdgcn_exp2f(x);
#else
  return exp2f(x);
#endif
}

#define GLDS16(gp, lp)                                                         \
  __builtin_amdgcn_global_load_lds(                                            \
      (const __attribute__((address_space(1))) void*)(gp),                     \
      (__attribute__((address_space(3))) void*)(lp), 16, 0, 0)

// ---------------- transpose + cast: W[K][N] f32 -> WT[N][K] bf16 ------------
__global__ __launch_bounds__(256) void transpose_cast(
    const float* __restrict__ W, u16* __restrict__ WT, int K, int N) {
  __shared__ float tile[32][33];
  const int tx = threadIdx.x & 31, ty = threadIdx.x >> 5;
  const int n0 = blockIdx.x * 32, k0 = blockIdx.y * 32;
#pragma unroll
  for (int i = 0; i < 4; ++i)
    tile[ty + 8 * i][tx] = W[(size_t)(k0 + ty + 8 * i) * N + n0 + tx];
  __syncthreads();
#pragma unroll
  for (int i = 0; i < 4; ++i)
    WT[(size_t)(n0 + ty + 8 * i) * K + k0 + tx] = f2b(tile[tx][ty + 8 * i]);
}

// ---------------- cast f32 -> bf16 (4 elems/thread) -------------------------
__global__ __launch_bounds__(256) void cast_b(const float* __restrict__ x,
                                              u16* __restrict__ y) {
  int i = blockIdx.x * 256 + threadIdx.x;
  float4 v = ((const float4*)x)[i];
  ushort4 o;
  o.x = f2b(v.x); o.y = f2b(v.y); o.z = f2b(v.z); o.w = f2b(v.w);
  ((ushort4*)y)[i] = o;
}

// ---------------- GEMM: C = A[M,K] @ BT[N,K]^T, bf16, dbuf 1-barrier loop ---
// MODE 2: fp32 out = acc + bias + res
// MODE 3: bf16 out = relu(acc + bias)
// MODE 5: fused QKV epilogues (q-scaled head / k,v fragment-order tiles)
// MODE 6: split-K 2-way partial -> outp (kh=0) or res (kh=1), f32, no bias.
template <int MODE, int BN>
__global__ __launch_bounds__(256) void gemmT(
    const u16* __restrict__ A, const u16* __restrict__ BT,
    const float* __restrict__ bias, const float* __restrict__ bias2,
    const float* __restrict__ bias3, const float* __restrict__ res,
    void* __restrict__ outp, const float* __restrict__ kW, int N_, int K_) {
  constexpr int ABYT = 128 * 32 * 2;
  constexpr int BBYT = BN * 32 * 2;
  constexpr int STRIDE = ABYT + BBYT;
  constexpr int MI = (BN == 128) ? 4 : 2;
  __shared__ __align__(16) char SH[2 * STRIDE];
  const int t = threadIdx.x, lane = t & 63, wid = t >> 6;
  const int gx = gridDim.x;
  const int id = blockIdx.y * gx + blockIdx.x;
  const int nb = gx * gridDim.y;
  const int sid = (id & 7) * (nb >> 3) + (id >> 3);
  const int bx = sid % gx;
  int by = sid / gx;
  int kh6 = 0;
  if constexpr (MODE == 6) { kh6 = by >> 5; by &= 31; }
  const int m0 = by * 128, n0 = bx * BN;
  const int wr = (BN == 128) ? (wid >> 1) * 64 : wid * 32;
  const int wc = (BN == 128) ? (wid & 1) * 64 : 0;
  const int lr = lane & 15, lg = lane >> 4;
  const int K = K_;
  const int koff = (MODE == 6) ? kh6 * 2048 : 0;

  f32x4 acc[MI][4] = {};

  const u16* ga0 = A + (size_t)(m0 + (t >> 2)) * K + koff + (t & 3) * 8;
  const u16* ga1 = ga0 + (size_t)64 * K;
  const u16* gb0 = BT + (size_t)(n0 + (t >> 2)) * K + koff + (t & 3) * 8;
  const u16* gb1 = gb0 + (size_t)64 * K;
  const int stA = wid * 1024;

#define STAGE(CUR, KT)                                                         \
  {                                                                            \
    char* l_ = (char*)SH + (CUR) * STRIDE + stA;                               \
    const size_t o_ = (size_t)(KT) * 32;                                       \
    GLDS16(ga0 + o_, l_);                                                      \
    GLDS16(ga1 + o_, l_ + 4096);                                               \
    GLDS16(gb0 + o_, l_ + ABYT);                                               \
    if constexpr (BN == 128) GLDS16(gb1 + o_, l_ + ABYT + 4096);               \
  }

  const int nk = (MODE == 6) ? 64 : (K >> 5);
  STAGE(0, 0);
  __syncthreads();
  int cur = 0;
  for (int kt = 0; kt < nk; ++kt) {
    if (kt + 1 < nk) STAGE(cur ^ 1, kt + 1);
    const char* l = (const char*)SH + cur * STRIDE;
    bf16x8 af[MI], bf[4];
#pragma unroll
    for (int i = 0; i < MI; ++i)
      af[i] = *(const bf16x8*)(l + (wr + i * 16 + lr) * 64 + lg * 16);
#pragma unroll
    for (int i = 0; i < 4; ++i)
      bf[i] = *(const bf16x8*)(l + ABYT + (wc + i * 16 + lr) * 64 + lg * 16);
#pragma unroll
    for (int mi = 0; mi < MI; ++mi)
#pragma unroll
      for (int ni = 0; ni < 4; ++ni)
        acc[mi][ni] = __builtin_amdgcn_mfma_f32_16x16x32_bf16(
            af[mi], bf[ni], acc[mi][ni], 0, 0, 0);
    __syncthreads();
    cur ^= 1;
  }
#undef STAGE

#pragma unroll
  for (int mi = 0; mi < MI; ++mi) {
#pragma unroll
    for (int ni = 0; ni < 4; ++ni) {
      const int row = m0 + wr + mi * 16 + lg * 4;
      const int col = n0 + wc + ni * 16 + lr;
      f32x4 v = acc[mi][ni];
      if constexpr (MODE == 2) {
        const float bv = bias[col];
        float* o = (float*)outp;
#pragma unroll
        for (int r = 0; r < 4; ++r) {
          const int rr = row + r;
          o[(size_t)rr * N_ + col] = v[r] + bv + res[(size_t)rr * N_ + col];
        }
      } else if constexpr (MODE == 3) {
        const float bv = bias[col];
        u16* o = (u16*)outp;
#pragma unroll
        for (int r = 0; r < 4; ++r) {
          const int rr = row + r;
          float y = v[r] + bv;
          o[(size_t)rr * N_ + col] = f2b(y > 0.f ? y : 0.f);
        }
      } else if constexpr (MODE == 6) {
        float* o = (kh6 == 0) ? (float*)outp : (float*)res;
#pragma unroll
        for (int r = 0; r < 4; ++r) {
          const int rr = row + r;
          o[(size_t)rr * N_ + col] = v[r];
        }
      } else {  // MODE 5
        const int proj = col >> 10, c = col & 1023;
        const int h = c >> 5, d = c & 31;
        u16* qout = (u16*)outp;
        if (proj == 0) {
          const float bv = bias[c];
          const float sc = kW[d * 32 + h] * 1.44269504089f;
#pragma unroll
          for (int r = 0; r < 4; ++r) {
            const int rr = row + r;
            const int bb = rr >> 11, s = rr & 2047;
            qout[(size_t)(((bb * 32 + h) * 2048) + s) * 32 + d] =
                f2b((v[r] + bv) * sc);
          }
        } else if (proj == 1) {
          const float bv = bias2[c];
          u16* kout = qout + 4194304;
          const int c2 = d >> 3;
#pragma unroll
          for (int r = 0; r < 4; ++r) {
            const int rr = row + r;
            const int bb = rr >> 11, s = rr & 2047;
            const int k = s & 63;
            const int g = ((k >> 5) << 1) | (c2 >> 1);
            kout[(size_t)(bb * 32 + h) * 65536 + (s >> 6) * 2048 + g * 512 +
                 (c2 & 1) * 256 + (k & 31) * 8 + (d & 7)] = f2b(v[r] + bv);
          }
        } else {
          const float bv = bias3[c];
          u16* vout = qout + 8388608;
          const int bb = row >> 11, s0 = row & 2047;
          const int k = s0 & 63;
          const int cc = k >> 3, rb = cc >> 1, hb = cc & 1, e = k & 7;
          ushort4 st;
          st.x = f2b(v[0] + bv); st.y = f2b(v[1] + bv);
          st.z = f2b(v[2] + bv); st.w = f2b(v[3] + bv);
          *(ushort4*)(vout + (size_t)(bb * 32 + h) * 65536 +
                      (s0 >> 6) * 2048 + rb * 512 + hb * 256 + d * 8 + e) = st;
        }
      }
    }
  }
}

// ---------------- attention tile compute (64 keys) --------------------------
__device__ __forceinline__ void attn_tile(
    const bf16x8& k0, const bf16x8& k1, const bf16x8& k2, const bf16x8& k3,
    const bf16x8& v0, const bf16x8& v1, const bf16x8& v2, const bf16x8& v3,
    const bf16x8& qb0, const bf16x8& qb1,
    f32x16& acc, float& la, float& lb, float& lc, float& ld) {
  const f32x16 z16 = {};
  f32x16 s0 = __builtin_amdgcn_mfma_f32_32x32x16_bf16(k0, qb0, z16, 0, 0, 0);
  s0 = __builtin_amdgcn_mfma_f32_32x32x16_bf16(k1, qb1, s0, 0, 0, 0);
  f32x16 s1 = __builtin_amdgcn_mfma_f32_32x32x16_bf16(k2, qb0, z16, 0, 0, 0);
  s1 = __builtin_amdgcn_mfma_f32_32x32x16_bf16(k3, qb1, s1, 0, 0, 0);
  float p0[16], p1[16];
#pragma unroll
  for (int r = 0; r < 16; ++r) p0[r] = expo2(s0[r]);
#pragma unroll
  for (int r = 0; r < 16; ++r) p1[r] = expo2(s1[r]);
#pragma unroll
  for (int r = 0; r < 4; ++r) {
    la += p0[r] + p1[r];
    lb += p0[4 + r] + p1[4 + r];
    lc += p0[8 + r] + p1[8 + r];
    ld += p0[12 + r] + p1[12 + r];
  }
  {
    u32 x0 = pkbf(p0[0], p0[1]), x1 = pkbf(p0[2], p0[3]);
    u32 y0 = pkbf(p0[4], p0[5]), y1 = pkbf(p0[6], p0[7]);
    asm("v_permlane32_swap_b32 %0, %1" : "+v"(x0), "+v"(y0));
    asm("v_permlane32_swap_b32 %0, %1" : "+v"(x1), "+v"(y1));
    union { u32 d[4]; bf16x8 v; } u;
    u.d[0] = x0; u.d[1] = x1; u.d[2] = y0; u.d[3] = y1;
    acc = __builtin_amdgcn_mfma_f32_32x32x16_bf16(v0, u.v, acc, 0, 0, 0);
  }
  {
    u32 x0 = pkbf(p0[8], p0[9]), x1 = pkbf(p0[10], p0[11]);
    u32 y0 = pkbf(p0[12], p0[13]), y1 = pkbf(p0[14], p0[15]);
    asm("v_permlane32_swap_b32 %0, %1" : "+v"(x0), "+v"(y0));
    asm("v_permlane32_swap_b32 %0, %1" : "+v"(x1), "+v"(y1));
    union { u32 d[4]; bf16x8 v; } u;
    u.d[0] = x0; u.d[1] = x1; u.d[2] = y0; u.d[3] = y1;
    acc = __builtin_amdgcn_mfma_f32_32x32x16_bf16(v1, u.v, acc, 0, 0, 0);
  }
  {
    u32 x0 = pkbf(p1[0], p1[1]), x1 = pkbf(p1[2], p1[3]);
    u32 y0 = pkbf(p1[4], p1[5]), y1 = pkbf(p1[6], p1[7]);
    asm("v_permlane32_swap_b32 %0, %1" : "+v"(x0), "+v"(y0));
    asm("v_permlane32_swap_b32 %0, %1" : "+v"(x1), "+v"(y1));
    union { u32 d[4]; bf16x8 v; } u;
    u.d[0] = x0; u.d[1] = x1; u.d[2] = y0; u.d[3] = y1;
    acc = __builtin_amdgcn_mfma_f32_32x32x16_bf16(v2, u.v, acc, 0, 0, 0);
  }
  {
    u32 x0 = pkbf(p1[8], p1[9]), x1 = pkbf(p1[10], p1[11]);
    u32 y0 = pkbf(p1[12], p1[13]), y1 = pkbf(p1[14], p1[15]);
    asm("v_permlane32_swap_b32 %0, %1" : "+v"(x0), "+v"(y0));
    asm("v_permlane32_swap_b32 %0, %1" : "+v"(x1), "+v"(y1));
    union { u32 d[4]; bf16x8 v; } u;
    u.d[0] = x0; u.d[1] = x1; u.d[2] = y0; u.d[3] = y1;
    acc = __builtin_amdgcn_mfma_f32_32x32x16_bf16(v3, u.v, acc, 0, 0, 0);
  }
}

// ---------------- swapped 32x32 flash attention, LDS-staged, 8 waves --------
// Block = 8 waves: qg = wid&3 (32 queries each, 128 total), kh = wid>>2
// (1024 keys each). Waves 0-3 stage K/V fragment-tiles (32KB dbuf shared by
// all 8 waves -> K/V L2 traffic halved vs 4-wave version).
__global__ __launch_bounds__(512) void attn_kernel(
    const u16* __restrict__ Q, const u16* __restrict__ K,
    const u16* __restrict__ VT, u16* __restrict__ O) {
  __shared__ __align__(16) char LDSB[32768];
  const int t = threadIdx.x, wid = t >> 6, lane = t & 63;
  const int qg = wid & 3, kh = wid >> 2;
  const int bid = blockIdx.x;                    // 1024 blocks
  const int swz = (bid & 7) * 128 + (bid >> 3);  // 8 XCDs
  const int bh = swz >> 4;                       // 0..63
  const int qt = swz & 15;                       // q-tile of 128
  const int q0 = qt * 128 + qg * 32;
  const int lq = lane & 31, hi = lane >> 5;
  const u16* Qh = Q + (size_t)bh * 65536;
  const u16* Kh = K + (size_t)bh * 65536;
  const u16* Vh = VT + (size_t)bh * 65536;

  const bf16x8 qb0 = *(const bf16x8*)(Qh + (size_t)(q0 + lq) * 32 + hi * 8);
  const bf16x8 qb1 = *(const bf16x8*)(Qh + (size_t)(q0 + lq) * 32 + 16 + hi * 8);

  // staging (waves 0-3): wave w covers quarter w of each 4KB region.
  const u16* kg = Kh + wid * 512 + lane * 8;
  const u16* vg = Vh + wid * 512 + lane * 8;
  const int lds_w = wid * 1024;

#define STAGEA(CUR, I)                                                         \
  if (wid < 4) {                                                               \
    char* b_ = LDSB + (CUR) * 16384 + lds_w;                                   \
    GLDS16(kg + (size_t)(I) * 2048, b_);                                       \
    GLDS16(vg + (size_t)(I) * 2048, b_ + 4096);                                \
    GLDS16(kg + (size_t)(16 + (I)) * 2048, b_ + 8192);                         \
    GLDS16(vg + (size_t)(16 + (I)) * 2048, b_ + 12288);                        \
  }

  f32x16 acc = {};
  float la = 0.f, lb = 0.f, lc = 0.f, ld = 0.f;

  STAGEA(0, 0);
  __syncthreads();
  int cur = 0;
#pragma unroll 1
  for (int i = 0; i < 16; ++i) {
    if (i < 15) STAGEA(cur ^ 1, i + 1);
    const char* kb = LDSB + cur * 16384 + kh * 8192 + lane * 16;
    const bf16x8 ka0 = *(const bf16x8*)(kb);
    const bf16x8 ka1 = *(const bf16x8*)(kb + 1024);
    const bf16x8 ka2 = *(const bf16x8*)(kb + 2048);
    const bf16x8 ka3 = *(const bf16x8*)(kb + 3072);
    const bf16x8 va0 = *(const bf16x8*)(kb + 4096);
    const bf16x8 va1 = *(const bf16x8*)(kb + 5120);
    const bf16x8 va2 = *(const bf16x8*)(kb + 6144);
    const bf16x8 va3 = *(const bf16x8*)(kb + 7168);
    attn_tile(ka0, ka1, ka2, ka3, va0, va1, va2, va3, qb0, qb1,
              acc, la, lb, lc, ld);
    __syncthreads();
    cur ^= 1;
  }
#undef STAGEA

  float lrun = (la + lb) + (lc + ld);
  lrun += __shfl_xor(lrun, 32);

  // merge scratch aliases staging LDS (dead after final loop barrier)
  float* sm_acc = (float*)LDSB;            // [4][64][16] = 16KB
  float* sm_l = (float*)(LDSB + 16384);    // [4][32]
  if (kh == 1) {
    sm_l[qg * 32 + lq] = lrun;
#pragma unroll
    for (int r = 0; r < 16; ++r) sm_acc[(qg * 64 + lane) * 16 + r] = acc[r];
  }
  __syncthreads();
  if (kh == 0) {
    const float inv = 1.f / (lrun + sm_l[qg * 32 + lq]);
    const int bb = bh >> 5, h = bh & 31;
    u16* o = O + (size_t)(bb * 2048 + q0 + lq) * 1024 + h * 32;
#pragma unroll
    for (int g = 0; g < 4; ++g) {
      ushort4 st;
      st.x = f2b((acc[g * 4 + 0] + sm_acc[(qg * 64 + lane) * 16 + g * 4 + 0]) * inv);
      st.y = f2b((acc[g * 4 + 1] + sm_acc[(qg * 64 + lane) * 16 + g * 4 + 1]) * inv);
      st.z = f2b((acc[g * 4 + 2] + sm_acc[(qg * 64 + lane) * 16 + g * 4 + 2]) * inv);
      st.w = f2b((acc[g * 4 + 3] + sm_acc[(qg * 64 + lane) * 16 + g * 4 + 3]) * inv);
      *(ushort4*)(o + g * 8 + hi * 4) = st;
    }
  }
}

// ---------------- LayerNorm (1 wave per row of 1024) ------------------------
template <int WB>
__global__ __launch_bounds__(256) void ln_kernel(
    const float* X, const float* __restrict__ g, const float* __restrict__ b,
    float* outf, u16* __restrict__ outb) {
  const int wid = threadIdx.x >> 6, lane = threadIdx.x & 63;
  const int row = blockIdx.x * 4 + wid;
  const float4* X4 = (const float4*)(X + (size_t)row * 1024);
  float4 xs[4];
  float s = 0.f, sq = 0.f;
#pragma unroll
  for (int i = 0; i < 4; ++i) {
    xs[i] = X4[lane + i * 64];
    s += xs[i].x + xs[i].y + xs[i].z + xs[i].w;
    sq += xs[i].x * xs[i].x + xs[i].y * xs[i].y + xs[i].z * xs[i].z + xs[i].w * xs[i].w;
  }
#pragma unroll
  for (int m = 1; m < 64; m <<= 1) { s += __shfl_xor(s, m); sq += __shfl_xor(sq, m); }
  const float mean = s * (1.f / 1024.f);
  float var = sq * (1.f / 1024.f) - mean * mean;
  var = var > 0.f ? var : 0.f;
  const float rstd = rsqrtf(var + 1e-5f);
  const float4* g4 = (const float4*)g;
  const float4* b4 = (const float4*)b;
  float4* of = (float4*)(outf + (size_t)row * 1024);
#pragma unroll
  for (int i = 0; i < 4; ++i) {
    const int c = lane + i * 64;
    const float4 gv = g4[c], bv = b4[c], x = xs[i];
    float4 y;
    y.x = (x.x - mean) * rstd * gv.x + bv.x;
    y.y = (x.y - mean) * rstd * gv.y + bv.y;
    y.z = (x.z - mean) * rstd * gv.z + bv.z;
    y.w = (x.w - mean) * rstd * gv.w + bv.w;
    of[c] = y;
    if constexpr (WB) {
      ushort4 yb;
      yb.x = f2b(y.x); yb.y = f2b(y.y); yb.z = f2b(y.z); yb.w = f2b(y.w);
      ((ushort4*)(outb + (size_t)row * 1024))[c] = yb;
    }
  }
}

// ---------------- LN2 with 4-way sum: x = pa + pb + res + bias --------------
__global__ __launch_bounds__(256) void ln2sum_kernel(
    const float* __restrict__ PA, const float* __restrict__ PB,
    const float* __restrict__ R, const float* __restrict__ bias,
    const float* __restrict__ g, const float* __restrict__ b,
    float* __restrict__ out) {
  const int wid = threadIdx.x >> 6, lane = threadIdx.x & 63;
  const int row = blockIdx.x * 4 + wid;
  const float4* A4 = (const float4*)(PA + (size_t)row * 1024);
  const float4* B4 = (const float4*)(PB + (size_t)row * 1024);
  const float4* R4 = (const float4*)(R + (size_t)row * 1024);
  const float4* Bi4 = (const float4*)bias;
  float4 xs[4];
  float s = 0.f, sq = 0.f;
#pragma unroll
  for (int i = 0; i < 4; ++i) {
    const int c = lane + i * 64;
    const float4 a = A4[c], pb = B4[c], r = R4[c], bi = Bi4[c];
    float4 x;
    x.x = a.x + pb.x + r.x + bi.x;
    x.y = a.y + pb.y + r.y + bi.y;
    x.z = a.z + pb.z + r.z + bi.z;
    x.w = a.w + pb.w + r.w + bi.w;
    xs[i] = x;
    s += x.x + x.y + x.z + x.w;
    sq += x.x * x.x + x.y * x.y + x.z * x.z + x.w * x.w;
  }
#pragma unroll
  for (int m = 1; m < 64; m <<= 1) { s += __shfl_xor(s, m); sq += __shfl_xor(sq, m); }
  const float mean = s * (1.f / 1024.f);
  float var = sq * (1.f / 1024.f) - mean * mean;
  var = var > 0.f ? var : 0.f;
  const float rstd = rsqrtf(var + 1e-5f);
  const float4* g4 = (const float4*)g;
  const float4* b4 = (const float4*)b;
  float4* of = (float4*)(out + (size_t)row * 1024);
#pragma unroll
  for (int i = 0; i < 4; ++i) {
    const int c = lane + i * 64;
    const float4 gv = g4[c], bv = b4[c], x = xs[i];
    float4 y;
    y.x = (x.x - mean) * rstd * gv.x + bv.x;
    y.y = (x.y - mean) * rstd * gv.y + bv.y;
    y.z = (x.z - mean) * rstd * gv.z + bv.z;
    y.w = (x.w - mean) * rstd * gv.w + bv.w;
    of[c] = y;
  }
}

// ---------------------------------------------------------------------------
extern "C" void kernel_launch(void* const* d_in, const int* in_sizes, int n_in,
                              void* d_out, int out_size, void* d_ws,
                              size_t ws_size, hipStream_t stream) {
  const float* x   = (const float*)d_in[0];
  const float* Wq  = (const float*)d_in[1];
  const float* bq  = (const float*)d_in[2];
  const float* Wk  = (const float*)d_in[3];
  const float* bk  = (const float*)d_in[4];
  const float* Wv  = (const float*)d_in[5];
  const float* bv  = (const float*)d_in[6];
  const float* kW  = (const float*)d_in[7];
  const float* Wo  = (const float*)d_in[8];
  const float* bo  = (const float*)d_in[9];
  const float* W1  = (const float*)d_in[10];
  const float* b1  = (const float*)d_in[11];
  const float* W2  = (const float*)d_in[12];
  const float* b2  = (const float*)d_in[13];
  const float* g1  = (const float*)d_in[14];
  const float* be1 = (const float*)d_in[15];
  const float* g2  = (const float*)d_in[16];
  const float* be2 = (const float*)d_in[17];

  char* ws = (char*)d_ws;
  const size_t MB = 1024 * 1024;
  u16*   WqT = (u16*)(ws + 0 * MB);   // [0,6) = fused QKV BT[3072][1024]
  u16*   WoT = (u16*)(ws + 6 * MB);
  u16*   W1T = (u16*)(ws + 8 * MB);
  u16*   W2T = (u16*)(ws + 16 * MB);
  float* r1  = (float*)(ws + 24 * MB);
  u16*   xb  = (u16*)(ws + 40 * MB);
  u16*   qhB = (u16*)(ws + 48 * MB);
  u16*   khB = (u16*)(ws + 56 * MB);
  u16*   vTB = (u16*)(ws + 64 * MB);
  u16*   hf  = (u16*)(ws + 40 * MB);
  u16*   ao  = (u16*)(ws + 72 * MB);
  u16*   x1b = (u16*)(ws + 80 * MB);
  float* r2a = (float*)(ws + 0 * MB);
  float* r2b = (float*)(ws + 72 * MB);

  const dim3 blk(256);

  transpose_cast<<<dim3(32, 32), blk, 0, stream>>>(Wq, WqT, 1024, 1024);
  transpose_cast<<<dim3(32, 32), blk, 0, stream>>>(Wk, WqT + 1048576, 1024, 1024);
  transpose_cast<<<dim3(32, 32), blk, 0, stream>>>(Wv, WqT + 2097152, 1024, 1024);
  transpose_cast<<<dim3(32, 32), blk, 0, stream>>>(Wo, WoT, 1024, 1024);
  transpose_cast<<<dim3(128, 32), blk, 0, stream>>>(W1, W1T, 1024, 4096);
  transpose_cast<<<dim3(32, 128), blk, 0, stream>>>(W2, W2T, 4096, 1024);
  cast_b<<<4096, blk, 0, stream>>>(x, xb);

  // fused QKV projection (q scaled by kernelW*log2e; k,v fragment-tiled)
  gemmT<5, 128><<<dim3(24, 32), blk, 0, stream>>>(
      xb, WqT, bq, bk, bv, nullptr, qhB, kW, 3072, 1024);

  // flash attention: 1024 blocks x 8 waves (4 qg x 2 key-halves), LDS-staged
  attn_kernel<<<1024, dim3(512), 0, stream>>>(qhB, khB, vTB, ao);

  // out-proj + residual -> r1 (fp32)
  gemmT<2, 64><<<dim3(16, 32), blk, 0, stream>>>(
      ao, WoT, bo, nullptr, nullptr, x, r1, nullptr, 1024, 1024);
  ln_kernel<1><<<1024, blk, 0, stream>>>(r1, g1, be1, r1, x1b);
  // FFN1
  gemmT<3, 128><<<dim3(32, 32), blk, 0, stream>>>(
      x1b, W1T, b1, nullptr, nullptr, nullptr, hf, nullptr, 4096, 1024);
  // FFN2: split-K 2-way, f32 partials to r2a/r2b (1024 blocks)
  gemmT<6, 64><<<dim3(16, 64), blk, 0, stream>>>(
      hf, W2T, nullptr, nullptr, nullptr, r2b, r2a, nullptr, 1024, 4096);
  // LN2 merges partials + residual + bias
  ln2sum_kernel<<<1024, blk, 0, stream>>>(r2a, r2b, r1, b2, g2, be2,
                                          (float*)d_out);

  (void)in_sizes; (void)n_in; (void)out_size; (void)ws_size;
}

// Round 13
// 253.497 us; speedup vs baseline: 1.4193x; 1.0201x over previous
//
#include <hip/hip_runtime.h>

// ---------------------------------------------------------------------------
// TransformerBlockQuantum: B=2,S=2048,E=1024,H=32,DK=32,FFN=4096
// GEMMs: bf16 MFMA 16x16x32, LDS double-buffer, single-barrier K-loop,
// XCD-chunked block swizzle. FFN2 = BN=128 split-K 4-way, bf16 partials
// (p0..p3), ln2sum merges. Attention: round-12 exact (8-wave LDS-staged).
// ws layout (MB):
//  [0,6) QKV BT  [6,8)WoT [8,16)W1T [16,24)W2T
//  [24,40) r1    [40,72) xb/qh/kh/vT then hf   [72,88) ao/x1b
//  FFN2 partials: p0[0,8) p1[8,16) p2[72,80) p3[80,88)  (all dead by then)
// ---------------------------------------------------------------------------

typedef unsigned short u16;
typedef unsigned int u32;
typedef __bf16 bf16x8 __attribute__((ext_vector_type(8)));
typedef float f32x4 __attribute__((ext_vector_type(4)));
typedef float f32x16 __attribute__((ext_vector_type(16)));

__device__ __forceinline__ u16 f2b(float f) {
  union { float f; unsigned u; } x; x.f = f;
  unsigned r = x.u + 0x7FFFu + ((x.u >> 16) & 1u);
  return (u16)(r >> 16);
}

__device__ __forceinline__ float b2f(u16 u) {
  union { u32 u; float f; } x; x.u = (u32)u << 16; return x.f;
}

__device__ __forceinline__ unsigned pkbf(float lo, float hi) {
  unsigned r;
  asm("v_cvt_pk_bf16_f32 %0, %1, %2" : "=v"(r) : "v"(lo), "v"(hi));
  return r;
}

__device__ __forceinline__ float expo2(float x) {
#if __has_builtin(__builtin_amdgcn_exp2f)
  return __builtin_amdgcn_exp2f(x);
#else
  return exp2f(x);
#endif
}

#define GLDS16(gp, lp)                                                         \
  __builtin_amdgcn_global_load_lds(                                            \
      (const __attribute__((address_space(1))) void*)(gp),                     \
      (__attribute__((address_space(3))) void*)(lp), 16, 0, 0)

// ---------------- transpose + cast: W[K][N] f32 -> WT[N][K] bf16 ------------
__global__ __launch_bounds__(256) void transpose_cast(
    const float* __restrict__ W, u16* __restrict__ WT, int K, int N) {
  __shared__ float tile[32][33];
  const int tx = threadIdx.x & 31, ty = threadIdx.x >> 5;
  const int n0 = blockIdx.x * 32, k0 = blockIdx.y * 32;
#pragma unroll
  for (int i = 0; i < 4; ++i)
    tile[ty + 8 * i][tx] = W[(size_t)(k0 + ty + 8 * i) * N + n0 + tx];
  __syncthreads();
#pragma unroll
  for (int i = 0; i < 4; ++i)
    WT[(size_t)(n0 + ty + 8 * i) * K + k0 + tx] = f2b(tile[tx][ty + 8 * i]);
}

// ---------------- cast f32 -> bf16 (4 elems/thread) -------------------------
__global__ __launch_bounds__(256) void cast_b(const float* __restrict__ x,
                                              u16* __restrict__ y) {
  int i = blockIdx.x * 256 + threadIdx.x;
  float4 v = ((const float4*)x)[i];
  ushort4 o;
  o.x = f2b(v.x); o.y = f2b(v.y); o.z = f2b(v.z); o.w = f2b(v.w);
  ((ushort4*)y)[i] = o;
}

// ---------------- GEMM: C = A[M,K] @ BT[N,K]^T, bf16, dbuf 1-barrier loop ---
// MODE 2: fp32 out = acc + bias + res
// MODE 3: bf16 out = relu(acc + bias)
// MODE 5: fused QKV epilogues (q-scaled head / k,v fragment-order tiles)
// MODE 6: split-K 4-way (by>>5 = k-quarter), bf16 partial -> p[kh6];
//         outp = base of p0/p1 (contig), res = base of p2/p3 (contig).
template <int MODE, int BN>
__global__ __launch_bounds__(256) void gemmT(
    const u16* __restrict__ A, const u16* __restrict__ BT,
    const float* __restrict__ bias, const float* __restrict__ bias2,
    const float* __restrict__ bias3, const float* __restrict__ res,
    void* __restrict__ outp, const float* __restrict__ kW, int N_, int K_) {
  constexpr int ABYT = 128 * 32 * 2;
  constexpr int BBYT = BN * 32 * 2;
  constexpr int STRIDE = ABYT + BBYT;
  constexpr int MI = (BN == 128) ? 4 : 2;
  __shared__ __align__(16) char SH[2 * STRIDE];
  const int t = threadIdx.x, lane = t & 63, wid = t >> 6;
  const int gx = gridDim.x;
  const int id = blockIdx.y * gx + blockIdx.x;
  const int nb = gx * gridDim.y;
  const int sid = (id & 7) * (nb >> 3) + (id >> 3);
  const int bx = sid % gx;
  int by = sid / gx;
  int kh6 = 0;
  if constexpr (MODE == 6) { kh6 = by >> 5; by &= 31; }
  const int m0 = by * 128, n0 = bx * BN;
  const int wr = (BN == 128) ? (wid >> 1) * 64 : wid * 32;
  const int wc = (BN == 128) ? (wid & 1) * 64 : 0;
  const int lr = lane & 15, lg = lane >> 4;
  const int K = K_;
  const int koff = (MODE == 6) ? kh6 * 1024 : 0;

  f32x4 acc[MI][4] = {};

  const u16* ga0 = A + (size_t)(m0 + (t >> 2)) * K + koff + (t & 3) * 8;
  const u16* ga1 = ga0 + (size_t)64 * K;
  const u16* gb0 = BT + (size_t)(n0 + (t >> 2)) * K + koff + (t & 3) * 8;
  const u16* gb1 = gb0 + (size_t)64 * K;
  const int stA = wid * 1024;

#define STAGE(CUR, KT)                                                         \
  {                                                                            \
    char* l_ = (char*)SH + (CUR) * STRIDE + stA;                               \
    const size_t o_ = (size_t)(KT) * 32;                                       \
    GLDS16(ga0 + o_, l_);                                                      \
    GLDS16(ga1 + o_, l_ + 4096);                                               \
    GLDS16(gb0 + o_, l_ + ABYT);                                               \
    if constexpr (BN == 128) GLDS16(gb1 + o_, l_ + ABYT + 4096);               \
  }

  const int nk = (MODE == 6) ? 32 : (K >> 5);
  STAGE(0, 0);
  __syncthreads();
  int cur = 0;
  for (int kt = 0; kt < nk; ++kt) {
    if (kt + 1 < nk) STAGE(cur ^ 1, kt + 1);
    const char* l = (const char*)SH + cur * STRIDE;
    bf16x8 af[MI], bf[4];
#pragma unroll
    for (int i = 0; i < MI; ++i)
      af[i] = *(const bf16x8*)(l + (wr + i * 16 + lr) * 64 + lg * 16);
#pragma unroll
    for (int i = 0; i < 4; ++i)
      bf[i] = *(const bf16x8*)(l + ABYT + (wc + i * 16 + lr) * 64 + lg * 16);
#pragma unroll
    for (int mi = 0; mi < MI; ++mi)
#pragma unroll
      for (int ni = 0; ni < 4; ++ni)
        acc[mi][ni] = __builtin_amdgcn_mfma_f32_16x16x32_bf16(
            af[mi], bf[ni], acc[mi][ni], 0, 0, 0);
    __syncthreads();
    cur ^= 1;
  }
#undef STAGE

#pragma unroll
  for (int mi = 0; mi < MI; ++mi) {
#pragma unroll
    for (int ni = 0; ni < 4; ++ni) {
      const int row = m0 + wr + mi * 16 + lg * 4;
      const int col = n0 + wc + ni * 16 + lr;
      f32x4 v = acc[mi][ni];
      if constexpr (MODE == 2) {
        const float bv = bias[col];
        float* o = (float*)outp;
#pragma unroll
        for (int r = 0; r < 4; ++r) {
          const int rr = row + r;
          o[(size_t)rr * N_ + col] = v[r] + bv + res[(size_t)rr * N_ + col];
        }
      } else if constexpr (MODE == 3) {
        const float bv = bias[col];
        u16* o = (u16*)outp;
#pragma unroll
        for (int r = 0; r < 4; ++r) {
          const int rr = row + r;
          float y = v[r] + bv;
          o[(size_t)rr * N_ + col] = f2b(y > 0.f ? y : 0.f);
        }
      } else if constexpr (MODE == 6) {
        u16* o = (kh6 < 2) ? ((u16*)outp + (size_t)kh6 * 4194304)
                           : ((u16*)res + (size_t)(kh6 - 2) * 4194304);
#pragma unroll
        for (int r = 0; r < 4; ++r) {
          const int rr = row + r;
          o[(size_t)rr * N_ + col] = f2b(v[r]);
        }
      } else {  // MODE 5
        const int proj = col >> 10, c = col & 1023;
        const int h = c >> 5, d = c & 31;
        u16* qout = (u16*)outp;
        if (proj == 0) {
          const float bv = bias[c];
          const float sc = kW[d * 32 + h] * 1.44269504089f;
#pragma unroll
          for (int r = 0; r < 4; ++r) {
            const int rr = row + r;
            const int bb = rr >> 11, s = rr & 2047;
            qout[(size_t)(((bb * 32 + h) * 2048) + s) * 32 + d] =
                f2b((v[r] + bv) * sc);
          }
        } else if (proj == 1) {
          const float bv = bias2[c];
          u16* kout = qout + 4194304;
          const int c2 = d >> 3;
#pragma unroll
          for (int r = 0; r < 4; ++r) {
            const int rr = row + r;
            const int bb = rr >> 11, s = rr & 2047;
            const int k = s & 63;
            const int g = ((k >> 5) << 1) | (c2 >> 1);
            kout[(size_t)(bb * 32 + h) * 65536 + (s >> 6) * 2048 + g * 512 +
                 (c2 & 1) * 256 + (k & 31) * 8 + (d & 7)] = f2b(v[r] + bv);
          }
        } else {
          const float bv = bias3[c];
          u16* vout = qout + 8388608;
          const int bb = row >> 11, s0 = row & 2047;
          const int k = s0 & 63;
          const int cc = k >> 3, rb = cc >> 1, hb = cc & 1, e = k & 7;
          ushort4 st;
          st.x = f2b(v[0] + bv); st.y = f2b(v[1] + bv);
          st.z = f2b(v[2] + bv); st.w = f2b(v[3] + bv);
          *(ushort4*)(vout + (size_t)(bb * 32 + h) * 65536 +
                      (s0 >> 6) * 2048 + rb * 512 + hb * 256 + d * 8 + e) = st;
        }
      }
    }
  }
}

// ---------------- attention tile compute (64 keys) --------------------------
__device__ __forceinline__ void attn_tile(
    const bf16x8& k0, const bf16x8& k1, const bf16x8& k2, const bf16x8& k3,
    const bf16x8& v0, const bf16x8& v1, const bf16x8& v2, const bf16x8& v3,
    const bf16x8& qb0, const bf16x8& qb1,
    f32x16& acc, float& la, float& lb, float& lc, float& ld) {
  const f32x16 z16 = {};
  f32x16 s0 = __builtin_amdgcn_mfma_f32_32x32x16_bf16(k0, qb0, z16, 0, 0, 0);
  s0 = __builtin_amdgcn_mfma_f32_32x32x16_bf16(k1, qb1, s0, 0, 0, 0);
  f32x16 s1 = __builtin_amdgcn_mfma_f32_32x32x16_bf16(k2, qb0, z16, 0, 0, 0);
  s1 = __builtin_amdgcn_mfma_f32_32x32x16_bf16(k3, qb1, s1, 0, 0, 0);
  float p0[16], p1[16];
#pragma unroll
  for (int r = 0; r < 16; ++r) p0[r] = expo2(s0[r]);
#pragma unroll
  for (int r = 0; r < 16; ++r) p1[r] = expo2(s1[r]);
#pragma unroll
  for (int r = 0; r < 4; ++r) {
    la += p0[r] + p1[r];
    lb += p0[4 + r] + p1[4 + r];
    lc += p0[8 + r] + p1[8 + r];
    ld += p0[12 + r] + p1[12 + r];
  }
  {
    u32 x0 = pkbf(p0[0], p0[1]), x1 = pkbf(p0[2], p0[3]);
    u32 y0 = pkbf(p0[4], p0[5]), y1 = pkbf(p0[6], p0[7]);
    asm("v_permlane32_swap_b32 %0, %1" : "+v"(x0), "+v"(y0));
    asm("v_permlane32_swap_b32 %0, %1" : "+v"(x1), "+v"(y1));
    union { u32 d[4]; bf16x8 v; } u;
    u.d[0] = x0; u.d[1] = x1; u.d[2] = y0; u.d[3] = y1;
    acc = __builtin_amdgcn_mfma_f32_32x32x16_bf16(v0, u.v, acc, 0, 0, 0);
  }
  {
    u32 x0 = pkbf(p0[8], p0[9]), x1 = pkbf(p0[10], p0[11]);
    u32 y0 = pkbf(p0[12], p0[13]), y1 = pkbf(p0[14], p0[15]);
    asm("v_permlane32_swap_b32 %0, %1" : "+v"(x0), "+v"(y0));
    asm("v_permlane32_swap_b32 %0, %1" : "+v"(x1), "+v"(y1));
    union { u32 d[4]; bf16x8 v; } u;
    u.d[0] = x0; u.d[1] = x1; u.d[2] = y0; u.d[3] = y1;
    acc = __builtin_amdgcn_mfma_f32_32x32x16_bf16(v1, u.v, acc, 0, 0, 0);
  }
  {
    u32 x0 = pkbf(p1[0], p1[1]), x1 = pkbf(p1[2], p1[3]);
    u32 y0 = pkbf(p1[4], p1[5]), y1 = pkbf(p1[6], p1[7]);
    asm("v_permlane32_swap_b32 %0, %1" : "+v"(x0), "+v"(y0));
    asm("v_permlane32_swap_b32 %0, %1" : "+v"(x1), "+v"(y1));
    union { u32 d[4]; bf16x8 v; } u;
    u.d[0] = x0; u.d[1] = x1; u.d[2] = y0; u.d[3] = y1;
    acc = __builtin_amdgcn_mfma_f32_32x32x16_bf16(v2, u.v, acc, 0, 0, 0);
  }
  {
    u32 x0 = pkbf(p1[8], p1[9]), x1 = pkbf(p1[10], p1[11]);
    u32 y0 = pkbf(p1[12], p1[13]), y1 = pkbf(p1[14], p1[15]);
    asm("v_permlane32_swap_b32 %0, %1" : "+v"(x0), "+v"(y0));
    asm("v_permlane32_swap_b32 %0, %1" : "+v"(x1), "+v"(y1));
    union { u32 d[4]; bf16x8 v; } u;
    u.d[0] = x0; u.d[1] = x1; u.d[2] = y0; u.d[3] = y1;
    acc = __builtin_amdgcn_mfma_f32_32x32x16_bf16(v3, u.v, acc, 0, 0, 0);
  }
}

// ---------------- swapped 32x32 flash attention, LDS-staged, 8 waves --------
__global__ __launch_bounds__(512) void attn_kernel(
    const u16* __restrict__ Q, const u16* __restrict__ K,
    const u16* __restrict__ VT, u16* __restrict__ O) {
  __shared__ __align__(16) char LDSB[32768];
  const int t = threadIdx.x, wid = t >> 6, lane = t & 63;
  const int qg = wid & 3, kh = wid >> 2;
  const int bid = blockIdx.x;                    // 1024 blocks
  const int swz = (bid & 7) * 128 + (bid >> 3);  // 8 XCDs
  const int bh = swz >> 4;                       // 0..63
  const int qt = swz & 15;                       // q-tile of 128
  const int q0 = qt * 128 + qg * 32;
  const int lq = lane & 31, hi = lane >> 5;
  const u16* Qh = Q + (size_t)bh * 65536;
  const u16* Kh = K + (size_t)bh * 65536;
  const u16* Vh = VT + (size_t)bh * 65536;

  const bf16x8 qb0 = *(const bf16x8*)(Qh + (size_t)(q0 + lq) * 32 + hi * 8);
  const bf16x8 qb1 = *(const bf16x8*)(Qh + (size_t)(q0 + lq) * 32 + 16 + hi * 8);

  const u16* kg = Kh + wid * 512 + lane * 8;
  const u16* vg = Vh + wid * 512 + lane * 8;
  const int lds_w = wid * 1024;

#define STAGEA(CUR, I)                                                         \
  if (wid < 4) {                                                               \
    char* b_ = LDSB + (CUR) * 16384 + lds_w;                                   \
    GLDS16(kg + (size_t)(I) * 2048, b_);                                       \
    GLDS16(vg + (size_t)(I) * 2048, b_ + 4096);                                \
    GLDS16(kg + (size_t)(16 + (I)) * 2048, b_ + 8192);                         \
    GLDS16(vg + (size_t)(16 + (I)) * 2048, b_ + 12288);                        \
  }

  f32x16 acc = {};
  float la = 0.f, lb = 0.f, lc = 0.f, ld = 0.f;

  STAGEA(0, 0);
  __syncthreads();
  int cur = 0;
#pragma unroll 1
  for (int i = 0; i < 16; ++i) {
    if (i < 15) STAGEA(cur ^ 1, i + 1);
    const char* kb = LDSB + cur * 16384 + kh * 8192 + lane * 16;
    const bf16x8 ka0 = *(const bf16x8*)(kb);
    const bf16x8 ka1 = *(const bf16x8*)(kb + 1024);
    const bf16x8 ka2 = *(const bf16x8*)(kb + 2048);
    const bf16x8 ka3 = *(const bf16x8*)(kb + 3072);
    const bf16x8 va0 = *(const bf16x8*)(kb + 4096);
    const bf16x8 va1 = *(const bf16x8*)(kb + 5120);
    const bf16x8 va2 = *(const bf16x8*)(kb + 6144);
    const bf16x8 va3 = *(const bf16x8*)(kb + 7168);
    attn_tile(ka0, ka1, ka2, ka3, va0, va1, va2, va3, qb0, qb1,
              acc, la, lb, lc, ld);
    __syncthreads();
    cur ^= 1;
  }
#undef STAGEA

  float lrun = (la + lb) + (lc + ld);
  lrun += __shfl_xor(lrun, 32);

  float* sm_acc = (float*)LDSB;            // [4][64][16] = 16KB
  float* sm_l = (float*)(LDSB + 16384);    // [4][32]
  if (kh == 1) {
    sm_l[qg * 32 + lq] = lrun;
#pragma unroll
    for (int r = 0; r < 16; ++r) sm_acc[(qg * 64 + lane) * 16 + r] = acc[r];
  }
  __syncthreads();
  if (kh == 0) {
    const float inv = 1.f / (lrun + sm_l[qg * 32 + lq]);
    const int bb = bh >> 5, h = bh & 31;
    u16* o = O + (size_t)(bb * 2048 + q0 + lq) * 1024 + h * 32;
#pragma unroll
    for (int g = 0; g < 4; ++g) {
      ushort4 st;
      st.x = f2b((acc[g * 4 + 0] + sm_acc[(qg * 64 + lane) * 16 + g * 4 + 0]) * inv);
      st.y = f2b((acc[g * 4 + 1] + sm_acc[(qg * 64 + lane) * 16 + g * 4 + 1]) * inv);
      st.z = f2b((acc[g * 4 + 2] + sm_acc[(qg * 64 + lane) * 16 + g * 4 + 2]) * inv);
      st.w = f2b((acc[g * 4 + 3] + sm_acc[(qg * 64 + lane) * 16 + g * 4 + 3]) * inv);
      *(ushort4*)(o + g * 8 + hi * 4) = st;
    }
  }
}

// ---------------- LayerNorm (1 wave per row of 1024) ------------------------
template <int WB>
__global__ __launch_bounds__(256) void ln_kernel(
    const float* X, const float* __restrict__ g, const float* __restrict__ b,
    float* outf, u16* __restrict__ outb) {
  const int wid = threadIdx.x >> 6, lane = threadIdx.x & 63;
  const int row = blockIdx.x * 4 + wid;
  const float4* X4 = (const float4*)(X + (size_t)row * 1024);
  float4 xs[4];
  float s = 0.f, sq = 0.f;
#pragma unroll
  for (int i = 0; i < 4; ++i) {
    xs[i] = X4[lane + i * 64];
    s += xs[i].x + xs[i].y + xs[i].z + xs[i].w;
    sq += xs[i].x * xs[i].x + xs[i].y * xs[i].y + xs[i].z * xs[i].z + xs[i].w * xs[i].w;
  }
#pragma unroll
  for (int m = 1; m < 64; m <<= 1) { s += __shfl_xor(s, m); sq += __shfl_xor(sq, m); }
  const float mean = s * (1.f / 1024.f);
  float var = sq * (1.f / 1024.f) - mean * mean;
  var = var > 0.f ? var : 0.f;
  const float rstd = rsqrtf(var + 1e-5f);
  const float4* g4 = (const float4*)g;
  const float4* b4 = (const float4*)b;
  float4* of = (float4*)(outf + (size_t)row * 1024);
#pragma unroll
  for (int i = 0; i < 4; ++i) {
    const int c = lane + i * 64;
    const float4 gv = g4[c], bv = b4[c], x = xs[i];
    float4 y;
    y.x = (x.x - mean) * rstd * gv.x + bv.x;
    y.y = (x.y - mean) * rstd * gv.y + bv.y;
    y.z = (x.z - mean) * rstd * gv.z + bv.z;
    y.w = (x.w - mean) * rstd * gv.w + bv.w;
    of[c] = y;
    if constexpr (WB) {
      ushort4 yb;
      yb.x = f2b(y.x); yb.y = f2b(y.y); yb.z = f2b(y.z); yb.w = f2b(y.w);
      ((ushort4*)(outb + (size_t)row * 1024))[c] = yb;
    }
  }
}

// ---------------- LN2: x = p0+p1+p2+p3 (bf16) + res + bias ------------------
__global__ __launch_bounds__(256) void ln2sum_kernel(
    const u16* __restrict__ P0, const u16* __restrict__ P1,
    const u16* __restrict__ P2, const u16* __restrict__ P3,
    const float* __restrict__ R, const float* __restrict__ bias,
    const float* __restrict__ g, const float* __restrict__ b,
    float* __restrict__ out) {
  const int wid = threadIdx.x >> 6, lane = threadIdx.x & 63;
  const int row = blockIdx.x * 4 + wid;
  const ushort4* A4 = (const ushort4*)(P0 + (size_t)row * 1024);
  const ushort4* B4 = (const ushort4*)(P1 + (size_t)row * 1024);
  const ushort4* C4 = (const ushort4*)(P2 + (size_t)row * 1024);
  const ushort4* D4 = (const ushort4*)(P3 + (size_t)row * 1024);
  const float4* R4 = (const float4*)(R + (size_t)row * 1024);
  const float4* Bi4 = (const float4*)bias;
  float4 xs[4];
  float s = 0.f, sq = 0.f;
#pragma unroll
  for (int i = 0; i < 4; ++i) {
    const int c = lane + i * 64;
    const ushort4 a = A4[c], pb = B4[c], pc = C4[c], pd = D4[c];
    const float4 r = R4[c], bi = Bi4[c];
    float4 x;
    x.x = (b2f(a.x) + b2f(pb.x)) + (b2f(pc.x) + b2f(pd.x)) + r.x + bi.x;
    x.y = (b2f(a.y) + b2f(pb.y)) + (b2f(pc.y) + b2f(pd.y)) + r.y + bi.y;
    x.z = (b2f(a.z) + b2f(pb.z)) + (b2f(pc.z) + b2f(pd.z)) + r.z + bi.z;
    x.w = (b2f(a.w) + b2f(pb.w)) + (b2f(pc.w) + b2f(pd.w)) + r.w + bi.w;
    xs[i] = x;
    s += x.x + x.y + x.z + x.w;
    sq += x.x * x.x + x.y * x.y + x.z * x.z + x.w * x.w;
  }
#pragma unroll
  for (int m = 1; m < 64; m <<= 1) { s += __shfl_xor(s, m); sq += __shfl_xor(sq, m); }
  const float mean = s * (1.f / 1024.f);
  float var = sq * (1.f / 1024.f) - mean * mean;
  var = var > 0.f ? var : 0.f;
  const float rstd = rsqrtf(var + 1e-5f);
  const float4* g4 = (const float4*)g;
  const float4* b4 = (const float4*)b;
  float4* of = (float4*)(out + (size_t)row * 1024);
#pragma unroll
  for (int i = 0; i < 4; ++i) {
    const int c = lane + i * 64;
    const float4 gv = g4[c], bv = b4[c], x = xs[i];
    float4 y;
    y.x = (x.x - mean) * rstd * gv.x + bv.x;
    y.y = (x.y - mean) * rstd * gv.y + bv.y;
    y.z = (x.z - mean) * rstd * gv.z + bv.z;
    y.w = (x.w - mean) * rstd * gv.w + bv.w;
    of[c] = y;
  }
}

// ---------------------------------------------------------------------------
extern "C" void kernel_launch(void* const* d_in, const int* in_sizes, int n_in,
                              void* d_out, int out_size, void* d_ws,
                              size_t ws_size, hipStream_t stream) {
  const float* x   = (const float*)d_in[0];
  const float* Wq  = (const float*)d_in[1];
  const float* bq  = (const float*)d_in[2];
  const float* Wk  = (const float*)d_in[3];
  const float* bk  = (const float*)d_in[4];
  const float* Wv  = (const float*)d_in[5];
  const float* bv  = (const float*)d_in[6];
  const float* kW  = (const float*)d_in[7];
  const float* Wo  = (const float*)d_in[8];
  const float* bo  = (const float*)d_in[9];
  const float* W1  = (const float*)d_in[10];
  const float* b1  = (const float*)d_in[11];
  const float* W2  = (const float*)d_in[12];
  const float* b2  = (const float*)d_in[13];
  const float* g1  = (const float*)d_in[14];
  const float* be1 = (const float*)d_in[15];
  const float* g2  = (const float*)d_in[16];
  const float* be2 = (const float*)d_in[17];

  char* ws = (char*)d_ws;
  const size_t MB = 1024 * 1024;
  u16*   WqT = (u16*)(ws + 0 * MB);   // [0,6) = fused QKV BT[3072][1024]
  u16*   WoT = (u16*)(ws + 6 * MB);
  u16*   W1T = (u16*)(ws + 8 * MB);
  u16*   W2T = (u16*)(ws + 16 * MB);
  float* r1  = (float*)(ws + 24 * MB);
  u16*   xb  = (u16*)(ws + 40 * MB);
  u16*   qhB = (u16*)(ws + 48 * MB);
  u16*   khB = (u16*)(ws + 56 * MB);
  u16*   vTB = (u16*)(ws + 64 * MB);
  u16*   hf  = (u16*)(ws + 40 * MB);
  u16*   ao  = (u16*)(ws + 72 * MB);
  u16*   x1b = (u16*)(ws + 80 * MB);
  u16*   p0  = (u16*)(ws + 0 * MB);   // FFN2 bf16 partials (dead regions)
  u16*   p2  = (u16*)(ws + 72 * MB);

  const dim3 blk(256);

  transpose_cast<<<dim3(32, 32), blk, 0, stream>>>(Wq, WqT, 1024, 1024);
  transpose_cast<<<dim3(32, 32), blk, 0, stream>>>(Wk, WqT + 1048576, 1024, 1024);
  transpose_cast<<<dim3(32, 32), blk, 0, stream>>>(Wv, WqT + 2097152, 1024, 1024);
  transpose_cast<<<dim3(32, 32), blk, 0, stream>>>(Wo, WoT, 1024, 1024);
  transpose_cast<<<dim3(128, 32), blk, 0, stream>>>(W1, W1T, 1024, 4096);
  transpose_cast<<<dim3(32, 128), blk, 0, stream>>>(W2, W2T, 4096, 1024);
  cast_b<<<4096, blk, 0, stream>>>(x, xb);

  // fused QKV projection (q scaled by kernelW*log2e; k,v fragment-tiled)
  gemmT<5, 128><<<dim3(24, 32), blk, 0, stream>>>(
      xb, WqT, bq, bk, bv, nullptr, qhB, kW, 3072, 1024);

  // flash attention: 1024 blocks x 8 waves (4 qg x 2 key-halves), LDS-staged
  attn_kernel<<<1024, dim3(512), 0, stream>>>(qhB, khB, vTB, ao);

  // out-proj + residual -> r1 (fp32)
  gemmT<2, 64><<<dim3(16, 32), blk, 0, stream>>>(
      ao, WoT, bo, nullptr, nullptr, x, r1, nullptr, 1024, 1024);
  ln_kernel<1><<<1024, blk, 0, stream>>>(r1, g1, be1, r1, x1b);
  // FFN1
  gemmT<3, 128><<<dim3(32, 32), blk, 0, stream>>>(
      x1b, W1T, b1, nullptr, nullptr, nullptr, hf, nullptr, 4096, 1024);
  // FFN2: BN=128, split-K 4-way, bf16 partials p0..p3 (1024 blocks, 4/CU)
  gemmT<6, 128><<<dim3(8, 128), blk, 0, stream>>>(
      hf, W2T, nullptr, nullptr, nullptr, (const float*)p2, p0, nullptr,
      1024, 4096);
  // LN2 merges 4 partials + residual + bias
  ln2sum_kernel<<<1024, blk, 0, stream>>>(p0, p0 + 4194304, p2, p2 + 4194304,
                                          r1, b2, g2, be2, (float*)d_out);

  (void)in_sizes; (void)n_in; (void)out_size; (void)ws_size;
}

// Round 14
// 235.890 us; speedup vs baseline: 1.5252x; 1.0746x over previous
//
#include <hip/hip_runtime.h>

// ---------------------------------------------------------------------------
// TransformerBlockQuantum: B=2,S=2048,E=1024,H=32,DK=32,FFN=4096
// GEMMs: bf16 MFMA 16x16x32, LDS dbuf single-barrier loop, XCD swizzle.
// FFN2 = BN=128 split-K 4-way, bf16 partials. Attention: r12-exact 8-wave.
// This round: fused prep kernel (6 transposes + cast in ONE dispatch);
// r1 residual stream in bf16 (Wo bf16 epilogue, in-place bf16 LN1,
// x1b eliminated, ln2sum bf16 residual).
// ws layout (MB):
//  [0,6) QKV BT  [6,8)WoT [8,16)W1T [16,24)W2T
//  [24,32) r1b (bf16)   [40,72) xb/qh/kh/vT then hf   [72,88) ao then p2/p3
//  FFN2 partials: p0[0,8) p1[8,16) p2[72,80) p3[80,88)
// ---------------------------------------------------------------------------

typedef unsigned short u16;
typedef unsigned int u32;
typedef __bf16 bf16x8 __attribute__((ext_vector_type(8)));
typedef float f32x4 __attribute__((ext_vector_type(4)));
typedef float f32x16 __attribute__((ext_vector_type(16)));

__device__ __forceinline__ u16 f2b(float f) {
  union { float f; unsigned u; } x; x.f = f;
  unsigned r = x.u + 0x7FFFu + ((x.u >> 16) & 1u);
  return (u16)(r >> 16);
}

__device__ __forceinline__ float b2f(u16 u) {
  union { u32 u; float f; } x; x.u = (u32)u << 16; return x.f;
}

__device__ __forceinline__ unsigned pkbf(float lo, float hi) {
  unsigned r;
  asm("v_cvt_pk_bf16_f32 %0, %1, %2" : "=v"(r) : "v"(lo), "v"(hi));
  return r;
}

__device__ __forceinline__ float expo2(float x) {
#if __has_builtin(__builtin_amdgcn_exp2f)
  return __builtin_amdgcn_exp2f(x);
#else
  return exp2f(x);
#endif
}

#define GLDS16(gp, lp)                                                         \
  __builtin_amdgcn_global_load_lds(                                            \
      (const __attribute__((address_space(1))) void*)(gp),                     \
      (__attribute__((address_space(3))) void*)(lp), 16, 0, 0)

// ---------------- fused prep: 6 weight transposes + x cast, one dispatch ----
// blocks [0,4096): Wq/Wk/Wv/Wo 32x32 tiles; [4096,8192): W1; [8192,12288): W2
// blocks [12288,16384): cast x -> xb (1024 f32 per block)
__global__ __launch_bounds__(256) void prep_kernel(
    const float* __restrict__ Wq, const float* __restrict__ Wk,
    const float* __restrict__ Wv, const float* __restrict__ Wo,
    const float* __restrict__ W1, const float* __restrict__ W2,
    const float* __restrict__ x, u16* __restrict__ WqT, u16* __restrict__ WoT,
    u16* __restrict__ W1T, u16* __restrict__ W2T, u16* __restrict__ xb) {
  __shared__ float tile[32][33];
  const int id = blockIdx.x;
  if (id < 12288) {
    const float* W; u16* WT; int K, N, bx, by;
    if (id < 4096) {
      const int w = id >> 10, local = id & 1023;
      bx = local & 31; by = local >> 5; K = 1024; N = 1024;
      W = (w == 0) ? Wq : (w == 1) ? Wk : (w == 2) ? Wv : Wo;
      WT = (w == 0) ? WqT : (w == 1) ? WqT + 1048576
           : (w == 2) ? WqT + 2097152 : WoT;
    } else if (id < 8192) {
      const int local = id - 4096;
      bx = local & 127; by = local >> 7; K = 1024; N = 4096;
      W = W1; WT = W1T;
    } else {
      const int local = id - 8192;
      bx = local & 31; by = local >> 5; K = 4096; N = 1024;
      W = W2; WT = W2T;
    }
    const int tx = threadIdx.x & 31, ty = threadIdx.x >> 5;
    const int n0 = bx * 32, k0 = by * 32;
#pragma unroll
    for (int i = 0; i < 4; ++i)
      tile[ty + 8 * i][tx] = W[(size_t)(k0 + ty + 8 * i) * N + n0 + tx];
    __syncthreads();
#pragma unroll
    for (int i = 0; i < 4; ++i)
      WT[(size_t)(n0 + ty + 8 * i) * K + k0 + tx] = f2b(tile[tx][ty + 8 * i]);
  } else {
    const int i = (id - 12288) * 256 + threadIdx.x;
    float4 v = ((const float4*)x)[i];
    ushort4 o;
    o.x = f2b(v.x); o.y = f2b(v.y); o.z = f2b(v.z); o.w = f2b(v.w);
    ((ushort4*)xb)[i] = o;
  }
}

// ---------------- GEMM: C = A[M,K] @ BT[N,K]^T, bf16, dbuf 1-barrier loop ---
// MODE 2: bf16 out = acc + bias + res(bf16)   (Wo path, r1b)
// MODE 3: bf16 out = relu(acc + bias)
// MODE 5: fused QKV epilogues (q-scaled head / k,v fragment-order tiles)
// MODE 6: split-K 4-way (by>>5 = k-quarter), bf16 partial -> p[kh6]
template <int MODE, int BN>
__global__ __launch_bounds__(256) void gemmT(
    const u16* __restrict__ A, const u16* __restrict__ BT,
    const float* __restrict__ bias, const float* __restrict__ bias2,
    const float* __restrict__ bias3, const float* __restrict__ res,
    void* __restrict__ outp, const float* __restrict__ kW, int N_, int K_) {
  constexpr int ABYT = 128 * 32 * 2;
  constexpr int BBYT = BN * 32 * 2;
  constexpr int STRIDE = ABYT + BBYT;
  constexpr int MI = (BN == 128) ? 4 : 2;
  __shared__ __align__(16) char SH[2 * STRIDE];
  const int t = threadIdx.x, lane = t & 63, wid = t >> 6;
  const int gx = gridDim.x;
  const int id = blockIdx.y * gx + blockIdx.x;
  const int nb = gx * gridDim.y;
  const int sid = (id & 7) * (nb >> 3) + (id >> 3);
  const int bx = sid % gx;
  int by = sid / gx;
  int kh6 = 0;
  if constexpr (MODE == 6) { kh6 = by >> 5; by &= 31; }
  const int m0 = by * 128, n0 = bx * BN;
  const int wr = (BN == 128) ? (wid >> 1) * 64 : wid * 32;
  const int wc = (BN == 128) ? (wid & 1) * 64 : 0;
  const int lr = lane & 15, lg = lane >> 4;
  const int K = K_;
  const int koff = (MODE == 6) ? kh6 * 1024 : 0;

  f32x4 acc[MI][4] = {};

  const u16* ga0 = A + (size_t)(m0 + (t >> 2)) * K + koff + (t & 3) * 8;
  const u16* ga1 = ga0 + (size_t)64 * K;
  const u16* gb0 = BT + (size_t)(n0 + (t >> 2)) * K + koff + (t & 3) * 8;
  const u16* gb1 = gb0 + (size_t)64 * K;
  const int stA = wid * 1024;

#define STAGE(CUR, KT)                                                         \
  {                                                                            \
    char* l_ = (char*)SH + (CUR) * STRIDE + stA;                               \
    const size_t o_ = (size_t)(KT) * 32;                                       \
    GLDS16(ga0 + o_, l_);                                                      \
    GLDS16(ga1 + o_, l_ + 4096);                                               \
    GLDS16(gb0 + o_, l_ + ABYT);                                               \
    if constexpr (BN == 128) GLDS16(gb1 + o_, l_ + ABYT + 4096);               \
  }

  const int nk = (MODE == 6) ? 32 : (K >> 5);
  STAGE(0, 0);
  __syncthreads();
  int cur = 0;
  for (int kt = 0; kt < nk; ++kt) {
    if (kt + 1 < nk) STAGE(cur ^ 1, kt + 1);
    const char* l = (const char*)SH + cur * STRIDE;
    bf16x8 af[MI], bf[4];
#pragma unroll
    for (int i = 0; i < MI; ++i)
      af[i] = *(const bf16x8*)(l + (wr + i * 16 + lr) * 64 + lg * 16);
#pragma unroll
    for (int i = 0; i < 4; ++i)
      bf[i] = *(const bf16x8*)(l + ABYT + (wc + i * 16 + lr) * 64 + lg * 16);
#pragma unroll
    for (int mi = 0; mi < MI; ++mi)
#pragma unroll
      for (int ni = 0; ni < 4; ++ni)
        acc[mi][ni] = __builtin_amdgcn_mfma_f32_16x16x32_bf16(
            af[mi], bf[ni], acc[mi][ni], 0, 0, 0);
    __syncthreads();
    cur ^= 1;
  }
#undef STAGE

#pragma unroll
  for (int mi = 0; mi < MI; ++mi) {
#pragma unroll
    for (int ni = 0; ni < 4; ++ni) {
      const int row = m0 + wr + mi * 16 + lg * 4;
      const int col = n0 + wc + ni * 16 + lr;
      f32x4 v = acc[mi][ni];
      if constexpr (MODE == 2) {
        const float bv = bias[col];
        u16* o = (u16*)outp;
        const u16* rb = (const u16*)res;
#pragma unroll
        for (int r = 0; r < 4; ++r) {
          const int rr = row + r;
          o[(size_t)rr * N_ + col] =
              f2b(v[r] + bv + b2f(rb[(size_t)rr * N_ + col]));
        }
      } else if constexpr (MODE == 3) {
        const float bv = bias[col];
        u16* o = (u16*)outp;
#pragma unroll
        for (int r = 0; r < 4; ++r) {
          const int rr = row + r;
          float y = v[r] + bv;
          o[(size_t)rr * N_ + col] = f2b(y > 0.f ? y : 0.f);
        }
      } else if constexpr (MODE == 6) {
        u16* o = (kh6 < 2) ? ((u16*)outp + (size_t)kh6 * 4194304)
                           : ((u16*)res + (size_t)(kh6 - 2) * 4194304);
#pragma unroll
        for (int r = 0; r < 4; ++r) {
          const int rr = row + r;
          o[(size_t)rr * N_ + col] = f2b(v[r]);
        }
      } else {  // MODE 5
        const int proj = col >> 10, c = col & 1023;
        const int h = c >> 5, d = c & 31;
        u16* qout = (u16*)outp;
        if (proj == 0) {
          const float bv = bias[c];
          const float sc = kW[d * 32 + h] * 1.44269504089f;
#pragma unroll
          for (int r = 0; r < 4; ++r) {
            const int rr = row + r;
            const int bb = rr >> 11, s = rr & 2047;
            qout[(size_t)(((bb * 32 + h) * 2048) + s) * 32 + d] =
                f2b((v[r] + bv) * sc);
          }
        } else if (proj == 1) {
          const float bv = bias2[c];
          u16* kout = qout + 4194304;
          const int c2 = d >> 3;
#pragma unroll
          for (int r = 0; r < 4; ++r) {
            const int rr = row + r;
            const int bb = rr >> 11, s = rr & 2047;
            const int k = s & 63;
            const int g = ((k >> 5) << 1) | (c2 >> 1);
            kout[(size_t)(bb * 32 + h) * 65536 + (s >> 6) * 2048 + g * 512 +
                 (c2 & 1) * 256 + (k & 31) * 8 + (d & 7)] = f2b(v[r] + bv);
          }
        } else {
          const float bv = bias3[c];
          u16* vout = qout + 8388608;
          const int bb = row >> 11, s0 = row & 2047;
          const int k = s0 & 63;
          const int cc = k >> 3, rb = cc >> 1, hb = cc & 1, e = k & 7;
          ushort4 st;
          st.x = f2b(v[0] + bv); st.y = f2b(v[1] + bv);
          st.z = f2b(v[2] + bv); st.w = f2b(v[3] + bv);
          *(ushort4*)(vout + (size_t)(bb * 32 + h) * 65536 +
                      (s0 >> 6) * 2048 + rb * 512 + hb * 256 + d * 8 + e) = st;
        }
      }
    }
  }
}

// ---------------- attention tile compute (64 keys) --------------------------
__device__ __forceinline__ void attn_tile(
    const bf16x8& k0, const bf16x8& k1, const bf16x8& k2, const bf16x8& k3,
    const bf16x8& v0, const bf16x8& v1, const bf16x8& v2, const bf16x8& v3,
    const bf16x8& qb0, const bf16x8& qb1,
    f32x16& acc, float& la, float& lb, float& lc, float& ld) {
  const f32x16 z16 = {};
  f32x16 s0 = __builtin_amdgcn_mfma_f32_32x32x16_bf16(k0, qb0, z16, 0, 0, 0);
  s0 = __builtin_amdgcn_mfma_f32_32x32x16_bf16(k1, qb1, s0, 0, 0, 0);
  f32x16 s1 = __builtin_amdgcn_mfma_f32_32x32x16_bf16(k2, qb0, z16, 0, 0, 0);
  s1 = __builtin_amdgcn_mfma_f32_32x32x16_bf16(k3, qb1, s1, 0, 0, 0);
  float p0[16], p1[16];
#pragma unroll
  for (int r = 0; r < 16; ++r) p0[r] = expo2(s0[r]);
#pragma unroll
  for (int r = 0; r < 16; ++r) p1[r] = expo2(s1[r]);
#pragma unroll
  for (int r = 0; r < 4; ++r) {
    la += p0[r] + p1[r];
    lb += p0[4 + r] + p1[4 + r];
    lc += p0[8 + r] + p1[8 + r];
    ld += p0[12 + r] + p1[12 + r];
  }
  {
    u32 x0 = pkbf(p0[0], p0[1]), x1 = pkbf(p0[2], p0[3]);
    u32 y0 = pkbf(p0[4], p0[5]), y1 = pkbf(p0[6], p0[7]);
    asm("v_permlane32_swap_b32 %0, %1" : "+v"(x0), "+v"(y0));
    asm("v_permlane32_swap_b32 %0, %1" : "+v"(x1), "+v"(y1));
    union { u32 d[4]; bf16x8 v; } u;
    u.d[0] = x0; u.d[1] = x1; u.d[2] = y0; u.d[3] = y1;
    acc = __builtin_amdgcn_mfma_f32_32x32x16_bf16(v0, u.v, acc, 0, 0, 0);
  }
  {
    u32 x0 = pkbf(p0[8], p0[9]), x1 = pkbf(p0[10], p0[11]);
    u32 y0 = pkbf(p0[12], p0[13]), y1 = pkbf(p0[14], p0[15]);
    asm("v_permlane32_swap_b32 %0, %1" : "+v"(x0), "+v"(y0));
    asm("v_permlane32_swap_b32 %0, %1" : "+v"(x1), "+v"(y1));
    union { u32 d[4]; bf16x8 v; } u;
    u.d[0] = x0; u.d[1] = x1; u.d[2] = y0; u.d[3] = y1;
    acc = __builtin_amdgcn_mfma_f32_32x32x16_bf16(v1, u.v, acc, 0, 0, 0);
  }
  {
    u32 x0 = pkbf(p1[0], p1[1]), x1 = pkbf(p1[2], p1[3]);
    u32 y0 = pkbf(p1[4], p1[5]), y1 = pkbf(p1[6], p1[7]);
    asm("v_permlane32_swap_b32 %0, %1" : "+v"(x0), "+v"(y0));
    asm("v_permlane32_swap_b32 %0, %1" : "+v"(x1), "+v"(y1));
    union { u32 d[4]; bf16x8 v; } u;
    u.d[0] = x0; u.d[1] = x1; u.d[2] = y0; u.d[3] = y1;
    acc = __builtin_amdgcn_mfma_f32_32x32x16_bf16(v2, u.v, acc, 0, 0, 0);
  }
  {
    u32 x0 = pkbf(p1[8], p1[9]), x1 = pkbf(p1[10], p1[11]);
    u32 y0 = pkbf(p1[12], p1[13]), y1 = pkbf(p1[14], p1[15]);
    asm("v_permlane32_swap_b32 %0, %1" : "+v"(x0), "+v"(y0));
    asm("v_permlane32_swap_b32 %0, %1" : "+v"(x1), "+v"(y1));
    union { u32 d[4]; bf16x8 v; } u;
    u.d[0] = x0; u.d[1] = x1; u.d[2] = y0; u.d[3] = y1;
    acc = __builtin_amdgcn_mfma_f32_32x32x16_bf16(v3, u.v, acc, 0, 0, 0);
  }
}

// ---------------- swapped 32x32 flash attention, LDS-staged, 8 waves --------
__global__ __launch_bounds__(512) void attn_kernel(
    const u16* __restrict__ Q, const u16* __restrict__ K,
    const u16* __restrict__ VT, u16* __restrict__ O) {
  __shared__ __align__(16) char LDSB[32768];
  const int t = threadIdx.x, wid = t >> 6, lane = t & 63;
  const int qg = wid & 3, kh = wid >> 2;
  const int bid = blockIdx.x;                    // 1024 blocks
  const int swz = (bid & 7) * 128 + (bid >> 3);  // 8 XCDs
  const int bh = swz >> 4;                       // 0..63
  const int qt = swz & 15;                       // q-tile of 128
  const int q0 = qt * 128 + qg * 32;
  const int lq = lane & 31, hi = lane >> 5;
  const u16* Qh = Q + (size_t)bh * 65536;
  const u16* Kh = K + (size_t)bh * 65536;
  const u16* Vh = VT + (size_t)bh * 65536;

  const bf16x8 qb0 = *(const bf16x8*)(Qh + (size_t)(q0 + lq) * 32 + hi * 8);
  const bf16x8 qb1 = *(const bf16x8*)(Qh + (size_t)(q0 + lq) * 32 + 16 + hi * 8);

  const u16* kg = Kh + wid * 512 + lane * 8;
  const u16* vg = Vh + wid * 512 + lane * 8;
  const int lds_w = wid * 1024;

#define STAGEA(CUR, I)                                                         \
  if (wid < 4) {                                                               \
    char* b_ = LDSB + (CUR) * 16384 + lds_w;                                   \
    GLDS16(kg + (size_t)(I) * 2048, b_);                                       \
    GLDS16(vg + (size_t)(I) * 2048, b_ + 4096);                                \
    GLDS16(kg + (size_t)(16 + (I)) * 2048, b_ + 8192);                         \
    GLDS16(vg + (size_t)(16 + (I)) * 2048, b_ + 12288);                        \
  }

  f32x16 acc = {};
  float la = 0.f, lb = 0.f, lc = 0.f, ld = 0.f;

  STAGEA(0, 0);
  __syncthreads();
  int cur = 0;
#pragma unroll 1
  for (int i = 0; i < 16; ++i) {
    if (i < 15) STAGEA(cur ^ 1, i + 1);
    const char* kb = LDSB + cur * 16384 + kh * 8192 + lane * 16;
    const bf16x8 ka0 = *(const bf16x8*)(kb);
    const bf16x8 ka1 = *(const bf16x8*)(kb + 1024);
    const bf16x8 ka2 = *(const bf16x8*)(kb + 2048);
    const bf16x8 ka3 = *(const bf16x8*)(kb + 3072);
    const bf16x8 va0 = *(const bf16x8*)(kb + 4096);
    const bf16x8 va1 = *(const bf16x8*)(kb + 5120);
    const bf16x8 va2 = *(const bf16x8*)(kb + 6144);
    const bf16x8 va3 = *(const bf16x8*)(kb + 7168);
    attn_tile(ka0, ka1, ka2, ka3, va0, va1, va2, va3, qb0, qb1,
              acc, la, lb, lc, ld);
    __syncthreads();
    cur ^= 1;
  }
#undef STAGEA

  float lrun = (la + lb) + (lc + ld);
  lrun += __shfl_xor(lrun, 32);

  float* sm_acc = (float*)LDSB;            // [4][64][16] = 16KB
  float* sm_l = (float*)(LDSB + 16384);    // [4][32]
  if (kh == 1) {
    sm_l[qg * 32 + lq] = lrun;
#pragma unroll
    for (int r = 0; r < 16; ++r) sm_acc[(qg * 64 + lane) * 16 + r] = acc[r];
  }
  __syncthreads();
  if (kh == 0) {
    const float inv = 1.f / (lrun + sm_l[qg * 32 + lq]);
    const int bb = bh >> 5, h = bh & 31;
    u16* o = O + (size_t)(bb * 2048 + q0 + lq) * 1024 + h * 32;
#pragma unroll
    for (int g = 0; g < 4; ++g) {
      ushort4 st;
      st.x = f2b((acc[g * 4 + 0] + sm_acc[(qg * 64 + lane) * 16 + g * 4 + 0]) * inv);
      st.y = f2b((acc[g * 4 + 1] + sm_acc[(qg * 64 + lane) * 16 + g * 4 + 1]) * inv);
      st.z = f2b((acc[g * 4 + 2] + sm_acc[(qg * 64 + lane) * 16 + g * 4 + 2]) * inv);
      st.w = f2b((acc[g * 4 + 3] + sm_acc[(qg * 64 + lane) * 16 + g * 4 + 3]) * inv);
      *(ushort4*)(o + g * 8 + hi * 4) = st;
    }
  }
}

// ---------------- LN1 in-place on bf16 r1b ----------------------------------
__global__ __launch_bounds__(256) void ln1b_kernel(
    u16* __restrict__ X, const float* __restrict__ g,
    const float* __restrict__ b) {
  const int wid = threadIdx.x >> 6, lane = threadIdx.x & 63;
  const int row = blockIdx.x * 4 + wid;
  ushort4* X4 = (ushort4*)(X + (size_t)row * 1024);
  float4 xs[4];
  float s = 0.f, sq = 0.f;
#pragma unroll
  for (int i = 0; i < 4; ++i) {
    const ushort4 u = X4[lane + i * 64];
    float4 v;
    v.x = b2f(u.x); v.y = b2f(u.y); v.z = b2f(u.z); v.w = b2f(u.w);
    xs[i] = v;
    s += v.x + v.y + v.z + v.w;
    sq += v.x * v.x + v.y * v.y + v.z * v.z + v.w * v.w;
  }
#pragma unroll
  for (int m = 1; m < 64; m <<= 1) { s += __shfl_xor(s, m); sq += __shfl_xor(sq, m); }
  const float mean = s * (1.f / 1024.f);
  float var = sq * (1.f / 1024.f) - mean * mean;
  var = var > 0.f ? var : 0.f;
  const float rstd = rsqrtf(var + 1e-5f);
  const float4* g4 = (const float4*)g;
  const float4* b4 = (const float4*)b;
#pragma unroll
  for (int i = 0; i < 4; ++i) {
    const int c = lane + i * 64;
    const float4 gv = g4[c], bv = b4[c], x = xs[i];
    ushort4 yb;
    yb.x = f2b((x.x - mean) * rstd * gv.x + bv.x);
    yb.y = f2b((x.y - mean) * rstd * gv.y + bv.y);
    yb.z = f2b((x.z - mean) * rstd * gv.z + bv.z);
    yb.w = f2b((x.w - mean) * rstd * gv.w + bv.w);
    X4[c] = yb;
  }
}

// ---------------- LN2: x = p0+p1+p2+p3 (bf16) + res(bf16) + bias ------------
__global__ __launch_bounds__(256) void ln2sum_kernel(
    const u16* __restrict__ P0, const u16* __restrict__ P1,
    const u16* __restrict__ P2, const u16* __restrict__ P3,
    const u16* __restrict__ R, const float* __restrict__ bias,
    const float* __restrict__ g, const float* __restrict__ b,
    float* __restrict__ out) {
  const int wid = threadIdx.x >> 6, lane = threadIdx.x & 63;
  const int row = blockIdx.x * 4 + wid;
  const ushort4* A4 = (const ushort4*)(P0 + (size_t)row * 1024);
  const ushort4* B4 = (const ushort4*)(P1 + (size_t)row * 1024);
  const ushort4* C4 = (const ushort4*)(P2 + (size_t)row * 1024);
  const ushort4* D4 = (const ushort4*)(P3 + (size_t)row * 1024);
  const ushort4* R4 = (const ushort4*)(R + (size_t)row * 1024);
  const float4* Bi4 = (const float4*)bias;
  float4 xs[4];
  float s = 0.f, sq = 0.f;
#pragma unroll
  for (int i = 0; i < 4; ++i) {
    const int c = lane + i * 64;
    const ushort4 a = A4[c], pb = B4[c], pc = C4[c], pd = D4[c], rr = R4[c];
    const float4 bi = Bi4[c];
    float4 x;
    x.x = (b2f(a.x) + b2f(pb.x)) + (b2f(pc.x) + b2f(pd.x)) + b2f(rr.x) + bi.x;
    x.y = (b2f(a.y) + b2f(pb.y)) + (b2f(pc.y) + b2f(pd.y)) + b2f(rr.y) + bi.y;
    x.z = (b2f(a.z) + b2f(pb.z)) + (b2f(pc.z) + b2f(pd.z)) + b2f(rr.z) + bi.z;
    x.w = (b2f(a.w) + b2f(pb.w)) + (b2f(pc.w) + b2f(pd.w)) + b2f(rr.w) + bi.w;
    xs[i] = x;
    s += x.x + x.y + x.z + x.w;
    sq += x.x * x.x + x.y * x.y + x.z * x.z + x.w * x.w;
  }
#pragma unroll
  for (int m = 1; m < 64; m <<= 1) { s += __shfl_xor(s, m); sq += __shfl_xor(sq, m); }
  const float mean = s * (1.f / 1024.f);
  float var = sq * (1.f / 1024.f) - mean * mean;
  var = var > 0.f ? var : 0.f;
  const float rstd = rsqrtf(var + 1e-5f);
  const float4* g4 = (const float4*)g;
  const float4* b4 = (const float4*)b;
  float4* of = (float4*)(out + (size_t)row * 1024);
#pragma unroll
  for (int i = 0; i < 4; ++i) {
    const int c = lane + i * 64;
    const float4 gv = g4[c], bv = b4[c], x = xs[i];
    float4 y;
    y.x = (x.x - mean) * rstd * gv.x + bv.x;
    y.y = (x.y - mean) * rstd * gv.y + bv.y;
    y.z = (x.z - mean) * rstd * gv.z + bv.z;
    y.w = (x.w - mean) * rstd * gv.w + bv.w;
    of[c] = y;
  }
}

// ---------------------------------------------------------------------------
extern "C" void kernel_launch(void* const* d_in, const int* in_sizes, int n_in,
                              void* d_out, int out_size, void* d_ws,
                              size_t ws_size, hipStream_t stream) {
  const float* x   = (const float*)d_in[0];
  const float* Wq  = (const float*)d_in[1];
  const float* bq  = (const float*)d_in[2];
  const float* Wk  = (const float*)d_in[3];
  const float* bk  = (const float*)d_in[4];
  const float* Wv  = (const float*)d_in[5];
  const float* bv  = (const float*)d_in[6];
  const float* kW  = (const float*)d_in[7];
  const float* Wo  = (const float*)d_in[8];
  const float* bo  = (const float*)d_in[9];
  const float* W1  = (const float*)d_in[10];
  const float* b1  = (const float*)d_in[11];
  const float* W2  = (const float*)d_in[12];
  const float* b2  = (const float*)d_in[13];
  const float* g1  = (const float*)d_in[14];
  const float* be1 = (const float*)d_in[15];
  const float* g2  = (const float*)d_in[16];
  const float* be2 = (const float*)d_in[17];

  char* ws = (char*)d_ws;
  const size_t MB = 1024 * 1024;
  u16*   WqT = (u16*)(ws + 0 * MB);   // [0,6) = fused QKV BT[3072][1024]
  u16*   WoT = (u16*)(ws + 6 * MB);
  u16*   W1T = (u16*)(ws + 8 * MB);
  u16*   W2T = (u16*)(ws + 16 * MB);
  u16*   r1b = (u16*)(ws + 24 * MB);  // bf16 residual stream [24,32)
  u16*   xb  = (u16*)(ws + 40 * MB);
  u16*   qhB = (u16*)(ws + 48 * MB);
  u16*   khB = (u16*)(ws + 56 * MB);
  u16*   vTB = (u16*)(ws + 64 * MB);
  u16*   hf  = (u16*)(ws + 40 * MB);  // FFN1 out, aliases xb..vT (dead)
  u16*   ao  = (u16*)(ws + 72 * MB);
  u16*   p0  = (u16*)(ws + 0 * MB);   // FFN2 bf16 partials (dead regions)
  u16*   p2  = (u16*)(ws + 72 * MB);

  const dim3 blk(256);

  // fused prep: all weight transposes + x cast in one dispatch
  prep_kernel<<<16384, blk, 0, stream>>>(Wq, Wk, Wv, Wo, W1, W2, x,
                                         WqT, WoT, W1T, W2T, xb);

  // fused QKV projection (q scaled by kernelW*log2e; k,v fragment-tiled)
  gemmT<5, 128><<<dim3(24, 32), blk, 0, stream>>>(
      xb, WqT, bq, bk, bv, nullptr, qhB, kW, 3072, 1024);

  // flash attention: 1024 blocks x 8 waves (4 qg x 2 key-halves), LDS-staged
  attn_kernel<<<1024, dim3(512), 0, stream>>>(qhB, khB, vTB, ao);

  // out-proj + residual(xb) -> r1b (bf16)
  gemmT<2, 64><<<dim3(16, 32), blk, 0, stream>>>(
      ao, WoT, bo, nullptr, nullptr, (const float*)xb, r1b, nullptr,
      1024, 1024);
  // LN1 in-place on r1b (post-LN1 bf16 feeds FFN1 and final residual)
  ln1b_kernel<<<1024, blk, 0, stream>>>(r1b, g1, be1);
  // FFN1
  gemmT<3, 128><<<dim3(32, 32), blk, 0, stream>>>(
      r1b, W1T, b1, nullptr, nullptr, nullptr, hf, nullptr, 4096, 1024);
  // FFN2: BN=128, split-K 4-way, bf16 partials p0..p3 (1024 blocks, 4/CU)
  gemmT<6, 128><<<dim3(8, 128), blk, 0, stream>>>(
      hf, W2T, nullptr, nullptr, nullptr, (const float*)p2, p0, nullptr,
      1024, 4096);
  // LN2 merges 4 partials + residual + bias
  ln2sum_kernel<<<1024, blk, 0, stream>>>(p0, p0 + 4194304, p2, p2 + 4194304,
                                          r1b, b2, g2, be2, (float*)d_out);

  (void)in_sizes; (void)n_in; (void)out_size; (void)ws_size;
}